// Round 5
// baseline (223.089 us; speedup 1.0000x reference)
//
#include <hip/hip_runtime.h>

// ---------- problem constants ----------
#define BQ   8
#define NQ   8192      // unknown points per batch
#define MK   2048      // known points per batch
#define C1v  128
#define C2v  256
#define CIN  384
#define HH   256
#define MTOT (BQ*NQ)   // 65536

typedef __attribute__((ext_vector_type(8))) __bf16 bf16x8;
typedef __attribute__((ext_vector_type(4))) float f32x4;
typedef __attribute__((ext_vector_type(8))) unsigned short us8;
typedef __attribute__((ext_vector_type(4))) unsigned short us4;
typedef __attribute__((ext_vector_type(2))) unsigned short us2;

__device__ __forceinline__ unsigned short f2bf(float f) {
  unsigned int u = __builtin_bit_cast(unsigned int, f);
  u += 0x7fffu + ((u >> 16) & 1u);           // round-to-nearest-even
  return (unsigned short)(u >> 16);
}
__device__ __forceinline__ float bf2f(unsigned short h) {
  unsigned int u = ((unsigned int)h) << 16;
  return __builtin_bit_cast(float, u);
}

__device__ __forceinline__ void gload16(const void* g, void* l) {
  __builtin_amdgcn_global_load_lds((const __attribute__((address_space(1))) void*)g,
                                   (__attribute__((address_space(3))) void*)l, 16, 0, 0);
}

// 4-op top-3 insert network: {s0,s1,s2} <- top3 of {s0,s1,s2,s}
#define TOP3_INS(s0, s1, s2, s)                        \
  do {                                                 \
    float _mn = fminf(fminf(s0, s1), (s));             \
    s2 = fmaxf(s2, _mn);                               \
    s1 = __builtin_amdgcn_fmed3f(s0, s1, (s));         \
    s0 = fmaxf(s0, (s));                               \
  } while (0)

// (score,index) insert, strict > so earlier index wins ties (top_k semantics)
#define TOP3_INS_IDX(c0, c1, c2, e0, e1, e2, s, jj)                  \
  do {                                                               \
    const bool g0 = (s) > c0, g1 = (s) > c1, g2 = (s) > c2;          \
    c2 = g1 ? c1 : (g2 ? (s) : c2);  e2 = g1 ? e1 : (g2 ? (jj) : e2);\
    c1 = g0 ? c0 : (g1 ? (s) : c1);  e1 = g0 ? e0 : (g1 ? (jj) : e1);\
    c0 = g0 ? (s) : c0;              e0 = g0 ? (jj) : e0;            \
  } while (0)

// score from a staged candidate: s = u.k - 0.5|k|^2  (kprep.w = -0.5|k|^2)
#define SCORE(k4) (fmaf((k4).x, ux, fmaf((k4).y, uy, (k4).z * uz)) + (k4).w)

// ---------- 1. prep: W->bf16, zero BN accumulators, stage kprep ----------
__global__ __launch_bounds__(256)
void prep_kernel(const float* __restrict__ W1, const float* __restrict__ W2,
                 const float* __restrict__ known,
                 unsigned short* __restrict__ w1b, unsigned short* __restrict__ w2b,
                 float* __restrict__ stats, float4* __restrict__ kprep) {
  int i = blockIdx.x * 256 + threadIdx.x;
  if (i < HH*CIN) w1b[i] = f2bf(W1[i]);
  else if (i < HH*CIN + HH*HH) w2b[i - HH*CIN] = f2bf(W2[i - HH*CIN]);
  int z = i - (HH*CIN + HH*HH);
  if (z >= 0 && z < 1024) stats[z] = 0.f;
  int z2 = i - (HH*CIN + HH*HH + 1024);
  if (z2 >= 0 && z2 < BQ*MK) {
    const float* kp = known + (size_t)z2 * 3;
    float x = kp[0], y = kp[1], zz = kp[2];
    kprep[z2] = make_float4(x, y, zz, -0.5f*(x*x + y*y + zz*zz));
  }
}

// ---------- 2. three_nn: pass1 = threshold only; pass2 = exact (score,idx) top-3 ----------
__global__ __launch_bounds__(256)
void nn_kernel(const float* __restrict__ unknown, const float4* __restrict__ kprep,
               int* __restrict__ widx, float* __restrict__ wwgt) {
  __shared__ float ps[4][64][3];       // per-chunk triples (scores)
  __shared__ int   pi[4][64][3];       // per-chunk triples (indices)
  const int b = blockIdx.y;
  const int tid = threadIdx.x;
  const int wave = tid >> 6, lane = tid & 63;

  const int q = blockIdx.x * 64 + lane;
  const float* up = unknown + ((size_t)b * NQ + q) * 3;
  const float ux = up[0], uy = up[1], uz = up[2];
  const float nu = ux*ux + uy*uy + uz*uz;
  const int jbase = wave * 512;
  // wave-uniform chunk pointer -> scalar-path candidate fetch
  const float4* cp = kprep + (b << 11) + __builtin_amdgcn_readfirstlane(jbase);

  // ---- pass 1: chunk-local top-3 scores (threshold only; no bit-match needed) ----
  float A0=-3.4e38f, A1=-3.4e38f, A2=-3.4e38f;
  float B0=-3.4e38f, B1=-3.4e38f, B2=-3.4e38f;
  #pragma unroll 4
  for (int j = 0; j < 512; j += 2) {
    float4 ka = cp[j];
    float4 kc = cp[j+1];
    float sA = SCORE(ka);
    float sB = SCORE(kc);
    TOP3_INS(A0, A1, A2, sA);
    TOP3_INS(B0, B1, B2, sB);
  }
  TOP3_INS(A0, A1, A2, B0);
  TOP3_INS(A0, A1, A2, B1);
  TOP3_INS(A0, A1, A2, B2);
  ps[wave][lane][0] = A0; ps[wave][lane][1] = A1; ps[wave][lane][2] = A2;
  __syncthreads();

  // ---- global 3rd-best score for this lane's query (redundant per wave) ----
  float m0=-3.4e38f, m1=-3.4e38f, m2=-3.4e38f;
  #pragma unroll
  for (int c = 0; c < 4; ++c)
    #pragma unroll
    for (int r = 0; r < 3; ++r) {
      float s = ps[c][lane][r];
      TOP3_INS(m0, m1, m2, s);
    }
  // relaxed threshold: tolerates pass1-vs-pass2 rounding drift; exactness
  // comes from the pass-2 insertion, not from this cutoff
  const float thr = m2 - (fabsf(m2) * 1e-5f + 1e-6f);
  __syncthreads();                    // ps is reused below

  // ---- pass 2: exact (score,index) top-3 among s >= thr, first-occurrence ties ----
  float c0=-3.4e38f, c1=-3.4e38f, c2=-3.4e38f;
  int   e0=0x7fffffff, e1=0x7fffffff, e2=0x7fffffff;
  #pragma unroll 4
  for (int j = 0; j < 512; ++j) {
    float4 k4 = cp[j];
    float s = SCORE(k4);
    if (__builtin_expect(s >= thr, 0)) {
      const int jj = jbase + j;
      TOP3_INS_IDX(c0, c1, c2, e0, e1, e2, s, jj);
    }
  }
  ps[wave][lane][0]=c0; ps[wave][lane][1]=c1; ps[wave][lane][2]=c2;
  pi[wave][lane][0]=e0; pi[wave][lane][1]=e1; pi[wave][lane][2]=e2;
  __syncthreads();

  if (tid < 64) {   // wave 0: lane == query; merge chunks in ascending index order
    float f0=-3.4e38f, f1=-3.4e38f, f2=-3.4e38f;
    int   x0=0x7fffffff, x1=0x7fffffff, x2=0x7fffffff;
    #pragma unroll
    for (int c = 0; c < 4; ++c)
      #pragma unroll
      for (int r = 0; r < 3; ++r) {
        float s = ps[c][tid][r]; int jj = pi[c][tid][r];
        TOP3_INS_IDX(f0, f1, f2, x0, x1, x2, s, jj);
      }
    if (x0 > MK-1) x0 = 0;     // safety net (thr guarantees >=3 hits)
    if (x1 > MK-1) x1 = x0;
    if (x2 > MK-1) x2 = x1;
    float d0 = sqrtf(fmaxf(nu - 2.f*f0, 0.f)) + 1e-10f;
    float d1 = sqrtf(fmaxf(nu - 2.f*f1, 0.f)) + 1e-10f;
    float d2 = sqrtf(fmaxf(nu - 2.f*f2, 0.f)) + 1e-10f;
    float r0 = 1.f/d0, r1 = 1.f/d1, r2 = 1.f/d2;
    float rs = 1.f/(r0 + r1 + r2);
    size_t p = (size_t)b * NQ + q;
    widx[p*3+0] = x0;    widx[p*3+1] = x1;    widx[p*3+2] = x2;
    wwgt[p*3+0] = r0*rs; wwgt[p*3+1] = r1*rs; wwgt[p*3+2] = r2*rs;
  }
}

// ---------- 3. interpolate + concat -> X [65536][384] bf16 ----------
__global__ __launch_bounds__(256)
void interp_kernel(const float* __restrict__ kf, const float* __restrict__ uf,
                   const int* __restrict__ widx, const float* __restrict__ wwgt,
                   unsigned short* __restrict__ X) {
  const int p = blockIdx.x * 4 + (threadIdx.x >> 6);
  const int lane = threadIdx.x & 63;
  const int b = p >> 13, q = p & 8191;
  const int*   ip = widx + (size_t)p * 3;
  const float* wp = wwgt + (size_t)p * 3;
  int   j0 = ip[0], j1 = ip[1], j2 = ip[2];
  float w0 = wp[0], w1 = wp[1], w2 = wp[2];
  const float4* f0 = (const float4*)(kf + ((size_t)b*MK + j0) * C2v);
  const float4* f1 = (const float4*)(kf + ((size_t)b*MK + j1) * C2v);
  const float4* f2 = (const float4*)(kf + ((size_t)b*MK + j2) * C2v);
  float4 a = f0[lane], c = f1[lane], d = f2[lane];
  unsigned short* xr = X + (size_t)p * CIN;
  us4 v;
  v[0] = f2bf(w0*a.x + w1*c.x + w2*d.x);
  v[1] = f2bf(w0*a.y + w1*c.y + w2*d.y);
  v[2] = f2bf(w0*a.z + w1*c.z + w2*d.z);
  v[3] = f2bf(w0*a.w + w1*c.w + w2*d.w);
  *(us4*)(xr + lane*4) = v;
  float2 uu = *(const float2*)(uf + ((size_t)b*NQ + q) * C1v + lane*2);
  us2 w; w[0] = f2bf(uu.x); w[1] = f2bf(uu.y);
  *(us2*)(xr + C2v + lane*2) = w;
}

// ---------- 4. GEMM: Y[M][256] = A[M][K] * Bw[256][K]^T + bias, + BN stats ----------
template<int K, bool OUT_BF16>
__global__ __launch_bounds__(256)
void gemm_kernel(const unsigned short* __restrict__ A,
                 const unsigned short* __restrict__ Bw,
                 const float* __restrict__ bias,
                 void* __restrict__ Out,
                 float* __restrict__ gsum, float* __restrict__ gsq) {
  __shared__ unsigned short As[128][64];   // 16 KB
  __shared__ unsigned short Bs[128][64];   // 16 KB
  const int tid  = threadIdx.x;
  const int lane = tid & 63;
  const int wave = tid >> 6;          // 0..3
  const int bm = blockIdx.x, bn = blockIdx.y;
  const int wm = wave >> 1, wn = wave & 1;

  f32x4 acc[4][4];
  const f32x4 zero = {0.f, 0.f, 0.f, 0.f};
  #pragma unroll
  for (int m = 0; m < 4; ++m)
    #pragma unroll
    for (int n = 0; n < 4; ++n) acc[m][n] = zero;

  for (int k0 = 0; k0 < K; k0 += 64) {
    #pragma unroll
    for (int i = 0; i < 4; ++i) {
      const int cbase = wave*64 + i*256;          // wave-uniform chunk base
      const int c = cbase + lane;                 // per-lane chunk (16 B)
      const int row = c >> 3, col = (c & 7) * 8;
      gload16(A  + ((size_t)(bm*128 + row))*K + k0 + col, (unsigned short*)As + cbase*8);
      gload16(Bw + ((size_t)(bn*128 + row))*K + k0 + col, (unsigned short*)Bs + cbase*8);
    }
    __syncthreads();
    const int kq = (lane >> 4) * 8;
    #pragma unroll
    for (int kk = 0; kk < 64; kk += 32) {
      bf16x8 af[4], bfr[4];
      #pragma unroll
      for (int m = 0; m < 4; ++m)
        af[m] = *(const bf16x8*)&As[wm*64 + m*16 + (lane & 15)][kk + kq];
      #pragma unroll
      for (int n = 0; n < 4; ++n)
        bfr[n] = *(const bf16x8*)&Bs[wn*64 + n*16 + (lane & 15)][kk + kq];
      #pragma unroll
      for (int m = 0; m < 4; ++m)
        #pragma unroll
        for (int n = 0; n < 4; ++n)
          acc[m][n] = __builtin_amdgcn_mfma_f32_16x16x32_bf16(af[m], bfr[n], acc[m][n], 0, 0, 0);
    }
    __syncthreads();
  }

  // epilogue: bias, store, per-channel sum/sumsq
  float* s_sum = (float*)&As[0][0];   // [2][128]
  float* s_sq  = s_sum + 256;         // [2][128]
  #pragma unroll
  for (int n = 0; n < 4; ++n) {
    const int cb   = wn*64 + n*16 + (lane & 15);
    const int gcol = bn*128 + cb;
    const float bv = bias[gcol];
    float sum = 0.f, sq = 0.f;
    #pragma unroll
    for (int m = 0; m < 4; ++m) {
      const size_t grow = (size_t)bm*128 + wm*64 + m*16 + (lane >> 4)*4;
      #pragma unroll
      for (int qq = 0; qq < 4; ++qq) {
        float y = acc[m][n][qq] + bv;
        sum += y; sq += y*y;
        if (OUT_BF16) ((unsigned short*)Out)[(grow+qq)*256 + gcol] = f2bf(y);
        else          ((float*)Out)[(grow+qq)*256 + gcol] = y;
      }
    }
    sum += __shfl_xor(sum, 16, 64); sum += __shfl_xor(sum, 32, 64);
    sq  += __shfl_xor(sq , 16, 64); sq  += __shfl_xor(sq , 32, 64);
    if (lane < 16) { s_sum[wm*128 + cb] = sum; s_sq[wm*128 + cb] = sq; }
  }
  __syncthreads();
  if (tid < 128) {
    atomicAdd(&gsum[bn*128 + tid], s_sum[tid] + s_sum[128 + tid]);
    atomicAdd(&gsq [bn*128 + tid], s_sq [tid] + s_sq [128 + tid]);
  }
}

// ---------- 5. BN stats finalize: scale/shift ----------
__global__ __launch_bounds__(256)
void stats_fin(const float* __restrict__ gsum, const float* __restrict__ gsq,
               const float* __restrict__ g, const float* __restrict__ beta,
               float* __restrict__ scale, float* __restrict__ shift) {
  int c = threadIdx.x;
  float mu  = gsum[c] * (1.f/65536.f);
  float var = gsq[c]  * (1.f/65536.f) - mu*mu;
  float sc  = g[c] * rsqrtf(var + 1e-5f);
  scale[c] = sc;
  shift[c] = beta[c] - mu*sc;
}

// ---------- 6. BN+ReLU elementwise (bf16 -> bf16) ----------
__global__ __launch_bounds__(256)
void bnrelu_kernel(const unsigned short* __restrict__ Y,
                   const float* __restrict__ scale, const float* __restrict__ shift,
                   unsigned short* __restrict__ Z) {
  __shared__ float sc[256], sh[256];
  if (threadIdx.x < 256) { sc[threadIdx.x] = scale[threadIdx.x]; sh[threadIdx.x] = shift[threadIdx.x]; }
  __syncthreads();
  size_t i = ((size_t)blockIdx.x * 256 + threadIdx.x) * 8;
  int c0 = (int)(i & 255);
  us8 v = *(const us8*)(Y + i);
  us8 o;
  #pragma unroll
  for (int j = 0; j < 8; ++j) {
    float y = bf2f(v[j]) * sc[c0+j] + sh[c0+j];
    o[j] = f2bf(fmaxf(y, 0.f));
  }
  *(us8*)(Z + i) = o;
}

// ---------- 7. final BN+ReLU in-place on d_out (fp32) ----------
__global__ __launch_bounds__(256)
void final_kernel(float* __restrict__ Y,
                  const float* __restrict__ scale, const float* __restrict__ shift) {
  __shared__ float sc[256], sh[256];
  if (threadIdx.x < 256) { sc[threadIdx.x] = scale[threadIdx.x]; sh[threadIdx.x] = shift[threadIdx.x]; }
  __syncthreads();
  size_t i = ((size_t)blockIdx.x * 256 + threadIdx.x) * 4;
  int c0 = (int)(i & 255);
  float4 v = *(float4*)(Y + i);
  v.x = fmaxf(fmaf(v.x, sc[c0+0], sh[c0+0]), 0.f);
  v.y = fmaxf(fmaf(v.y, sc[c0+1], sh[c0+1]), 0.f);
  v.z = fmaxf(fmaf(v.z, sc[c0+2], sh[c0+2]), 0.f);
  v.w = fmaxf(fmaf(v.w, sc[c0+3], sh[c0+3]), 0.f);
  *(float4*)(Y + i) = v;
}

// ---------- launch ----------
extern "C" void kernel_launch(void* const* d_in, const int* in_sizes, int n_in,
                              void* d_out, int out_size, void* d_ws, size_t ws_size,
                              hipStream_t stream) {
  const float* unknown = (const float*)d_in[0];
  const float* known   = (const float*)d_in[1];
  const float* uf      = (const float*)d_in[2];
  const float* kf      = (const float*)d_in[3];
  const float* W1      = (const float*)d_in[4];
  const float* b1      = (const float*)d_in[5];
  const float* g1      = (const float*)d_in[6];
  const float* be1     = (const float*)d_in[7];
  const float* W2      = (const float*)d_in[8];
  const float* b2      = (const float*)d_in[9];
  const float* g2      = (const float*)d_in[10];
  const float* be2     = (const float*)d_in[11];

  char* ws = (char*)d_ws;
  unsigned short* X    = (unsigned short*)(ws);                 // 65536*384*2 = 50,331,648
  unsigned short* Y1   = (unsigned short*)(ws + 50331648);      // 65536*256*2 = 33,554,432
  unsigned short* w1b  = (unsigned short*)(ws + 83886080);      // 196,608
  unsigned short* w2b  = (unsigned short*)(ws + 84082688);      // 131,072
  int*            widx = (int*)  (ws + 84213760);               // 786,432
  float*          wwgt = (float*)(ws + 85000192);               // 786,432
  float*          stats= (float*)(ws + 85786624);               // 8 KB
  float4*         kprep= (float4*)(ws + 85794816);              // 8*2048*16 = 262,144
  float *sum1 = stats,        *sq1 = stats + 256;
  float *sum2 = stats + 512,  *sq2 = stats + 768;
  float *scale1 = stats + 1024, *shift1 = stats + 1280;
  float *scale2 = stats + 1536, *shift2 = stats + 1792;
  float* out = (float*)d_out;

  prep_kernel<<<708, 256, 0, stream>>>(W1, W2, known, w1b, w2b, stats, kprep);
  nn_kernel<<<dim3(128, 8), 256, 0, stream>>>(unknown, kprep, widx, wwgt);
  interp_kernel<<<16384, 256, 0, stream>>>(kf, uf, widx, wwgt, X);
  gemm_kernel<CIN, true ><<<dim3(512, 2), 256, 0, stream>>>(X, w1b, b1, Y1, sum1, sq1);
  stats_fin<<<1, 256, 0, stream>>>(sum1, sq1, g1, be1, scale1, shift1);
  bnrelu_kernel<<<8192, 256, 0, stream>>>(Y1, scale1, shift1, X);   // X reused as layer-2 input
  gemm_kernel<HH, false><<<dim3(512, 2), 256, 0, stream>>>(X, w2b, b2, out, sum2, sq2);
  stats_fin<<<1, 256, 0, stream>>>(sum2, sq2, g2, be2, scale2, shift2);
  final_kernel<<<16384, 256, 0, stream>>>(out, scale2, shift2);
}

// Round 6
// 207.455 us; speedup vs baseline: 1.0754x; 1.0754x over previous
//
#include <hip/hip_runtime.h>

// ---------- problem constants ----------
#define BQ   8
#define NQ   8192      // unknown points per batch
#define MK   2048      // known points per batch
#define C1v  128
#define C2v  256
#define CIN  384
#define HH   256
#define MTOT (BQ*NQ)   // 65536

#define NCHUNK 8       // candidate chunks per block (= waves per nn block)
#define CHSZ   (MK/NCHUNK)   // 256 candidates per chunk

typedef __attribute__((ext_vector_type(8))) __bf16 bf16x8;
typedef __attribute__((ext_vector_type(4))) float f32x4;
typedef __attribute__((ext_vector_type(8))) unsigned short us8;
typedef __attribute__((ext_vector_type(4))) unsigned short us4;
typedef __attribute__((ext_vector_type(2))) unsigned short us2;

__device__ __forceinline__ unsigned short f2bf(float f) {
  unsigned int u = __builtin_bit_cast(unsigned int, f);
  u += 0x7fffu + ((u >> 16) & 1u);           // round-to-nearest-even
  return (unsigned short)(u >> 16);
}
__device__ __forceinline__ float bf2f(unsigned short h) {
  unsigned int u = ((unsigned int)h) << 16;
  return __builtin_bit_cast(float, u);
}

__device__ __forceinline__ void gload16(const void* g, void* l) {
  __builtin_amdgcn_global_load_lds((const __attribute__((address_space(1))) void*)g,
                                   (__attribute__((address_space(3))) void*)l, 16, 0, 0);
}

// 5-op top-3 insert network: {s0,s1,s2} <- top3 of {s0,s1,s2,s}
#define TOP3_INS(s0, s1, s2, s)                        \
  do {                                                 \
    float _mn = fminf(fminf(s0, s1), (s));             \
    s2 = fmaxf(s2, _mn);                               \
    s1 = __builtin_amdgcn_fmed3f(s0, s1, (s));         \
    s0 = fmaxf(s0, (s));                               \
  } while (0)

// (score,index) insert, strict > so earlier index wins ties (top_k semantics)
#define TOP3_INS_IDX(c0, c1, c2, e0, e1, e2, s, jj)                  \
  do {                                                               \
    const bool g0 = (s) > c0, g1 = (s) > c1, g2 = (s) > c2;          \
    c2 = g1 ? c1 : (g2 ? (s) : c2);  e2 = g1 ? e1 : (g2 ? (jj) : e2);\
    c1 = g0 ? c0 : (g1 ? (s) : c1);  e1 = g0 ? e0 : (g1 ? (jj) : e1);\
    c0 = g0 ? (s) : c0;              e0 = g0 ? (jj) : e0;            \
  } while (0)

// score from a staged candidate: s = u.k - 0.5|k|^2  (kprep.w = -0.5|k|^2)
#define SCORE(k4) (fmaf((k4).x, ux, fmaf((k4).y, uy, (k4).z * uz)) + (k4).w)

// ---------- 1. prep: W->bf16, zero BN accumulators, stage kprep ----------
__global__ __launch_bounds__(256)
void prep_kernel(const float* __restrict__ W1, const float* __restrict__ W2,
                 const float* __restrict__ known,
                 unsigned short* __restrict__ w1b, unsigned short* __restrict__ w2b,
                 float* __restrict__ stats, float4* __restrict__ kprep) {
  int i = blockIdx.x * 256 + threadIdx.x;
  if (i < HH*CIN) w1b[i] = f2bf(W1[i]);
  else if (i < HH*CIN + HH*HH) w2b[i - HH*CIN] = f2bf(W2[i - HH*CIN]);
  int z = i - (HH*CIN + HH*HH);
  if (z >= 0 && z < 1024) stats[z] = 0.f;
  int z2 = i - (HH*CIN + HH*HH + 1024);
  if (z2 >= 0 && z2 < BQ*MK) {
    const float* kp = known + (size_t)z2 * 3;
    float x = kp[0], y = kp[1], zz = kp[2];
    kprep[z2] = make_float4(x, y, zz, -0.5f*(x*x + y*y + zz*zz));
  }
}

// ---------- 2. three_nn: 8 waves/block (256 cands each) for full CU residency;
//             pass1 = threshold only; pass2 = exact (score,idx) top-3 ----------
__global__ __launch_bounds__(512)
void nn_kernel(const float* __restrict__ unknown, const float4* __restrict__ kprep,
               int* __restrict__ widx, float* __restrict__ wwgt) {
  __shared__ float ps[NCHUNK][64][3];       // per-chunk triples (scores)
  __shared__ int   pi[NCHUNK][64][3];       // per-chunk triples (indices)
  const int b = blockIdx.y;
  const int tid = threadIdx.x;
  const int wave = tid >> 6, lane = tid & 63;

  const int q = blockIdx.x * 64 + lane;
  const float* up = unknown + ((size_t)b * NQ + q) * 3;
  const float ux = up[0], uy = up[1], uz = up[2];
  const float nu = ux*ux + uy*uy + uz*uz;
  const int jbase = wave * CHSZ;
  // wave-uniform chunk pointer -> scalar-path candidate fetch
  const float4* cp = kprep + (b << 11) + __builtin_amdgcn_readfirstlane(jbase);

  // ---- pass 1: chunk-local top-3 scores (threshold only; no bit-match needed) ----
  float A0=-3.4e38f, A1=-3.4e38f, A2=-3.4e38f;
  float B0=-3.4e38f, B1=-3.4e38f, B2=-3.4e38f;
  #pragma unroll 4
  for (int j = 0; j < CHSZ; j += 2) {
    float4 ka = cp[j];
    float4 kc = cp[j+1];
    float sA = SCORE(ka);
    float sB = SCORE(kc);
    TOP3_INS(A0, A1, A2, sA);
    TOP3_INS(B0, B1, B2, sB);
  }
  TOP3_INS(A0, A1, A2, B0);
  TOP3_INS(A0, A1, A2, B1);
  TOP3_INS(A0, A1, A2, B2);
  ps[wave][lane][0] = A0; ps[wave][lane][1] = A1; ps[wave][lane][2] = A2;
  __syncthreads();

  // ---- global 3rd-best score for this lane's query (redundant per wave) ----
  float m0=-3.4e38f, m1=-3.4e38f, m2=-3.4e38f;
  #pragma unroll
  for (int c = 0; c < NCHUNK; ++c)
    #pragma unroll
    for (int r = 0; r < 3; ++r) {
      float s = ps[c][lane][r];
      TOP3_INS(m0, m1, m2, s);
    }
  // relaxed threshold: tolerates pass1-vs-pass2 rounding drift; exactness
  // comes from the pass-2 insertion, not from this cutoff
  const float thr = m2 - (fabsf(m2) * 1e-5f + 1e-6f);
  __syncthreads();                    // ps is reused below

  // ---- pass 2: exact (score,index) top-3 among s >= thr, first-occurrence ties ----
  float c0=-3.4e38f, c1=-3.4e38f, c2=-3.4e38f;
  int   e0=0x7fffffff, e1=0x7fffffff, e2=0x7fffffff;
  #pragma unroll 4
  for (int j = 0; j < CHSZ; ++j) {
    float4 k4 = cp[j];
    float s = SCORE(k4);
    if (__builtin_expect(s >= thr, 0)) {
      const int jj = jbase + j;
      TOP3_INS_IDX(c0, c1, c2, e0, e1, e2, s, jj);
    }
  }
  ps[wave][lane][0]=c0; ps[wave][lane][1]=c1; ps[wave][lane][2]=c2;
  pi[wave][lane][0]=e0; pi[wave][lane][1]=e1; pi[wave][lane][2]=e2;
  __syncthreads();

  if (tid < 64) {   // wave 0: lane == query; merge chunks in ascending index order
    float f0=-3.4e38f, f1=-3.4e38f, f2=-3.4e38f;
    int   x0=0x7fffffff, x1=0x7fffffff, x2=0x7fffffff;
    #pragma unroll
    for (int c = 0; c < NCHUNK; ++c)
      #pragma unroll
      for (int r = 0; r < 3; ++r) {
        float s = ps[c][tid][r]; int jj = pi[c][tid][r];
        TOP3_INS_IDX(f0, f1, f2, x0, x1, x2, s, jj);
      }
    if (x0 > MK-1) x0 = 0;     // safety net (thr guarantees >=3 hits)
    if (x1 > MK-1) x1 = x0;
    if (x2 > MK-1) x2 = x1;
    float d0 = sqrtf(fmaxf(nu - 2.f*f0, 0.f)) + 1e-10f;
    float d1 = sqrtf(fmaxf(nu - 2.f*f1, 0.f)) + 1e-10f;
    float d2 = sqrtf(fmaxf(nu - 2.f*f2, 0.f)) + 1e-10f;
    float r0 = 1.f/d0, r1 = 1.f/d1, r2 = 1.f/d2;
    float rs = 1.f/(r0 + r1 + r2);
    size_t p = (size_t)b * NQ + q;
    widx[p*3+0] = x0;    widx[p*3+1] = x1;    widx[p*3+2] = x2;
    wwgt[p*3+0] = r0*rs; wwgt[p*3+1] = r1*rs; wwgt[p*3+2] = r2*rs;
  }
}

// ---------- 3. interpolate + concat -> X [65536][384] bf16 ----------
__global__ __launch_bounds__(256)
void interp_kernel(const float* __restrict__ kf, const float* __restrict__ uf,
                   const int* __restrict__ widx, const float* __restrict__ wwgt,
                   unsigned short* __restrict__ X) {
  const int p = blockIdx.x * 4 + (threadIdx.x >> 6);
  const int lane = threadIdx.x & 63;
  const int b = p >> 13, q = p & 8191;
  const int*   ip = widx + (size_t)p * 3;
  const float* wp = wwgt + (size_t)p * 3;
  int   j0 = ip[0], j1 = ip[1], j2 = ip[2];
  float w0 = wp[0], w1 = wp[1], w2 = wp[2];
  const float4* f0 = (const float4*)(kf + ((size_t)b*MK + j0) * C2v);
  const float4* f1 = (const float4*)(kf + ((size_t)b*MK + j1) * C2v);
  const float4* f2 = (const float4*)(kf + ((size_t)b*MK + j2) * C2v);
  float4 a = f0[lane], c = f1[lane], d = f2[lane];
  unsigned short* xr = X + (size_t)p * CIN;
  us4 v;
  v[0] = f2bf(w0*a.x + w1*c.x + w2*d.x);
  v[1] = f2bf(w0*a.y + w1*c.y + w2*d.y);
  v[2] = f2bf(w0*a.z + w1*c.z + w2*d.z);
  v[3] = f2bf(w0*a.w + w1*c.w + w2*d.w);
  *(us4*)(xr + lane*4) = v;
  float2 uu = *(const float2*)(uf + ((size_t)b*NQ + q) * C1v + lane*2);
  us2 w; w[0] = f2bf(uu.x); w[1] = f2bf(uu.y);
  *(us2*)(xr + C2v + lane*2) = w;
}

// ---------- 4. GEMM: Y[M][256] = A[M][K] * Bw[256][K]^T + bias, + BN stats ----------
template<int K, bool OUT_BF16>
__global__ __launch_bounds__(256)
void gemm_kernel(const unsigned short* __restrict__ A,
                 const unsigned short* __restrict__ Bw,
                 const float* __restrict__ bias,
                 void* __restrict__ Out,
                 float* __restrict__ gsum, float* __restrict__ gsq) {
  __shared__ unsigned short As[128][64];   // 16 KB
  __shared__ unsigned short Bs[128][64];   // 16 KB
  const int tid  = threadIdx.x;
  const int lane = tid & 63;
  const int wave = tid >> 6;          // 0..3
  const int bm = blockIdx.x, bn = blockIdx.y;
  const int wm = wave >> 1, wn = wave & 1;

  f32x4 acc[4][4];
  const f32x4 zero = {0.f, 0.f, 0.f, 0.f};
  #pragma unroll
  for (int m = 0; m < 4; ++m)
    #pragma unroll
    for (int n = 0; n < 4; ++n) acc[m][n] = zero;

  for (int k0 = 0; k0 < K; k0 += 64) {
    #pragma unroll
    for (int i = 0; i < 4; ++i) {
      const int cbase = wave*64 + i*256;          // wave-uniform chunk base
      const int c = cbase + lane;                 // per-lane chunk (16 B)
      const int row = c >> 3, col = (c & 7) * 8;
      gload16(A  + ((size_t)(bm*128 + row))*K + k0 + col, (unsigned short*)As + cbase*8);
      gload16(Bw + ((size_t)(bn*128 + row))*K + k0 + col, (unsigned short*)Bs + cbase*8);
    }
    __syncthreads();
    const int kq = (lane >> 4) * 8;
    #pragma unroll
    for (int kk = 0; kk < 64; kk += 32) {
      bf16x8 af[4], bfr[4];
      #pragma unroll
      for (int m = 0; m < 4; ++m)
        af[m] = *(const bf16x8*)&As[wm*64 + m*16 + (lane & 15)][kk + kq];
      #pragma unroll
      for (int n = 0; n < 4; ++n)
        bfr[n] = *(const bf16x8*)&Bs[wn*64 + n*16 + (lane & 15)][kk + kq];
      #pragma unroll
      for (int m = 0; m < 4; ++m)
        #pragma unroll
        for (int n = 0; n < 4; ++n)
          acc[m][n] = __builtin_amdgcn_mfma_f32_16x16x32_bf16(af[m], bfr[n], acc[m][n], 0, 0, 0);
    }
    __syncthreads();
  }

  // epilogue: bias, store, per-channel sum/sumsq
  float* s_sum = (float*)&As[0][0];   // [2][128]
  float* s_sq  = s_sum + 256;         // [2][128]
  #pragma unroll
  for (int n = 0; n < 4; ++n) {
    const int cb   = wn*64 + n*16 + (lane & 15);
    const int gcol = bn*128 + cb;
    const float bv = bias[gcol];
    float sum = 0.f, sq = 0.f;
    #pragma unroll
    for (int m = 0; m < 4; ++m) {
      const size_t grow = (size_t)bm*128 + wm*64 + m*16 + (lane >> 4)*4;
      #pragma unroll
      for (int qq = 0; qq < 4; ++qq) {
        float y = acc[m][n][qq] + bv;
        sum += y; sq += y*y;
        if (OUT_BF16) ((unsigned short*)Out)[(grow+qq)*256 + gcol] = f2bf(y);
        else          ((float*)Out)[(grow+qq)*256 + gcol] = y;
      }
    }
    sum += __shfl_xor(sum, 16, 64); sum += __shfl_xor(sum, 32, 64);
    sq  += __shfl_xor(sq , 16, 64); sq  += __shfl_xor(sq , 32, 64);
    if (lane < 16) { s_sum[wm*128 + cb] = sum; s_sq[wm*128 + cb] = sq; }
  }
  __syncthreads();
  if (tid < 128) {
    atomicAdd(&gsum[bn*128 + tid], s_sum[tid] + s_sum[128 + tid]);
    atomicAdd(&gsq [bn*128 + tid], s_sq [tid] + s_sq [128 + tid]);
  }
}

// ---------- 5. BN stats finalize: scale/shift ----------
__global__ __launch_bounds__(256)
void stats_fin(const float* __restrict__ gsum, const float* __restrict__ gsq,
               const float* __restrict__ g, const float* __restrict__ beta,
               float* __restrict__ scale, float* __restrict__ shift) {
  int c = threadIdx.x;
  float mu  = gsum[c] * (1.f/65536.f);
  float var = gsq[c]  * (1.f/65536.f) - mu*mu;
  float sc  = g[c] * rsqrtf(var + 1e-5f);
  scale[c] = sc;
  shift[c] = beta[c] - mu*sc;
}

// ---------- 6. BN+ReLU elementwise (bf16 -> bf16) ----------
__global__ __launch_bounds__(256)
void bnrelu_kernel(const unsigned short* __restrict__ Y,
                   const float* __restrict__ scale, const float* __restrict__ shift,
                   unsigned short* __restrict__ Z) {
  __shared__ float sc[256], sh[256];
  if (threadIdx.x < 256) { sc[threadIdx.x] = scale[threadIdx.x]; sh[threadIdx.x] = shift[threadIdx.x]; }
  __syncthreads();
  size_t i = ((size_t)blockIdx.x * 256 + threadIdx.x) * 8;
  int c0 = (int)(i & 255);
  us8 v = *(const us8*)(Y + i);
  us8 o;
  #pragma unroll
  for (int j = 0; j < 8; ++j) {
    float y = bf2f(v[j]) * sc[c0+j] + sh[c0+j];
    o[j] = f2bf(fmaxf(y, 0.f));
  }
  *(us8*)(Z + i) = o;
}

// ---------- 7. final BN+ReLU in-place on d_out (fp32) ----------
__global__ __launch_bounds__(256)
void final_kernel(float* __restrict__ Y,
                  const float* __restrict__ scale, const float* __restrict__ shift) {
  __shared__ float sc[256], sh[256];
  if (threadIdx.x < 256) { sc[threadIdx.x] = scale[threadIdx.x]; sh[threadIdx.x] = shift[threadIdx.x]; }
  __syncthreads();
  size_t i = ((size_t)blockIdx.x * 256 + threadIdx.x) * 4;
  int c0 = (int)(i & 255);
  float4 v = *(float4*)(Y + i);
  v.x = fmaxf(fmaf(v.x, sc[c0+0], sh[c0+0]), 0.f);
  v.y = fmaxf(fmaf(v.y, sc[c0+1], sh[c0+1]), 0.f);
  v.z = fmaxf(fmaf(v.z, sc[c0+2], sh[c0+2]), 0.f);
  v.w = fmaxf(fmaf(v.w, sc[c0+3], sh[c0+3]), 0.f);
  *(float4*)(Y + i) = v;
}

// ---------- launch ----------
extern "C" void kernel_launch(void* const* d_in, const int* in_sizes, int n_in,
                              void* d_out, int out_size, void* d_ws, size_t ws_size,
                              hipStream_t stream) {
  const float* unknown = (const float*)d_in[0];
  const float* known   = (const float*)d_in[1];
  const float* uf      = (const float*)d_in[2];
  const float* kf      = (const float*)d_in[3];
  const float* W1      = (const float*)d_in[4];
  const float* b1      = (const float*)d_in[5];
  const float* g1      = (const float*)d_in[6];
  const float* be1     = (const float*)d_in[7];
  const float* W2      = (const float*)d_in[8];
  const float* b2      = (const float*)d_in[9];
  const float* g2      = (const float*)d_in[10];
  const float* be2     = (const float*)d_in[11];

  char* ws = (char*)d_ws;
  unsigned short* X    = (unsigned short*)(ws);                 // 65536*384*2 = 50,331,648
  unsigned short* Y1   = (unsigned short*)(ws + 50331648);      // 65536*256*2 = 33,554,432
  unsigned short* w1b  = (unsigned short*)(ws + 83886080);      // 196,608
  unsigned short* w2b  = (unsigned short*)(ws + 84082688);      // 131,072
  int*            widx = (int*)  (ws + 84213760);               // 786,432
  float*          wwgt = (float*)(ws + 85000192);               // 786,432
  float*          stats= (float*)(ws + 85786624);               // 8 KB
  float4*         kprep= (float4*)(ws + 85794816);              // 8*2048*16 = 262,144
  float *sum1 = stats,        *sq1 = stats + 256;
  float *sum2 = stats + 512,  *sq2 = stats + 768;
  float *scale1 = stats + 1024, *shift1 = stats + 1280;
  float *scale2 = stats + 1536, *shift2 = stats + 1792;
  float* out = (float*)d_out;

  prep_kernel<<<708, 256, 0, stream>>>(W1, W2, known, w1b, w2b, stats, kprep);
  nn_kernel<<<dim3(128, 8), 512, 0, stream>>>(unknown, kprep, widx, wwgt);
  interp_kernel<<<16384, 256, 0, stream>>>(kf, uf, widx, wwgt, X);
  gemm_kernel<CIN, true ><<<dim3(512, 2), 256, 0, stream>>>(X, w1b, b1, Y1, sum1, sq1);
  stats_fin<<<1, 256, 0, stream>>>(sum1, sq1, g1, be1, scale1, shift1);
  bnrelu_kernel<<<8192, 256, 0, stream>>>(Y1, scale1, shift1, X);   // X reused as layer-2 input
  gemm_kernel<HH, false><<<dim3(512, 2), 256, 0, stream>>>(X, w2b, b2, out, sum2, sq2);
  stats_fin<<<1, 256, 0, stream>>>(sum2, sq2, g2, be2, scale2, shift2);
  final_kernel<<<16384, 256, 0, stream>>>(out, scale2, shift2);
}

// Round 7
// 187.565 us; speedup vs baseline: 1.1894x; 1.1060x over previous
//
#include <hip/hip_runtime.h>

// ---------- problem constants ----------
#define BQ   8
#define NQ   8192      // unknown points per batch
#define MK   2048      // known points per batch
#define C1v  128
#define C2v  256
#define CIN  384
#define HH   256
#define MTOT (BQ*NQ)   // 65536

#define NCHUNK 8       // candidate chunks per nn block (= waves per block)
#define CHSZ   (MK/NCHUNK)   // 256 candidates per chunk

typedef __attribute__((ext_vector_type(8))) __bf16 bf16x8;
typedef __attribute__((ext_vector_type(4))) float f32x4;
typedef __attribute__((ext_vector_type(2))) float f32x2;
typedef __attribute__((ext_vector_type(8))) unsigned short us8;
typedef __attribute__((ext_vector_type(4))) unsigned short us4;
typedef __attribute__((ext_vector_type(2))) unsigned short us2;

__device__ __forceinline__ unsigned short f2bf(float f) {
  unsigned int u = __builtin_bit_cast(unsigned int, f);
  u += 0x7fffu + ((u >> 16) & 1u);           // round-to-nearest-even
  return (unsigned short)(u >> 16);
}
__device__ __forceinline__ float bf2f(unsigned short h) {
  unsigned int u = ((unsigned int)h) << 16;
  return __builtin_bit_cast(float, u);
}

__device__ __forceinline__ void gload16(const void* g, void* l) {
  __builtin_amdgcn_global_load_lds((const __attribute__((address_space(1))) void*)g,
                                   (__attribute__((address_space(3))) void*)l, 16, 0, 0);
}

// 4-op top-3 insert network (min3/med3/max fuse): {s0,s1,s2} <- top3 of {s0,s1,s2,s}
#define TOP3_INS(s0, s1, s2, s)                        \
  do {                                                 \
    float _mn = fminf(fminf(s0, s1), (s));             \
    s2 = fmaxf(s2, _mn);                               \
    s1 = __builtin_amdgcn_fmed3f(s0, s1, (s));         \
    s0 = fmaxf(s0, (s));                               \
  } while (0)

// (score,index) insert, strict > so earlier index wins ties (top_k semantics)
#define TOP3_INS_IDX(c0, c1, c2, e0, e1, e2, s, jj)                  \
  do {                                                               \
    const bool g0 = (s) > c0, g1 = (s) > c1, g2 = (s) > c2;          \
    c2 = g1 ? c1 : (g2 ? (s) : c2);  e2 = g1 ? e1 : (g2 ? (jj) : e2);\
    c1 = g0 ? c0 : (g1 ? (s) : c1);  e1 = g0 ? e0 : (g1 ? (jj) : e1);\
    c0 = g0 ? (s) : c0;              e0 = g0 ? (jj) : e0;            \
  } while (0)

// ---------- 1. prep: W->bf16, zero BN accumulators, stage kprep (pair-SoA) ----------
// kprep layout per pair p of candidates (2p,2p+1), 8 floats:
//   [x0,x1, y0,y1, z0,z1, w0,w1]  with w = -0.5*|k|^2
__global__ __launch_bounds__(256)
void prep_kernel(const float* __restrict__ W1, const float* __restrict__ W2,
                 const float* __restrict__ known,
                 unsigned short* __restrict__ w1b, unsigned short* __restrict__ w2b,
                 float* __restrict__ stats, float* __restrict__ kprep) {
  int i = blockIdx.x * 256 + threadIdx.x;
  if (i < HH*CIN) w1b[i] = f2bf(W1[i]);
  else if (i < HH*CIN + HH*HH) w2b[i - HH*CIN] = f2bf(W2[i - HH*CIN]);
  int z = i - (HH*CIN + HH*HH);
  if (z >= 0 && z < 1024) stats[z] = 0.f;
  int z2 = i - (HH*CIN + HH*HH + 1024);
  if (z2 >= 0 && z2 < BQ*MK) {
    const int b = z2 >> 11, jj = z2 & (MK-1);
    const float* kp = known + (size_t)z2 * 3;
    float x = kp[0], y = kp[1], zz = kp[2];
    float w = -0.5f*(x*x + y*y + zz*zz);
    size_t pb = ((size_t)(b << 10) + (jj >> 1)) * 8 + (jj & 1);
    kprep[pb + 0] = x;
    kprep[pb + 2] = y;
    kprep[pb + 4] = zz;
    kprep[pb + 6] = w;
  }
}

// ---------- 2. three_nn: packed-fp32 scores, pass1 threshold + pass2 exact ----------
__global__ __launch_bounds__(512)
void nn_kernel(const float* __restrict__ unknown, const float* __restrict__ kprep,
               int* __restrict__ widx, float* __restrict__ wwgt) {
  __shared__ float ps[NCHUNK][64][3];       // per-chunk triples (scores)
  __shared__ int   pi[NCHUNK][64][3];       // per-chunk triples (indices)
  const int b = blockIdx.y;
  const int tid = threadIdx.x;
  const int wave = tid >> 6, lane = tid & 63;

  const int q = blockIdx.x * 64 + lane;
  const float* up = unknown + ((size_t)b * NQ + q) * 3;
  const float ux = up[0], uy = up[1], uz = up[2];
  const float nu = ux*ux + uy*uy + uz*uz;
  const f32x2 ux2 = {ux, ux}, uy2 = {uy, uy}, uz2 = {uz, uz};
  const int jbase = wave * CHSZ;
  // wave-uniform pair pointer -> scalar-path (s_load) candidate fetch
  const f32x2* cp2 = (const f32x2*)kprep
      + ((size_t)(b << 10) + __builtin_amdgcn_readfirstlane(jbase >> 1)) * 4;

  // ---- pass 1: chunk-local top-3 scores (threshold only) ----
  float A0=-3.4e38f, A1=-3.4e38f, A2=-3.4e38f;   // even candidates
  float B0=-3.4e38f, B1=-3.4e38f, B2=-3.4e38f;   // odd candidates
  #pragma unroll 4
  for (int p = 0; p < CHSZ/2; ++p) {
    f32x2 X2 = cp2[p*4+0], Y2 = cp2[p*4+1], Z2 = cp2[p*4+2], W2 = cp2[p*4+3];
    f32x2 s = __builtin_elementwise_fma(X2, ux2,
              __builtin_elementwise_fma(Y2, uy2, Z2*uz2)) + W2;
    TOP3_INS(A0, A1, A2, s.x);
    TOP3_INS(B0, B1, B2, s.y);
  }
  TOP3_INS(A0, A1, A2, B0);
  TOP3_INS(A0, A1, A2, B1);
  TOP3_INS(A0, A1, A2, B2);
  ps[wave][lane][0] = A0; ps[wave][lane][1] = A1; ps[wave][lane][2] = A2;
  __syncthreads();

  // ---- global 3rd-best score for this lane's query (redundant per wave) ----
  float m0=-3.4e38f, m1=-3.4e38f, m2=-3.4e38f;
  #pragma unroll
  for (int c = 0; c < NCHUNK; ++c)
    #pragma unroll
    for (int r = 0; r < 3; ++r) {
      float s = ps[c][lane][r];
      TOP3_INS(m0, m1, m2, s);
    }
  // relaxed threshold: tolerates pass1-vs-pass2 rounding drift; exactness
  // comes from the pass-2 insertion, not from this cutoff
  const float thr = m2 - (fabsf(m2) * 1e-5f + 1e-6f);
  __syncthreads();                    // ps is reused below

  // ---- pass 2: exact (score,index) top-3 among s >= thr, first-occurrence ties ----
  float c0=-3.4e38f, c1=-3.4e38f, c2=-3.4e38f;
  int   e0=0x7fffffff, e1=0x7fffffff, e2=0x7fffffff;
  #pragma unroll 4
  for (int p = 0; p < CHSZ/2; ++p) {
    f32x2 X2 = cp2[p*4+0], Y2 = cp2[p*4+1], Z2 = cp2[p*4+2], W2 = cp2[p*4+3];
    f32x2 s = __builtin_elementwise_fma(X2, ux2,
              __builtin_elementwise_fma(Y2, uy2, Z2*uz2)) + W2;
    if (__builtin_expect(fmaxf(s.x, s.y) >= thr, 0)) {
      const int jj = jbase + 2*p;
      // exact insertion (below-thr member of the pair is harmless: strict > keeps order)
      TOP3_INS_IDX(c0, c1, c2, e0, e1, e2, s.x, jj);
      TOP3_INS_IDX(c0, c1, c2, e0, e1, e2, s.y, jj+1);
    }
  }
  ps[wave][lane][0]=c0; ps[wave][lane][1]=c1; ps[wave][lane][2]=c2;
  pi[wave][lane][0]=e0; pi[wave][lane][1]=e1; pi[wave][lane][2]=e2;
  __syncthreads();

  if (tid < 64) {   // wave 0: lane == query; merge chunks in ascending index order
    float f0=-3.4e38f, f1=-3.4e38f, f2=-3.4e38f;
    int   x0=0x7fffffff, x1=0x7fffffff, x2=0x7fffffff;
    #pragma unroll
    for (int c = 0; c < NCHUNK; ++c)
      #pragma unroll
      for (int r = 0; r < 3; ++r) {
        float s = ps[c][tid][r]; int jj = pi[c][tid][r];
        TOP3_INS_IDX(f0, f1, f2, x0, x1, x2, s, jj);
      }
    if (x0 > MK-1) x0 = 0;     // safety net (thr guarantees >=3 hits)
    if (x1 > MK-1) x1 = x0;
    if (x2 > MK-1) x2 = x1;
    float d0 = sqrtf(fmaxf(nu - 2.f*f0, 0.f)) + 1e-10f;
    float d1 = sqrtf(fmaxf(nu - 2.f*f1, 0.f)) + 1e-10f;
    float d2 = sqrtf(fmaxf(nu - 2.f*f2, 0.f)) + 1e-10f;
    float r0 = 1.f/d0, r1 = 1.f/d1, r2 = 1.f/d2;
    float rs = 1.f/(r0 + r1 + r2);
    size_t p = (size_t)b * NQ + q;
    widx[p*3+0] = x0;    widx[p*3+1] = x1;    widx[p*3+2] = x2;
    wwgt[p*3+0] = r0*rs; wwgt[p*3+1] = r1*rs; wwgt[p*3+2] = r2*rs;
  }
}

// ---------- 3. interpolate + concat -> X [65536][384] bf16 ----------
__global__ __launch_bounds__(256)
void interp_kernel(const float* __restrict__ kf, const float* __restrict__ uf,
                   const int* __restrict__ widx, const float* __restrict__ wwgt,
                   unsigned short* __restrict__ X) {
  const int p = blockIdx.x * 4 + (threadIdx.x >> 6);
  const int lane = threadIdx.x & 63;
  const int b = p >> 13, q = p & 8191;
  const int*   ip = widx + (size_t)p * 3;
  const float* wp = wwgt + (size_t)p * 3;
  int   j0 = ip[0], j1 = ip[1], j2 = ip[2];
  float w0 = wp[0], w1 = wp[1], w2 = wp[2];
  const float4* f0 = (const float4*)(kf + ((size_t)b*MK + j0) * C2v);
  const float4* f1 = (const float4*)(kf + ((size_t)b*MK + j1) * C2v);
  const float4* f2 = (const float4*)(kf + ((size_t)b*MK + j2) * C2v);
  float4 a = f0[lane], c = f1[lane], d = f2[lane];
  unsigned short* xr = X + (size_t)p * CIN;
  us4 v;
  v[0] = f2bf(w0*a.x + w1*c.x + w2*d.x);
  v[1] = f2bf(w0*a.y + w1*c.y + w2*d.y);
  v[2] = f2bf(w0*a.z + w1*c.z + w2*d.z);
  v[3] = f2bf(w0*a.w + w1*c.w + w2*d.w);
  *(us4*)(xr + lane*4) = v;
  float2 uu = *(const float2*)(uf + ((size_t)b*NQ + q) * C1v + lane*2);
  us2 w; w[0] = f2bf(uu.x); w[1] = f2bf(uu.y);
  *(us2*)(xr + C2v + lane*2) = w;
}

// ---------- 4. GEMM: Y[M][256] = A[M][K] * Bw[256][K]^T + bias, + BN stats ----------
// 1-D grid of 1024, pair-swizzled so (bm,0) and (bm,1) land on the same XCD
// (wid and wid+8 share wid%8) 8 dispatches apart -> A panel L2-hit on 2nd read.
template<int K, bool OUT_BF16>
__global__ __launch_bounds__(256)
void gemm_kernel(const unsigned short* __restrict__ A,
                 const unsigned short* __restrict__ Bw,
                 const float* __restrict__ bias,
                 void* __restrict__ Out,
                 float* __restrict__ gsum, float* __restrict__ gsq) {
  __shared__ unsigned short As[128][64];   // 16 KB
  __shared__ unsigned short Bs[128][64];   // 16 KB
  const int tid  = threadIdx.x;
  const int lane = tid & 63;
  const int wave = tid >> 6;          // 0..3
  const int wid  = blockIdx.x;
  const int slot = wid & 15;
  const int bm = ((wid >> 4) << 3) | (slot & 7);
  const int bn = slot >> 3;
  const int wm = wave >> 1, wn = wave & 1;

  f32x4 acc[4][4];
  const f32x4 zero = {0.f, 0.f, 0.f, 0.f};
  #pragma unroll
  for (int m = 0; m < 4; ++m)
    #pragma unroll
    for (int n = 0; n < 4; ++n) acc[m][n] = zero;

  for (int k0 = 0; k0 < K; k0 += 64) {
    #pragma unroll
    for (int i = 0; i < 4; ++i) {
      const int cbase = wave*64 + i*256;          // wave-uniform chunk base
      const int c = cbase + lane;                 // per-lane chunk (16 B)
      const int row = c >> 3, col = (c & 7) * 8;
      gload16(A  + ((size_t)(bm*128 + row))*K + k0 + col, (unsigned short*)As + cbase*8);
      gload16(Bw + ((size_t)(bn*128 + row))*K + k0 + col, (unsigned short*)Bs + cbase*8);
    }
    __syncthreads();
    const int kq = (lane >> 4) * 8;
    #pragma unroll
    for (int kk = 0; kk < 64; kk += 32) {
      bf16x8 af[4], bfr[4];
      #pragma unroll
      for (int m = 0; m < 4; ++m)
        af[m] = *(const bf16x8*)&As[wm*64 + m*16 + (lane & 15)][kk + kq];
      #pragma unroll
      for (int n = 0; n < 4; ++n)
        bfr[n] = *(const bf16x8*)&Bs[wn*64 + n*16 + (lane & 15)][kk + kq];
      #pragma unroll
      for (int m = 0; m < 4; ++m)
        #pragma unroll
        for (int n = 0; n < 4; ++n)
          acc[m][n] = __builtin_amdgcn_mfma_f32_16x16x32_bf16(af[m], bfr[n], acc[m][n], 0, 0, 0);
    }
    __syncthreads();
  }

  // epilogue: bias, store, per-channel sum/sumsq
  float* s_sum = (float*)&As[0][0];   // [2][128]
  float* s_sq  = s_sum + 256;         // [2][128]
  #pragma unroll
  for (int n = 0; n < 4; ++n) {
    const int cb   = wn*64 + n*16 + (lane & 15);
    const int gcol = bn*128 + cb;
    const float bv = bias[gcol];
    float sum = 0.f, sq = 0.f;
    #pragma unroll
    for (int m = 0; m < 4; ++m) {
      const size_t grow = (size_t)bm*128 + wm*64 + m*16 + (lane >> 4)*4;
      #pragma unroll
      for (int qq = 0; qq < 4; ++qq) {
        float y = acc[m][n][qq] + bv;
        sum += y; sq += y*y;
        if (OUT_BF16) ((unsigned short*)Out)[(grow+qq)*256 + gcol] = f2bf(y);
        else          ((float*)Out)[(grow+qq)*256 + gcol] = y;
      }
    }
    sum += __shfl_xor(sum, 16, 64); sum += __shfl_xor(sum, 32, 64);
    sq  += __shfl_xor(sq , 16, 64); sq  += __shfl_xor(sq , 32, 64);
    if (lane < 16) { s_sum[wm*128 + cb] = sum; s_sq[wm*128 + cb] = sq; }
  }
  __syncthreads();
  if (tid < 128) {
    atomicAdd(&gsum[bn*128 + tid], s_sum[tid] + s_sum[128 + tid]);
    atomicAdd(&gsq [bn*128 + tid], s_sq [tid] + s_sq [128 + tid]);
  }
}

// ---------- 5. BN stats finalize: scale/shift ----------
__global__ __launch_bounds__(256)
void stats_fin(const float* __restrict__ gsum, const float* __restrict__ gsq,
               const float* __restrict__ g, const float* __restrict__ beta,
               float* __restrict__ scale, float* __restrict__ shift) {
  int c = threadIdx.x;
  float mu  = gsum[c] * (1.f/65536.f);
  float var = gsq[c]  * (1.f/65536.f) - mu*mu;
  float sc  = g[c] * rsqrtf(var + 1e-5f);
  scale[c] = sc;
  shift[c] = beta[c] - mu*sc;
}

// ---------- 6. BN+ReLU elementwise (bf16 -> bf16) ----------
__global__ __launch_bounds__(256)
void bnrelu_kernel(const unsigned short* __restrict__ Y,
                   const float* __restrict__ scale, const float* __restrict__ shift,
                   unsigned short* __restrict__ Z) {
  __shared__ float sc[256], sh[256];
  if (threadIdx.x < 256) { sc[threadIdx.x] = scale[threadIdx.x]; sh[threadIdx.x] = shift[threadIdx.x]; }
  __syncthreads();
  size_t i = ((size_t)blockIdx.x * 256 + threadIdx.x) * 8;
  int c0 = (int)(i & 255);
  us8 v = *(const us8*)(Y + i);
  us8 o;
  #pragma unroll
  for (int j = 0; j < 8; ++j) {
    float y = bf2f(v[j]) * sc[c0+j] + sh[c0+j];
    o[j] = f2bf(fmaxf(y, 0.f));
  }
  *(us8*)(Z + i) = o;
}

// ---------- 7. final BN+ReLU: bf16 y2 -> fp32 d_out ----------
__global__ __launch_bounds__(256)
void final_kernel(const unsigned short* __restrict__ Y2, float* __restrict__ Out,
                  const float* __restrict__ scale, const float* __restrict__ shift) {
  __shared__ float sc[256], sh[256];
  if (threadIdx.x < 256) { sc[threadIdx.x] = scale[threadIdx.x]; sh[threadIdx.x] = shift[threadIdx.x]; }
  __syncthreads();
  size_t i = ((size_t)blockIdx.x * 256 + threadIdx.x) * 8;
  int c0 = (int)(i & 255);
  us8 v = *(const us8*)(Y2 + i);
  float4 o1, o2;
  o1.x = fmaxf(fmaf(bf2f(v[0]), sc[c0+0], sh[c0+0]), 0.f);
  o1.y = fmaxf(fmaf(bf2f(v[1]), sc[c0+1], sh[c0+1]), 0.f);
  o1.z = fmaxf(fmaf(bf2f(v[2]), sc[c0+2], sh[c0+2]), 0.f);
  o1.w = fmaxf(fmaf(bf2f(v[3]), sc[c0+3], sh[c0+3]), 0.f);
  o2.x = fmaxf(fmaf(bf2f(v[4]), sc[c0+4], sh[c0+4]), 0.f);
  o2.y = fmaxf(fmaf(bf2f(v[5]), sc[c0+5], sh[c0+5]), 0.f);
  o2.z = fmaxf(fmaf(bf2f(v[6]), sc[c0+6], sh[c0+6]), 0.f);
  o2.w = fmaxf(fmaf(bf2f(v[7]), sc[c0+7], sh[c0+7]), 0.f);
  *(float4*)(Out + i)     = o1;
  *(float4*)(Out + i + 4) = o2;
}

// ---------- launch ----------
extern "C" void kernel_launch(void* const* d_in, const int* in_sizes, int n_in,
                              void* d_out, int out_size, void* d_ws, size_t ws_size,
                              hipStream_t stream) {
  const float* unknown = (const float*)d_in[0];
  const float* known   = (const float*)d_in[1];
  const float* uf      = (const float*)d_in[2];
  const float* kf      = (const float*)d_in[3];
  const float* W1      = (const float*)d_in[4];
  const float* b1      = (const float*)d_in[5];
  const float* g1      = (const float*)d_in[6];
  const float* be1     = (const float*)d_in[7];
  const float* W2      = (const float*)d_in[8];
  const float* b2      = (const float*)d_in[9];
  const float* g2      = (const float*)d_in[10];
  const float* be2     = (const float*)d_in[11];

  char* ws = (char*)d_ws;
  unsigned short* X    = (unsigned short*)(ws);                 // 65536*384*2 = 50,331,648
  unsigned short* Y1   = (unsigned short*)(ws + 50331648);      // 65536*256*2 = 33,554,432 (y1, then y2)
  unsigned short* w1b  = (unsigned short*)(ws + 83886080);      // 196,608
  unsigned short* w2b  = (unsigned short*)(ws + 84082688);      // 131,072
  int*            widx = (int*)  (ws + 84213760);               // 786,432
  float*          wwgt = (float*)(ws + 85000192);               // 786,432
  float*          stats= (float*)(ws + 85786624);               // 8 KB
  float*          kprep= (float*)(ws + 85794816);               // 8*2048*16 = 262,144
  float *sum1 = stats,        *sq1 = stats + 256;
  float *sum2 = stats + 512,  *sq2 = stats + 768;
  float *scale1 = stats + 1024, *shift1 = stats + 1280;
  float *scale2 = stats + 1536, *shift2 = stats + 1792;
  float* out = (float*)d_out;

  prep_kernel<<<708, 256, 0, stream>>>(W1, W2, known, w1b, w2b, stats, kprep);
  nn_kernel<<<dim3(128, 8), 512, 0, stream>>>(unknown, kprep, widx, wwgt);
  interp_kernel<<<16384, 256, 0, stream>>>(kf, uf, widx, wwgt, X);
  gemm_kernel<CIN, true ><<<1024, 256, 0, stream>>>(X, w1b, b1, Y1, sum1, sq1);
  stats_fin<<<1, 256, 0, stream>>>(sum1, sq1, g1, be1, scale1, shift1);
  bnrelu_kernel<<<8192, 256, 0, stream>>>(Y1, scale1, shift1, X);   // X reused as layer-2 input
  gemm_kernel<HH, true ><<<1024, 256, 0, stream>>>(X, w2b, b2, Y1, sum2, sq2);  // y2 bf16 into Y1
  stats_fin<<<1, 256, 0, stream>>>(sum2, sq2, g2, be2, scale2, shift2);
  final_kernel<<<8192, 256, 0, stream>>>(Y1, out, scale2, shift2);
}

// Round 8
// 178.649 us; speedup vs baseline: 1.2488x; 1.0499x over previous
//
#include <hip/hip_runtime.h>

// ---------- problem constants ----------
#define BQ   8
#define NQ   8192      // unknown points per batch
#define MK   2048      // known points per batch
#define C1v  128
#define C2v  256
#define CIN  384
#define HH   256
#define MTOT (BQ*NQ)   // 65536

#define NCHUNK 8       // candidate chunks per nn block (= waves per block)
#define CHSZ   (MK/NCHUNK)   // 256 candidates per chunk

typedef __attribute__((ext_vector_type(8))) __bf16 bf16x8;
typedef __attribute__((ext_vector_type(4))) float f32x4;
typedef __attribute__((ext_vector_type(8))) unsigned short us8;
typedef __attribute__((ext_vector_type(4))) unsigned short us4;
typedef __attribute__((ext_vector_type(2))) unsigned short us2;

__device__ __forceinline__ unsigned short f2bf(float f) {
  unsigned int u = __builtin_bit_cast(unsigned int, f);
  u += 0x7fffu + ((u >> 16) & 1u);           // round-to-nearest-even
  return (unsigned short)(u >> 16);
}
__device__ __forceinline__ float bf2f(unsigned short h) {
  unsigned int u = ((unsigned int)h) << 16;
  return __builtin_bit_cast(float, u);
}

__device__ __forceinline__ void gload16(const void* g, void* l) {
  __builtin_amdgcn_global_load_lds((const __attribute__((address_space(1))) void*)g,
                                   (__attribute__((address_space(3))) void*)l, 16, 0, 0);
}

// 4-op top-3 insert network: {s0,s1,s2} <- top3 of {s0,s1,s2,s}
#define TOP3_INS(s0, s1, s2, s)                        \
  do {                                                 \
    float _mn = fminf(fminf(s0, s1), (s));             \
    s2 = fmaxf(s2, _mn);                               \
    s1 = __builtin_amdgcn_fmed3f(s0, s1, (s));         \
    s0 = fmaxf(s0, (s));                               \
  } while (0)

// (score,index) insert, strict > so earlier index wins ties (top_k semantics)
#define TOP3_INS_IDX(c0, c1, c2, e0, e1, e2, s, jj)                  \
  do {                                                               \
    const bool g0 = (s) > c0, g1 = (s) > c1, g2 = (s) > c2;          \
    c2 = g1 ? c1 : (g2 ? (s) : c2);  e2 = g1 ? e1 : (g2 ? (jj) : e2);\
    c1 = g0 ? c0 : (g1 ? (s) : c1);  e1 = g0 ? e0 : (g1 ? (jj) : e1);\
    c0 = g0 ? (s) : c0;              e0 = g0 ? (jj) : e0;            \
  } while (0)

// score from a staged candidate: s = u.k - 0.5|k|^2  (kprep.w = -0.5|k|^2)
#define SCORE(k4) (fmaf((k4).x, ux, fmaf((k4).y, uy, (k4).z * uz)) + (k4).w)

// ---------- 1. prep: W->bf16, zero BN accumulators, stage kprep ----------
__global__ __launch_bounds__(256)
void prep_kernel(const float* __restrict__ W1, const float* __restrict__ W2,
                 const float* __restrict__ known,
                 unsigned short* __restrict__ w1b, unsigned short* __restrict__ w2b,
                 float* __restrict__ stats, float4* __restrict__ kprep) {
  int i = blockIdx.x * 256 + threadIdx.x;
  if (i < HH*CIN) w1b[i] = f2bf(W1[i]);
  else if (i < HH*CIN + HH*HH) w2b[i - HH*CIN] = f2bf(W2[i - HH*CIN]);
  int z = i - (HH*CIN + HH*HH);
  if (z >= 0 && z < 1024) stats[z] = 0.f;
  int z2 = i - (HH*CIN + HH*HH + 1024);
  if (z2 >= 0 && z2 < BQ*MK) {
    const float* kp = known + (size_t)z2 * 3;
    float x = kp[0], y = kp[1], zz = kp[2];
    kprep[z2] = make_float4(x, y, zz, -0.5f*(x*x + y*y + zz*zz));
  }
}

// ---------- 2. three_nn: 8 waves/block, scalar-path loads (round-6 proven) ----------
__global__ __launch_bounds__(512)
void nn_kernel(const float* __restrict__ unknown, const float4* __restrict__ kprep,
               int* __restrict__ widx, float* __restrict__ wwgt) {
  __shared__ float ps[NCHUNK][64][3];       // per-chunk triples (scores)
  __shared__ int   pi[NCHUNK][64][3];       // per-chunk triples (indices)
  const int b = blockIdx.y;
  const int tid = threadIdx.x;
  const int wave = tid >> 6, lane = tid & 63;

  const int q = blockIdx.x * 64 + lane;
  const float* up = unknown + ((size_t)b * NQ + q) * 3;
  const float ux = up[0], uy = up[1], uz = up[2];
  const float nu = ux*ux + uy*uy + uz*uz;
  const int jbase = wave * CHSZ;
  // wave-uniform chunk pointer -> scalar-path candidate fetch
  const float4* cp = kprep + (b << 11) + __builtin_amdgcn_readfirstlane(jbase);

  // ---- pass 1: chunk-local top-3 scores (threshold only; no bit-match needed) ----
  float A0=-3.4e38f, A1=-3.4e38f, A2=-3.4e38f;
  float B0=-3.4e38f, B1=-3.4e38f, B2=-3.4e38f;
  #pragma unroll 4
  for (int j = 0; j < CHSZ; j += 2) {
    float4 ka = cp[j];
    float4 kc = cp[j+1];
    float sA = SCORE(ka);
    float sB = SCORE(kc);
    TOP3_INS(A0, A1, A2, sA);
    TOP3_INS(B0, B1, B2, sB);
  }
  TOP3_INS(A0, A1, A2, B0);
  TOP3_INS(A0, A1, A2, B1);
  TOP3_INS(A0, A1, A2, B2);
  ps[wave][lane][0] = A0; ps[wave][lane][1] = A1; ps[wave][lane][2] = A2;
  __syncthreads();

  // ---- global 3rd-best score for this lane's query (redundant per wave) ----
  float m0=-3.4e38f, m1=-3.4e38f, m2=-3.4e38f;
  #pragma unroll
  for (int c = 0; c < NCHUNK; ++c)
    #pragma unroll
    for (int r = 0; r < 3; ++r) {
      float s = ps[c][lane][r];
      TOP3_INS(m0, m1, m2, s);
    }
  // relaxed threshold: tolerates pass1-vs-pass2 rounding drift; exactness
  // comes from the pass-2 insertion, not from this cutoff
  const float thr = m2 - (fabsf(m2) * 1e-5f + 1e-6f);
  __syncthreads();                    // ps is reused below

  // ---- pass 2: exact (score,index) top-3 among s >= thr, first-occurrence ties ----
  float c0=-3.4e38f, c1=-3.4e38f, c2=-3.4e38f;
  int   e0=0x7fffffff, e1=0x7fffffff, e2=0x7fffffff;
  #pragma unroll 4
  for (int j = 0; j < CHSZ; ++j) {
    float4 k4 = cp[j];
    float s = SCORE(k4);
    if (__builtin_expect(s >= thr, 0)) {
      const int jj = jbase + j;
      TOP3_INS_IDX(c0, c1, c2, e0, e1, e2, s, jj);
    }
  }
  ps[wave][lane][0]=c0; ps[wave][lane][1]=c1; ps[wave][lane][2]=c2;
  pi[wave][lane][0]=e0; pi[wave][lane][1]=e1; pi[wave][lane][2]=e2;
  __syncthreads();

  if (tid < 64) {   // wave 0: lane == query; merge chunks in ascending index order
    float f0=-3.4e38f, f1=-3.4e38f, f2=-3.4e38f;
    int   x0=0x7fffffff, x1=0x7fffffff, x2=0x7fffffff;
    #pragma unroll
    for (int c = 0; c < NCHUNK; ++c)
      #pragma unroll
      for (int r = 0; r < 3; ++r) {
        float s = ps[c][tid][r]; int jj = pi[c][tid][r];
        TOP3_INS_IDX(f0, f1, f2, x0, x1, x2, s, jj);
      }
    if (x0 > MK-1) x0 = 0;     // safety net (thr guarantees >=3 hits)
    if (x1 > MK-1) x1 = x0;
    if (x2 > MK-1) x2 = x1;
    float d0 = sqrtf(fmaxf(nu - 2.f*f0, 0.f)) + 1e-10f;
    float d1 = sqrtf(fmaxf(nu - 2.f*f1, 0.f)) + 1e-10f;
    float d2 = sqrtf(fmaxf(nu - 2.f*f2, 0.f)) + 1e-10f;
    float r0 = 1.f/d0, r1 = 1.f/d1, r2 = 1.f/d2;
    float rs = 1.f/(r0 + r1 + r2);
    size_t p = (size_t)b * NQ + q;
    widx[p*3+0] = x0;    widx[p*3+1] = x1;    widx[p*3+2] = x2;
    wwgt[p*3+0] = r0*rs; wwgt[p*3+1] = r1*rs; wwgt[p*3+2] = r2*rs;
  }
}

// ---------- 3. interpolate + concat -> X [65536][384] bf16 ----------
__global__ __launch_bounds__(256)
void interp_kernel(const float* __restrict__ kf, const float* __restrict__ uf,
                   const int* __restrict__ widx, const float* __restrict__ wwgt,
                   unsigned short* __restrict__ X) {
  const int p = blockIdx.x * 4 + (threadIdx.x >> 6);
  const int lane = threadIdx.x & 63;
  const int b = p >> 13, q = p & 8191;
  const int*   ip = widx + (size_t)p * 3;
  const float* wp = wwgt + (size_t)p * 3;
  int   j0 = ip[0], j1 = ip[1], j2 = ip[2];
  float w0 = wp[0], w1 = wp[1], w2 = wp[2];
  const float4* f0 = (const float4*)(kf + ((size_t)b*MK + j0) * C2v);
  const float4* f1 = (const float4*)(kf + ((size_t)b*MK + j1) * C2v);
  const float4* f2 = (const float4*)(kf + ((size_t)b*MK + j2) * C2v);
  float4 a = f0[lane], c = f1[lane], d = f2[lane];
  unsigned short* xr = X + (size_t)p * CIN;
  us4 v;
  v[0] = f2bf(w0*a.x + w1*c.x + w2*d.x);
  v[1] = f2bf(w0*a.y + w1*c.y + w2*d.y);
  v[2] = f2bf(w0*a.z + w1*c.z + w2*d.z);
  v[3] = f2bf(w0*a.w + w1*c.w + w2*d.w);
  *(us4*)(xr + lane*4) = v;
  float2 uu = *(const float2*)(uf + ((size_t)b*NQ + q) * C1v + lane*2);
  us2 w; w[0] = f2bf(uu.x); w[1] = f2bf(uu.y);
  *(us2*)(xr + C2v + lane*2) = w;
}

// ---------- 4. GEMM: Y[M][256] = A[M][K] * Bw[256][K]^T + bias, + BN stats ----------
// FUSE_BN: A is raw y1 (bf16); apply scale/shift + ReLU during reg-staged A load.
// 1-D grid of 1024, pair-swizzled so (bm,0) and (bm,1) share an XCD (wid%8).
template<int K, bool FUSE_BN, bool OUT_BF16>
__global__ __launch_bounds__(256)
void gemm_kernel(const unsigned short* __restrict__ A,
                 const unsigned short* __restrict__ Bw,
                 const float* __restrict__ bias,
                 void* __restrict__ Out,
                 float* __restrict__ gsum, float* __restrict__ gsq,
                 const float* __restrict__ scf, const float* __restrict__ shf) {
  __shared__ unsigned short As[128][64];   // 16 KB
  __shared__ unsigned short Bs[128][64];   // 16 KB
  __shared__ float sc_l[HH], sh_l[HH];     // 2 KB (FUSE_BN only)
  const int tid  = threadIdx.x;
  const int lane = tid & 63;
  const int wave = tid >> 6;          // 0..3
  const int wid  = blockIdx.x;
  const int slot = wid & 15;
  const int bm = ((wid >> 4) << 3) | (slot & 7);
  const int bn = slot >> 3;
  const int wm = wave >> 1, wn = wave & 1;

  if (FUSE_BN) {
    sc_l[tid] = scf[tid]; sh_l[tid] = shf[tid];
    __syncthreads();
  }

  f32x4 acc[4][4];
  const f32x4 zero = {0.f, 0.f, 0.f, 0.f};
  #pragma unroll
  for (int m = 0; m < 4; ++m)
    #pragma unroll
    for (int n = 0; n < 4; ++n) acc[m][n] = zero;

  for (int k0 = 0; k0 < K; k0 += 64) {
    #pragma unroll
    for (int i = 0; i < 4; ++i) {
      const int cbase = wave*64 + i*256;          // wave-uniform chunk base
      const int c = cbase + lane;                 // per-lane chunk (16 B)
      const int row = c >> 3, col = (c & 7) * 8;
      gload16(Bw + ((size_t)(bn*128 + row))*K + k0 + col, (unsigned short*)Bs + cbase*8);
      if (FUSE_BN) {
        us8 v = *(const us8*)(A + ((size_t)(bm*128 + row))*K + k0 + col);
        us8 o;
        #pragma unroll
        for (int j = 0; j < 8; ++j) {
          float y = fmaxf(fmaf(bf2f(v[j]), sc_l[k0+col+j], sh_l[k0+col+j]), 0.f);
          o[j] = f2bf(y);
        }
        *(us8*)((unsigned short*)As + cbase*8 + lane*8) = o;
      } else {
        gload16(A + ((size_t)(bm*128 + row))*K + k0 + col, (unsigned short*)As + cbase*8);
      }
    }
    __syncthreads();
    const int kq = (lane >> 4) * 8;
    #pragma unroll
    for (int kk = 0; kk < 64; kk += 32) {
      bf16x8 af[4], bfr[4];
      #pragma unroll
      for (int m = 0; m < 4; ++m)
        af[m] = *(const bf16x8*)&As[wm*64 + m*16 + (lane & 15)][kk + kq];
      #pragma unroll
      for (int n = 0; n < 4; ++n)
        bfr[n] = *(const bf16x8*)&Bs[wn*64 + n*16 + (lane & 15)][kk + kq];
      #pragma unroll
      for (int m = 0; m < 4; ++m)
        #pragma unroll
        for (int n = 0; n < 4; ++n)
          acc[m][n] = __builtin_amdgcn_mfma_f32_16x16x32_bf16(af[m], bfr[n], acc[m][n], 0, 0, 0);
    }
    __syncthreads();
  }

  // epilogue: bias, store, per-channel sum/sumsq
  float* s_sum = (float*)&As[0][0];   // [2][128]
  float* s_sq  = s_sum + 256;         // [2][128]
  #pragma unroll
  for (int n = 0; n < 4; ++n) {
    const int cb   = wn*64 + n*16 + (lane & 15);
    const int gcol = bn*128 + cb;
    const float bv = bias[gcol];
    float sum = 0.f, sq = 0.f;
    #pragma unroll
    for (int m = 0; m < 4; ++m) {
      const size_t grow = (size_t)bm*128 + wm*64 + m*16 + (lane >> 4)*4;
      #pragma unroll
      for (int qq = 0; qq < 4; ++qq) {
        float y = acc[m][n][qq] + bv;
        sum += y; sq += y*y;
        if (OUT_BF16) ((unsigned short*)Out)[(grow+qq)*256 + gcol] = f2bf(y);
        else          ((float*)Out)[(grow+qq)*256 + gcol] = y;
      }
    }
    sum += __shfl_xor(sum, 16, 64); sum += __shfl_xor(sum, 32, 64);
    sq  += __shfl_xor(sq , 16, 64); sq  += __shfl_xor(sq , 32, 64);
    if (lane < 16) { s_sum[wm*128 + cb] = sum; s_sq[wm*128 + cb] = sq; }
  }
  __syncthreads();
  if (tid < 128) {
    atomicAdd(&gsum[bn*128 + tid], s_sum[tid] + s_sum[128 + tid]);
    atomicAdd(&gsq [bn*128 + tid], s_sq [tid] + s_sq [128 + tid]);
  }
}

// ---------- 5. BN stats finalize: scale/shift ----------
__global__ __launch_bounds__(256)
void stats_fin(const float* __restrict__ gsum, const float* __restrict__ gsq,
               const float* __restrict__ g, const float* __restrict__ beta,
               float* __restrict__ scale, float* __restrict__ shift) {
  int c = threadIdx.x;
  float mu  = gsum[c] * (1.f/65536.f);
  float var = gsq[c]  * (1.f/65536.f) - mu*mu;
  float sc  = g[c] * rsqrtf(var + 1e-5f);
  scale[c] = sc;
  shift[c] = beta[c] - mu*sc;
}

// ---------- 6. final BN+ReLU: bf16 y2 -> fp32 d_out ----------
__global__ __launch_bounds__(256)
void final_kernel(const unsigned short* __restrict__ Y2, float* __restrict__ Out,
                  const float* __restrict__ scale, const float* __restrict__ shift) {
  __shared__ float sc[256], sh[256];
  if (threadIdx.x < 256) { sc[threadIdx.x] = scale[threadIdx.x]; sh[threadIdx.x] = shift[threadIdx.x]; }
  __syncthreads();
  size_t i = ((size_t)blockIdx.x * 256 + threadIdx.x) * 8;
  int c0 = (int)(i & 255);
  us8 v = *(const us8*)(Y2 + i);
  float4 o1, o2;
  o1.x = fmaxf(fmaf(bf2f(v[0]), sc[c0+0], sh[c0+0]), 0.f);
  o1.y = fmaxf(fmaf(bf2f(v[1]), sc[c0+1], sh[c0+1]), 0.f);
  o1.z = fmaxf(fmaf(bf2f(v[2]), sc[c0+2], sh[c0+2]), 0.f);
  o1.w = fmaxf(fmaf(bf2f(v[3]), sc[c0+3], sh[c0+3]), 0.f);
  o2.x = fmaxf(fmaf(bf2f(v[4]), sc[c0+4], sh[c0+4]), 0.f);
  o2.y = fmaxf(fmaf(bf2f(v[5]), sc[c0+5], sh[c0+5]), 0.f);
  o2.z = fmaxf(fmaf(bf2f(v[6]), sc[c0+6], sh[c0+6]), 0.f);
  o2.w = fmaxf(fmaf(bf2f(v[7]), sc[c0+7], sh[c0+7]), 0.f);
  *(float4*)(Out + i)     = o1;
  *(float4*)(Out + i + 4) = o2;
}

// ---------- launch ----------
extern "C" void kernel_launch(void* const* d_in, const int* in_sizes, int n_in,
                              void* d_out, int out_size, void* d_ws, size_t ws_size,
                              hipStream_t stream) {
  const float* unknown = (const float*)d_in[0];
  const float* known   = (const float*)d_in[1];
  const float* uf      = (const float*)d_in[2];
  const float* kf      = (const float*)d_in[3];
  const float* W1      = (const float*)d_in[4];
  const float* b1      = (const float*)d_in[5];
  const float* g1      = (const float*)d_in[6];
  const float* be1     = (const float*)d_in[7];
  const float* W2      = (const float*)d_in[8];
  const float* b2      = (const float*)d_in[9];
  const float* g2      = (const float*)d_in[10];
  const float* be2     = (const float*)d_in[11];

  char* ws = (char*)d_ws;
  unsigned short* X    = (unsigned short*)(ws);                 // 50,331,648 (x, then y2)
  unsigned short* Y1   = (unsigned short*)(ws + 50331648);      // 33,554,432 (y1 raw)
  unsigned short* w1b  = (unsigned short*)(ws + 83886080);      // 196,608
  unsigned short* w2b  = (unsigned short*)(ws + 84082688);      // 131,072
  int*            widx = (int*)  (ws + 84213760);               // 786,432
  float*          wwgt = (float*)(ws + 85000192);               // 786,432
  float*          stats= (float*)(ws + 85786624);               // 8 KB
  float4*         kprep= (float4*)(ws + 85794816);              // 262,144
  float *sum1 = stats,        *sq1 = stats + 256;
  float *sum2 = stats + 512,  *sq2 = stats + 768;
  float *scale1 = stats + 1024, *shift1 = stats + 1280;
  float *scale2 = stats + 1536, *shift2 = stats + 1792;
  float* out = (float*)d_out;

  prep_kernel<<<708, 256, 0, stream>>>(W1, W2, known, w1b, w2b, stats, kprep);
  nn_kernel<<<dim3(128, 8), 512, 0, stream>>>(unknown, kprep, widx, wwgt);
  interp_kernel<<<16384, 256, 0, stream>>>(kf, uf, widx, wwgt, X);
  gemm_kernel<CIN, false, true><<<1024, 256, 0, stream>>>(X, w1b, b1, Y1, sum1, sq1, nullptr, nullptr);
  stats_fin<<<1, 256, 0, stream>>>(sum1, sq1, g1, be1, scale1, shift1);
  // gemm2: reads raw y1 with fused BN1+ReLU on the A-path, writes y2 (bf16) into X
  gemm_kernel<HH, true, true><<<1024, 256, 0, stream>>>(Y1, w2b, b2, X, sum2, sq2, scale1, shift1);
  stats_fin<<<1, 256, 0, stream>>>(sum2, sq2, g2, be2, scale2, shift2);
  final_kernel<<<8192, 256, 0, stream>>>(X, out, scale2, shift2);
}

// Round 10
// 172.992 us; speedup vs baseline: 1.2896x; 1.0327x over previous
//
#include <hip/hip_runtime.h>

// ---------- problem constants ----------
#define BQ   8
#define NQ   8192      // unknown points per batch
#define MK   2048      // known points per batch
#define C1v  128
#define C2v  256
#define CIN  384
#define HH   256
#define MTOT (BQ*NQ)   // 65536

#define NCHUNK 8       // candidate chunks per nn block (= waves per block)
#define CHSZ   (MK/NCHUNK)   // 256 candidates per chunk

typedef __attribute__((ext_vector_type(8))) __bf16 bf16x8;
typedef __attribute__((ext_vector_type(4))) float f32x4;
typedef __attribute__((ext_vector_type(8))) unsigned short us8;
typedef __attribute__((ext_vector_type(4))) unsigned short us4;
typedef __attribute__((ext_vector_type(2))) unsigned short us2;

__device__ __forceinline__ unsigned short f2bf(float f) {
  unsigned int u = __builtin_bit_cast(unsigned int, f);
  u += 0x7fffu + ((u >> 16) & 1u);           // round-to-nearest-even
  return (unsigned short)(u >> 16);
}
__device__ __forceinline__ float bf2f(unsigned short h) {
  unsigned int u = ((unsigned int)h) << 16;
  return __builtin_bit_cast(float, u);
}

__device__ __forceinline__ void gload16(const void* g, void* l) {
  __builtin_amdgcn_global_load_lds((const __attribute__((address_space(1))) void*)g,
                                   (__attribute__((address_space(3))) void*)l, 16, 0, 0);
}

// score from a staged candidate: s = u.k - 0.5|k|^2  (kprep.w = -0.5|k|^2)
#define SCORE(k4) (fmaf((k4).x, ux, fmaf((k4).y, uy, (k4).z * uz)) + (k4).w)

// pack fp32 score + candidate index into one exactly-ordered f64 key:
// (double)s has 29 zero low mantissa bits; OR in (2047-j). Distinct fp32
// scores keep exact order; equal scores tie-break to smaller j (top_k rule).
__device__ __forceinline__ double packsd(float s, int negj) {
  unsigned long long u = __builtin_bit_cast(unsigned long long, (double)s)
                       | (unsigned long long)(unsigned int)negj;
  return __builtin_bit_cast(double, u);
}

// 5-op f64 top-3 insert (keys are all distinct): {s0,s1,s2} <- top3 of {s0,s1,s2,t}
#define INS3D(s0, s1, s2, t)                                  \
  do {                                                        \
    double _hi0 = fmax(s0, (t)), _lo0 = fmin(s0, (t));        \
    double _hi1 = fmax(s1, _lo0), _lo1 = fmin(s1, _lo0);      \
    s0 = _hi0; s1 = _hi1; s2 = fmax(s2, _lo1);                \
  } while (0)

// ---------- 1. prep: W->bf16, zero BN accumulators, stage kprep ----------
__global__ __launch_bounds__(256)
void prep_kernel(const float* __restrict__ W1, const float* __restrict__ W2,
                 const float* __restrict__ known,
                 unsigned short* __restrict__ w1b, unsigned short* __restrict__ w2b,
                 float* __restrict__ stats, float4* __restrict__ kprep) {
  int i = blockIdx.x * 256 + threadIdx.x;
  if (i < HH*CIN) w1b[i] = f2bf(W1[i]);
  else if (i < HH*CIN + HH*HH) w2b[i - HH*CIN] = f2bf(W2[i - HH*CIN]);
  int z = i - (HH*CIN + HH*HH);
  if (z >= 0 && z < 1024) stats[z] = 0.f;
  int z2 = i - (HH*CIN + HH*HH + 1024);
  if (z2 >= 0 && z2 < BQ*MK) {
    const float* kp = known + (size_t)z2 * 3;
    float x = kp[0], y = kp[1], zz = kp[2];
    kprep[z2] = make_float4(x, y, zz, -0.5f*(x*x + y*y + zz*zz));
  }
}

// ---------- 2. three_nn: single pass, index-packed f64 keys ----------
__global__ __launch_bounds__(512)
void nn_kernel(const float* __restrict__ unknown, const float4* __restrict__ kprep,
               int* __restrict__ widx, float* __restrict__ wwgt) {
  __shared__ double pd[NCHUNK][64][3];      // per-chunk packed triples (12 KB)
  const int b = blockIdx.y;
  const int tid = threadIdx.x;
  const int wave = tid >> 6, lane = tid & 63;

  const int q = blockIdx.x * 64 + lane;
  const float* up = unknown + ((size_t)b * NQ + q) * 3;
  const float ux = up[0], uy = up[1], uz = up[2];
  const float nu = ux*ux + uy*uy + uz*uz;
  const int jbase = wave * CHSZ;
  // wave-uniform chunk pointer -> scalar-path candidate fetch
  const float4* cp = kprep + (b << 11) + __builtin_amdgcn_readfirstlane(jbase);

  // dual accumulator sets for ILP; keys are distinct so merge order is free
  double A0=-1e300, A1=-1e300, A2=-1e300;
  double B0=-1e300, B1=-1e300, B2=-1e300;
  #pragma unroll 4
  for (int j = 0; j < CHSZ; j += 2) {
    float4 ka = cp[j];
    float4 kc = cp[j+1];
    float sA = SCORE(ka);
    float sB = SCORE(kc);
    double da = packsd(sA, 2047 - (jbase + j));
    double db = packsd(sB, 2047 - (jbase + j + 1));
    INS3D(A0, A1, A2, da);
    INS3D(B0, B1, B2, db);
  }
  INS3D(A0, A1, A2, B0);
  INS3D(A0, A1, A2, B1);
  INS3D(A0, A1, A2, B2);
  pd[wave][lane][0] = A0; pd[wave][lane][1] = A1; pd[wave][lane][2] = A2;
  __syncthreads();

  if (tid < 64) {   // wave 0: lane == query; merge the 8 chunk triples
    double f0=-1e300, f1=-1e300, f2=-1e300;
    #pragma unroll
    for (int c = 0; c < NCHUNK; ++c) {
      INS3D(f0, f1, f2, pd[c][tid][0]);
      INS3D(f0, f1, f2, pd[c][tid][1]);
      INS3D(f0, f1, f2, pd[c][tid][2]);
    }
    unsigned long long u0 = __builtin_bit_cast(unsigned long long, f0);
    unsigned long long u1 = __builtin_bit_cast(unsigned long long, f1);
    unsigned long long u2 = __builtin_bit_cast(unsigned long long, f2);
    int x0 = 2047 - (int)(u0 & 2047ULL);
    int x1 = 2047 - (int)(u1 & 2047ULL);
    int x2 = 2047 - (int)(u2 & 2047ULL);
    // masking restores the exact fp32 score bits
    float s0 = (float)__builtin_bit_cast(double, u0 & ~2047ULL);
    float s1 = (float)__builtin_bit_cast(double, u1 & ~2047ULL);
    float s2 = (float)__builtin_bit_cast(double, u2 & ~2047ULL);
    float d0 = sqrtf(fmaxf(nu - 2.f*s0, 0.f)) + 1e-10f;
    float d1 = sqrtf(fmaxf(nu - 2.f*s1, 0.f)) + 1e-10f;
    float d2 = sqrtf(fmaxf(nu - 2.f*s2, 0.f)) + 1e-10f;
    float r0 = 1.f/d0, r1 = 1.f/d1, r2 = 1.f/d2;
    float rs = 1.f/(r0 + r1 + r2);
    size_t p = (size_t)b * NQ + q;
    widx[p*3+0] = x0;    widx[p*3+1] = x1;    widx[p*3+2] = x2;
    wwgt[p*3+0] = r0*rs; wwgt[p*3+1] = r1*rs; wwgt[p*3+2] = r2*rs;
  }
}

// ---------- 3. interpolate + concat -> X [65536][384] bf16 ----------
__global__ __launch_bounds__(256)
void interp_kernel(const float* __restrict__ kf, const float* __restrict__ uf,
                   const int* __restrict__ widx, const float* __restrict__ wwgt,
                   unsigned short* __restrict__ X) {
  const int p = blockIdx.x * 4 + (threadIdx.x >> 6);
  const int lane = threadIdx.x & 63;
  const int b = p >> 13, q = p & 8191;
  const int*   ip = widx + (size_t)p * 3;
  const float* wp = wwgt + (size_t)p * 3;
  int   j0 = ip[0], j1 = ip[1], j2 = ip[2];
  float w0 = wp[0], w1 = wp[1], w2 = wp[2];
  const float4* f0 = (const float4*)(kf + ((size_t)b*MK + j0) * C2v);
  const float4* f1 = (const float4*)(kf + ((size_t)b*MK + j1) * C2v);
  const float4* f2 = (const float4*)(kf + ((size_t)b*MK + j2) * C2v);
  float4 a = f0[lane], c = f1[lane], d = f2[lane];
  unsigned short* xr = X + (size_t)p * CIN;
  us4 v;
  v[0] = f2bf(w0*a.x + w1*c.x + w2*d.x);
  v[1] = f2bf(w0*a.y + w1*c.y + w2*d.y);
  v[2] = f2bf(w0*a.z + w1*c.z + w2*d.z);
  v[3] = f2bf(w0*a.w + w1*c.w + w2*d.w);
  *(us4*)(xr + lane*4) = v;
  float2 uu = *(const float2*)(uf + ((size_t)b*NQ + q) * C1v + lane*2);
  us2 w; w[0] = f2bf(uu.x); w[1] = f2bf(uu.y);
  *(us2*)(xr + C2v + lane*2) = w;
}

// ---------- 4. GEMM1: Y1[M][256] = X[M][384] * W1^T + b1, + BN1 stats ----------
__global__ __launch_bounds__(256)
void gemm_kernel(const unsigned short* __restrict__ A,
                 const unsigned short* __restrict__ Bw,
                 const float* __restrict__ bias,
                 unsigned short* __restrict__ Out,
                 float* __restrict__ gsum, float* __restrict__ gsq) {
  constexpr int K = CIN;
  __shared__ unsigned short As[128][64];   // 16 KB
  __shared__ unsigned short Bs[128][64];   // 16 KB
  const int tid  = threadIdx.x;
  const int lane = tid & 63;
  const int wave = tid >> 6;          // 0..3
  const int wid  = blockIdx.x;
  const int slot = wid & 15;
  const int bm = ((wid >> 4) << 3) | (slot & 7);
  const int bn = slot >> 3;
  const int wm = wave >> 1, wn = wave & 1;

  f32x4 acc[4][4];
  const f32x4 zero = {0.f, 0.f, 0.f, 0.f};
  #pragma unroll
  for (int m = 0; m < 4; ++m)
    #pragma unroll
    for (int n = 0; n < 4; ++n) acc[m][n] = zero;

  for (int k0 = 0; k0 < K; k0 += 64) {
    #pragma unroll
    for (int i = 0; i < 4; ++i) {
      const int cbase = wave*64 + i*256;          // wave-uniform chunk base
      const int c = cbase + lane;                 // per-lane chunk (16 B)
      const int row = c >> 3, col = (c & 7) * 8;
      gload16(Bw + ((size_t)(bn*128 + row))*K + k0 + col, (unsigned short*)Bs + cbase*8);
      gload16(A  + ((size_t)(bm*128 + row))*K + k0 + col, (unsigned short*)As + cbase*8);
    }
    __syncthreads();
    const int kq = (lane >> 4) * 8;
    #pragma unroll
    for (int kk = 0; kk < 64; kk += 32) {
      bf16x8 af[4], bfr[4];
      #pragma unroll
      for (int m = 0; m < 4; ++m)
        af[m] = *(const bf16x8*)&As[wm*64 + m*16 + (lane & 15)][kk + kq];
      #pragma unroll
      for (int n = 0; n < 4; ++n)
        bfr[n] = *(const bf16x8*)&Bs[wn*64 + n*16 + (lane & 15)][kk + kq];
      #pragma unroll
      for (int m = 0; m < 4; ++m)
        #pragma unroll
        for (int n = 0; n < 4; ++n)
          acc[m][n] = __builtin_amdgcn_mfma_f32_16x16x32_bf16(af[m], bfr[n], acc[m][n], 0, 0, 0);
    }
    __syncthreads();
  }

  // epilogue: bias, store bf16, per-channel sum/sumsq
  float* s_sum = (float*)&As[0][0];   // [2][128]
  float* s_sq  = s_sum + 256;         // [2][128]
  #pragma unroll
  for (int n = 0; n < 4; ++n) {
    const int cb   = wn*64 + n*16 + (lane & 15);
    const int gcol = bn*128 + cb;
    const float bv = bias[gcol];
    float sum = 0.f, sq = 0.f;
    #pragma unroll
    for (int m = 0; m < 4; ++m) {
      const size_t grow = (size_t)bm*128 + wm*64 + m*16 + (lane >> 4)*4;
      #pragma unroll
      for (int qq = 0; qq < 4; ++qq) {
        float y = acc[m][n][qq] + bv;
        sum += y; sq += y*y;
        Out[(grow+qq)*256 + gcol] = f2bf(y);
      }
    }
    sum += __shfl_xor(sum, 16, 64); sum += __shfl_xor(sum, 32, 64);
    sq  += __shfl_xor(sq , 16, 64); sq  += __shfl_xor(sq , 32, 64);
    if (lane < 16) { s_sum[wm*128 + cb] = sum; s_sq[wm*128 + cb] = sq; }
  }
  __syncthreads();
  if (tid < 128) {
    atomicAdd(&gsum[bn*128 + tid], s_sum[tid] + s_sum[128 + tid]);
    atomicAdd(&gsq [bn*128 + tid], s_sq [tid] + s_sq [128 + tid]);
  }
}

// ---------- 5. GEMM2: fused BN1+ReLU on A-load (scale/shift computed in preamble
// from raw sums), y2 bf16 out, + BN2 stats ----------
__global__ __launch_bounds__(256)
void gemm2_kernel(const unsigned short* __restrict__ A,     // y1 raw bf16
                  const unsigned short* __restrict__ Bw,    // W2 bf16
                  const float* __restrict__ bias,           // b2
                  unsigned short* __restrict__ Out,         // y2 bf16
                  float* __restrict__ gsum, float* __restrict__ gsq,     // BN2 accum
                  const float* __restrict__ gsum1, const float* __restrict__ gsq1,
                  const float* __restrict__ g1, const float* __restrict__ be1) {
  constexpr int K = HH;
  __shared__ unsigned short As[128][64];   // 16 KB
  __shared__ unsigned short Bs[128][64];   // 16 KB
  __shared__ float sc_l[HH], sh_l[HH];     // 2 KB
  const int tid  = threadIdx.x;
  const int lane = tid & 63;
  const int wave = tid >> 6;          // 0..3
  const int wid  = blockIdx.x;
  const int slot = wid & 15;
  const int bm = ((wid >> 4) << 3) | (slot & 7);
  const int bn = slot >> 3;
  const int wm = wave >> 1, wn = wave & 1;

  {  // BN1 finalize (redundant per block; replaces stats_fin dispatch)
    float mu  = gsum1[tid] * (1.f/65536.f);
    float var = gsq1[tid]  * (1.f/65536.f) - mu*mu;
    float sc  = g1[tid] * rsqrtf(var + 1e-5f);
    sc_l[tid] = sc;
    sh_l[tid] = be1[tid] - mu*sc;
  }
  __syncthreads();

  f32x4 acc[4][4];
  const f32x4 zero = {0.f, 0.f, 0.f, 0.f};
  #pragma unroll
  for (int m = 0; m < 4; ++m)
    #pragma unroll
    for (int n = 0; n < 4; ++n) acc[m][n] = zero;

  for (int k0 = 0; k0 < K; k0 += 64) {
    #pragma unroll
    for (int i = 0; i < 4; ++i) {
      const int cbase = wave*64 + i*256;          // wave-uniform chunk base
      const int c = cbase + lane;                 // per-lane chunk (16 B)
      const int row = c >> 3, col = (c & 7) * 8;
      gload16(Bw + ((size_t)(bn*128 + row))*K + k0 + col, (unsigned short*)Bs + cbase*8);
      us8 v = *(const us8*)(A + ((size_t)(bm*128 + row))*K + k0 + col);
      us8 o;
      #pragma unroll
      for (int j = 0; j < 8; ++j) {
        float y = fmaxf(fmaf(bf2f(v[j]), sc_l[k0+col+j], sh_l[k0+col+j]), 0.f);
        o[j] = f2bf(y);
      }
      *(us8*)((unsigned short*)As + cbase*8 + lane*8) = o;
    }
    __syncthreads();
    const int kq = (lane >> 4) * 8;
    #pragma unroll
    for (int kk = 0; kk < 64; kk += 32) {
      bf16x8 af[4], bfr[4];
      #pragma unroll
      for (int m = 0; m < 4; ++m)
        af[m] = *(const bf16x8*)&As[wm*64 + m*16 + (lane & 15)][kk + kq];
      #pragma unroll
      for (int n = 0; n < 4; ++n)
        bfr[n] = *(const bf16x8*)&Bs[wn*64 + n*16 + (lane & 15)][kk + kq];
      #pragma unroll
      for (int m = 0; m < 4; ++m)
        #pragma unroll
        for (int n = 0; n < 4; ++n)
          acc[m][n] = __builtin_amdgcn_mfma_f32_16x16x32_bf16(af[m], bfr[n], acc[m][n], 0, 0, 0);
    }
    __syncthreads();
  }

  // epilogue: bias, store bf16 y2, per-channel sum/sumsq
  float* s_sum = (float*)&As[0][0];   // [2][128]
  float* s_sq  = s_sum + 256;         // [2][128]
  #pragma unroll
  for (int n = 0; n < 4; ++n) {
    const int cb   = wn*64 + n*16 + (lane & 15);
    const int gcol = bn*128 + cb;
    const float bv = bias[gcol];
    float sum = 0.f, sq = 0.f;
    #pragma unroll
    for (int m = 0; m < 4; ++m) {
      const size_t grow = (size_t)bm*128 + wm*64 + m*16 + (lane >> 4)*4;
      #pragma unroll
      for (int qq = 0; qq < 4; ++qq) {
        float y = acc[m][n][qq] + bv;
        sum += y; sq += y*y;
        Out[(grow+qq)*256 + gcol] = f2bf(y);
      }
    }
    sum += __shfl_xor(sum, 16, 64); sum += __shfl_xor(sum, 32, 64);
    sq  += __shfl_xor(sq , 16, 64); sq  += __shfl_xor(sq , 32, 64);
    if (lane < 16) { s_sum[wm*128 + cb] = sum; s_sq[wm*128 + cb] = sq; }
  }
  __syncthreads();
  if (tid < 128) {
    atomicAdd(&gsum[bn*128 + tid], s_sum[tid] + s_sum[128 + tid]);
    atomicAdd(&gsq [bn*128 + tid], s_sq [tid] + s_sq [128 + tid]);
  }
}

// ---------- 6. final BN2+ReLU: bf16 y2 -> fp32 d_out (scale/shift in preamble) ----------
__global__ __launch_bounds__(256)
void final_kernel(const unsigned short* __restrict__ Y2, float* __restrict__ Out,
                  const float* __restrict__ gsum, const float* __restrict__ gsq,
                  const float* __restrict__ g2, const float* __restrict__ be2) {
  __shared__ float sc[256], sh[256];
  {  // BN2 finalize (redundant per block; replaces stats_fin dispatch)
    float mu  = gsum[threadIdx.x] * (1.f/65536.f);
    float var = gsq[threadIdx.x]  * (1.f/65536.f) - mu*mu;
    float scv = g2[threadIdx.x] * rsqrtf(var + 1e-5f);
    sc[threadIdx.x] = scv;
    sh[threadIdx.x] = be2[threadIdx.x] - mu*scv;
  }
  __syncthreads();
  size_t i = ((size_t)blockIdx.x * 256 + threadIdx.x) * 8;
  int c0 = (int)(i & 255);
  us8 v = *(const us8*)(Y2 + i);
  float4 o1, o2;
  o1.x = fmaxf(fmaf(bf2f(v[0]), sc[c0+0], sh[c0+0]), 0.f);
  o1.y = fmaxf(fmaf(bf2f(v[1]), sc[c0+1], sh[c0+1]), 0.f);
  o1.z = fmaxf(fmaf(bf2f(v[2]), sc[c0+2], sh[c0+2]), 0.f);
  o1.w = fmaxf(fmaf(bf2f(v[3]), sc[c0+3], sh[c0+3]), 0.f);
  o2.x = fmaxf(fmaf(bf2f(v[4]), sc[c0+4], sh[c0+4]), 0.f);
  o2.y = fmaxf(fmaf(bf2f(v[5]), sc[c0+5], sh[c0+5]), 0.f);
  o2.z = fmaxf(fmaf(bf2f(v[6]), sc[c0+6], sh[c0+6]), 0.f);
  o2.w = fmaxf(fmaf(bf2f(v[7]), sc[c0+7], sh[c0+7]), 0.f);
  *(float4*)(Out + i)     = o1;
  *(float4*)(Out + i + 4) = o2;
}

// ---------- launch ----------
extern "C" void kernel_launch(void* const* d_in, const int* in_sizes, int n_in,
                              void* d_out, int out_size, void* d_ws, size_t ws_size,
                              hipStream_t stream) {
  const float* unknown = (const float*)d_in[0];
  const float* known   = (const float*)d_in[1];
  const float* uf      = (const float*)d_in[2];
  const float* kf      = (const float*)d_in[3];
  const float* W1      = (const float*)d_in[4];
  const float* b1      = (const float*)d_in[5];
  const float* g1      = (const float*)d_in[6];
  const float* be1     = (const float*)d_in[7];
  const float* W2      = (const float*)d_in[8];
  const float* b2      = (const float*)d_in[9];
  const float* g2      = (const float*)d_in[10];
  const float* be2     = (const float*)d_in[11];

  char* ws = (char*)d_ws;
  unsigned short* X    = (unsigned short*)(ws);                 // 50,331,648 (x, then y2)
  unsigned short* Y1   = (unsigned short*)(ws + 50331648);      // 33,554,432 (y1 raw)
  unsigned short* w1b  = (unsigned short*)(ws + 83886080);      // 196,608
  unsigned short* w2b  = (unsigned short*)(ws + 84082688);      // 131,072
  int*            widx = (int*)  (ws + 84213760);               // 786,432
  float*          wwgt = (float*)(ws + 85000192);               // 786,432
  float*          stats= (float*)(ws + 85786624);               // 8 KB
  float4*         kprep= (float4*)(ws + 85794816);              // 262,144
  float *sum1 = stats,        *sq1 = stats + 256;
  float *sum2 = stats + 512,  *sq2 = stats + 768;
  float* out = (float*)d_out;

  prep_kernel<<<708, 256, 0, stream>>>(W1, W2, known, w1b, w2b, stats, kprep);
  nn_kernel<<<dim3(128, 8), 512, 0, stream>>>(unknown, kprep, widx, wwgt);
  interp_kernel<<<16384, 256, 0, stream>>>(kf, uf, widx, wwgt, X);
  gemm_kernel<<<1024, 256, 0, stream>>>(X, w1b, b1, Y1, sum1, sq1);
  // gemm2: BN1 finalized in-kernel from raw sums; fused BN1+ReLU on A; y2 -> X
  gemm2_kernel<<<1024, 256, 0, stream>>>(Y1, w2b, b2, X, sum2, sq2, sum1, sq1, g1, be1);
  // final: BN2 finalized in-kernel from raw sums; bf16 y2 -> fp32 d_out
  final_kernel<<<8192, 256, 0, stream>>>(X, out, sum2, sq2, g2, be2);
}

// Round 11
// 163.262 us; speedup vs baseline: 1.3664x; 1.0596x over previous
//
#include <hip/hip_runtime.h>

// ---------- problem constants ----------
#define BQ   8
#define NQ   8192      // unknown points per batch
#define MK   2048      // known points per batch
#define C1v  128
#define C2v  256
#define CIN  384
#define HH   256
#define MTOT (BQ*NQ)   // 65536

#define NCHUNK 8       // candidate chunks per nn block (= waves per block)
#define CHSZ   (MK/NCHUNK)   // 256 candidates per chunk

typedef __attribute__((ext_vector_type(8))) __bf16 bf16x8;
typedef __attribute__((ext_vector_type(4))) float f32x4;
typedef __attribute__((ext_vector_type(8))) unsigned short us8;
typedef __attribute__((ext_vector_type(4))) unsigned short us4;
typedef __attribute__((ext_vector_type(2))) unsigned short us2;

__device__ __forceinline__ unsigned short f2bf(float f) {
  unsigned int u = __builtin_bit_cast(unsigned int, f);
  u += 0x7fffu + ((u >> 16) & 1u);           // round-to-nearest-even
  return (unsigned short)(u >> 16);
}
__device__ __forceinline__ float bf2f(unsigned short h) {
  unsigned int u = ((unsigned int)h) << 16;
  return __builtin_bit_cast(float, u);
}

__device__ __forceinline__ void gload16(const void* g, void* l) {
  __builtin_amdgcn_global_load_lds((const __attribute__((address_space(1))) void*)g,
                                   (__attribute__((address_space(3))) void*)l, 16, 0, 0);
}

// packed f32->bf16 RNE convert (dst.lo = src0, dst.hi = src1)
__device__ __forceinline__ unsigned int cvtpk_bf16(float lo, float hi) {
  unsigned int r;
  asm("v_cvt_pk_bf16_f32 %0, %1, %2" : "=v"(r) : "v"(lo), "v"(hi));
  return r;
}

// score from a staged candidate: s = u.k - 0.5|k|^2  (kprep.w = -0.5|k|^2)
#define SCORE(k4) (fmaf((k4).x, ux, fmaf((k4).y, uy, (k4).z * uz)) + (k4).w)

// pack fp32 score + candidate index into one exactly-ordered f64 key:
// (double)s has 29 zero low mantissa bits; OR in (2047-j). Distinct fp32
// scores keep exact order; equal scores tie-break to smaller j (top_k rule).
__device__ __forceinline__ double packsd(float s, int negj) {
  unsigned long long u = __builtin_bit_cast(unsigned long long, (double)s)
                       | (unsigned long long)(unsigned int)negj;
  return __builtin_bit_cast(double, u);
}

// 5-op f64 top-3 insert (keys are all distinct): {s0,s1,s2} <- top3 of {s0,s1,s2,t}
#define INS3D(s0, s1, s2, t)                                  \
  do {                                                        \
    double _hi0 = fmax(s0, (t)), _lo0 = fmin(s0, (t));        \
    double _hi1 = fmax(s1, _lo0), _lo1 = fmin(s1, _lo0);      \
    s0 = _hi0; s1 = _hi1; s2 = fmax(s2, _lo1);                \
  } while (0)

// ---------- 1. prep: W->bf16, zero BN accumulators, stage kprep ----------
__global__ __launch_bounds__(256)
void prep_kernel(const float* __restrict__ W1, const float* __restrict__ W2,
                 const float* __restrict__ known,
                 unsigned short* __restrict__ w1b, unsigned short* __restrict__ w2b,
                 float* __restrict__ stats, float4* __restrict__ kprep) {
  int i = blockIdx.x * 256 + threadIdx.x;
  if (i < HH*CIN) w1b[i] = f2bf(W1[i]);
  else if (i < HH*CIN + HH*HH) w2b[i - HH*CIN] = f2bf(W2[i - HH*CIN]);
  int z = i - (HH*CIN + HH*HH);
  if (z >= 0 && z < 1024) stats[z] = 0.f;
  int z2 = i - (HH*CIN + HH*HH + 1024);
  if (z2 >= 0 && z2 < BQ*MK) {
    const float* kp = known + (size_t)z2 * 3;
    float x = kp[0], y = kp[1], zz = kp[2];
    kprep[z2] = make_float4(x, y, zz, -0.5f*(x*x + y*y + zz*zz));
  }
}

// ---------- 2. three_nn: single pass, index-packed f64 keys ----------
__global__ __launch_bounds__(512)
void nn_kernel(const float* __restrict__ unknown, const float4* __restrict__ kprep,
               int* __restrict__ widx, float* __restrict__ wwgt) {
  __shared__ double pd[NCHUNK][64][3];      // per-chunk packed triples (12 KB)
  const int b = blockIdx.y;
  const int tid = threadIdx.x;
  const int wave = tid >> 6, lane = tid & 63;

  const int q = blockIdx.x * 64 + lane;
  const float* up = unknown + ((size_t)b * NQ + q) * 3;
  const float ux = up[0], uy = up[1], uz = up[2];
  const float nu = ux*ux + uy*uy + uz*uz;
  const int jbase = wave * CHSZ;
  // wave-uniform chunk pointer -> scalar-path candidate fetch
  const float4* cp = kprep + (b << 11) + __builtin_amdgcn_readfirstlane(jbase);

  // dual accumulator sets for ILP; keys are distinct so merge order is free
  double A0=-1e300, A1=-1e300, A2=-1e300;
  double B0=-1e300, B1=-1e300, B2=-1e300;
  #pragma unroll 4
  for (int j = 0; j < CHSZ; j += 2) {
    float4 ka = cp[j];
    float4 kc = cp[j+1];
    float sA = SCORE(ka);
    float sB = SCORE(kc);
    double da = packsd(sA, 2047 - (jbase + j));
    double db = packsd(sB, 2047 - (jbase + j + 1));
    INS3D(A0, A1, A2, da);
    INS3D(B0, B1, B2, db);
  }
  INS3D(A0, A1, A2, B0);
  INS3D(A0, A1, A2, B1);
  INS3D(A0, A1, A2, B2);
  pd[wave][lane][0] = A0; pd[wave][lane][1] = A1; pd[wave][lane][2] = A2;
  __syncthreads();

  if (tid < 64) {   // wave 0: lane == query; merge the 8 chunk triples
    double f0=-1e300, f1=-1e300, f2=-1e300;
    #pragma unroll
    for (int c = 0; c < NCHUNK; ++c) {
      INS3D(f0, f1, f2, pd[c][tid][0]);
      INS3D(f0, f1, f2, pd[c][tid][1]);
      INS3D(f0, f1, f2, pd[c][tid][2]);
    }
    unsigned long long u0 = __builtin_bit_cast(unsigned long long, f0);
    unsigned long long u1 = __builtin_bit_cast(unsigned long long, f1);
    unsigned long long u2 = __builtin_bit_cast(unsigned long long, f2);
    int x0 = 2047 - (int)(u0 & 2047ULL);
    int x1 = 2047 - (int)(u1 & 2047ULL);
    int x2 = 2047 - (int)(u2 & 2047ULL);
    // masking restores the exact fp32 score bits
    float s0 = (float)__builtin_bit_cast(double, u0 & ~2047ULL);
    float s1 = (float)__builtin_bit_cast(double, u1 & ~2047ULL);
    float s2 = (float)__builtin_bit_cast(double, u2 & ~2047ULL);
    float d0 = sqrtf(fmaxf(nu - 2.f*s0, 0.f)) + 1e-10f;
    float d1 = sqrtf(fmaxf(nu - 2.f*s1, 0.f)) + 1e-10f;
    float d2 = sqrtf(fmaxf(nu - 2.f*s2, 0.f)) + 1e-10f;
    float r0 = 1.f/d0, r1 = 1.f/d1, r2 = 1.f/d2;
    float rs = 1.f/(r0 + r1 + r2);
    size_t p = (size_t)b * NQ + q;
    widx[p*3+0] = x0;    widx[p*3+1] = x1;    widx[p*3+2] = x2;
    wwgt[p*3+0] = r0*rs; wwgt[p*3+1] = r1*rs; wwgt[p*3+2] = r2*rs;
  }
}

// ---------- 3. GEMM1 (fused interp): A[p][k] built in-staging from
// gather+lerp (k<256) and uf concat (k>=256); Y1 bf16 out + BN1 stats ----------
__global__ __launch_bounds__(256)
void gemm1_fused(const float* __restrict__ kf, const float* __restrict__ uf,
                 const int* __restrict__ widx, const float* __restrict__ wwgt,
                 const unsigned short* __restrict__ Bw,
                 const float* __restrict__ bias,
                 unsigned short* __restrict__ Out,
                 float* __restrict__ gsum, float* __restrict__ gsq) {
  constexpr int K = CIN;
  __shared__ unsigned short As[128][64];   // 16 KB
  __shared__ unsigned short Bs[128][64];   // 16 KB
  const int tid  = threadIdx.x;
  const int lane = tid & 63;
  const int wave = tid >> 6;          // 0..3
  const int wid  = blockIdx.x;
  const int slot = wid & 15;
  const int bm = ((wid >> 4) << 3) | (slot & 7);
  const int bn = slot >> 3;
  const int wm = wave >> 1, wn = wave & 1;

  // prologue: per-chunk gather byte-offsets + weights (chunk i -> fixed row/col)
  unsigned int vo0[4], vo1[4], vo2[4], voU[4];
  float w0r[4], w1r[4], w2r[4];
  #pragma unroll
  for (int i = 0; i < 4; ++i) {
    const int c = wave*64 + i*256 + lane;
    const int row = c >> 3, colB = (c & 7) * 32;   // byte offset of col8*8 floats
    const int p = bm*128 + row;
    const int b = p >> 13;
    w0r[i] = wwgt[p*3+0]; w1r[i] = wwgt[p*3+1]; w2r[i] = wwgt[p*3+2];
    vo0[i] = ((unsigned)((b << 11) + widx[p*3+0]) << 10) + colB;  // kf row = 1024 B
    vo1[i] = ((unsigned)((b << 11) + widx[p*3+1]) << 10) + colB;
    vo2[i] = ((unsigned)((b << 11) + widx[p*3+2]) << 10) + colB;
    voU[i] = (unsigned)p * 512u + colB;                            // uf row = 512 B
  }

  f32x4 acc[4][4];
  const f32x4 zero = {0.f, 0.f, 0.f, 0.f};
  #pragma unroll
  for (int m = 0; m < 4; ++m)
    #pragma unroll
    for (int n = 0; n < 4; ++n) acc[m][n] = zero;

  const char* kfb = (const char*)kf;
  const char* ufb = (const char*)uf;

  #pragma unroll
  for (int t = 0; t < 6; ++t) {
    const int k0 = t * 64;
    #pragma unroll
    for (int i = 0; i < 4; ++i) {
      const int cbase = wave*64 + i*256;
      const int c = cbase + lane;
      const int brow = c >> 3, bcol = (c & 7) * 8;
      gload16(Bw + ((size_t)(bn*128 + brow))*K + k0 + bcol, (unsigned short*)Bs + cbase*8);
      float4 r0, r1;
      if (t < 4) {           // interp region: 3-way lerp of gathered kf rows
        float4 a0 = *(const float4*)(kfb + vo0[i] + k0*4);
        float4 a1 = *(const float4*)(kfb + vo0[i] + k0*4 + 16);
        float4 e0 = *(const float4*)(kfb + vo1[i] + k0*4);
        float4 e1 = *(const float4*)(kfb + vo1[i] + k0*4 + 16);
        float4 g0 = *(const float4*)(kfb + vo2[i] + k0*4);
        float4 g1 = *(const float4*)(kfb + vo2[i] + k0*4 + 16);
        const float w0 = w0r[i], w1 = w1r[i], w2 = w2r[i];
        r0.x = w0*a0.x + w1*e0.x + w2*g0.x;
        r0.y = w0*a0.y + w1*e0.y + w2*g0.y;
        r0.z = w0*a0.z + w1*e0.z + w2*g0.z;
        r0.w = w0*a0.w + w1*e0.w + w2*g0.w;
        r1.x = w0*a1.x + w1*e1.x + w2*g1.x;
        r1.y = w0*a1.y + w1*e1.y + w2*g1.y;
        r1.z = w0*a1.z + w1*e1.z + w2*g1.z;
        r1.w = w0*a1.w + w1*e1.w + w2*g1.w;
      } else {               // concat region: uf passthrough
        r0 = *(const float4*)(ufb + voU[i] + (k0 - 256)*4);
        r1 = *(const float4*)(ufb + voU[i] + (k0 - 256)*4 + 16);
      }
      uint4 ov;
      ov.x = cvtpk_bf16(r0.x, r0.y);
      ov.y = cvtpk_bf16(r0.z, r0.w);
      ov.z = cvtpk_bf16(r1.x, r1.y);
      ov.w = cvtpk_bf16(r1.z, r1.w);
      *(uint4*)((unsigned short*)As + (size_t)c*8) = ov;
    }
    __syncthreads();
    const int kq = (lane >> 4) * 8;
    #pragma unroll
    for (int kk = 0; kk < 64; kk += 32) {
      bf16x8 af[4], bfr[4];
      #pragma unroll
      for (int m = 0; m < 4; ++m)
        af[m] = *(const bf16x8*)&As[wm*64 + m*16 + (lane & 15)][kk + kq];
      #pragma unroll
      for (int n = 0; n < 4; ++n)
        bfr[n] = *(const bf16x8*)&Bs[wn*64 + n*16 + (lane & 15)][kk + kq];
      #pragma unroll
      for (int m = 0; m < 4; ++m)
        #pragma unroll
        for (int n = 0; n < 4; ++n)
          acc[m][n] = __builtin_amdgcn_mfma_f32_16x16x32_bf16(af[m], bfr[n], acc[m][n], 0, 0, 0);
    }
    __syncthreads();
  }

  // epilogue: bias, store bf16, per-channel sum/sumsq
  float* s_sum = (float*)&As[0][0];   // [2][128]
  float* s_sq  = s_sum + 256;         // [2][128]
  #pragma unroll
  for (int n = 0; n < 4; ++n) {
    const int cb   = wn*64 + n*16 + (lane & 15);
    const int gcol = bn*128 + cb;
    const float bv = bias[gcol];
    float sum = 0.f, sq = 0.f;
    #pragma unroll
    for (int m = 0; m < 4; ++m) {
      const size_t grow = (size_t)bm*128 + wm*64 + m*16 + (lane >> 4)*4;
      #pragma unroll
      for (int qq = 0; qq < 4; ++qq) {
        float y = acc[m][n][qq] + bv;
        sum += y; sq += y*y;
        Out[(grow+qq)*256 + gcol] = f2bf(y);
      }
    }
    sum += __shfl_xor(sum, 16, 64); sum += __shfl_xor(sum, 32, 64);
    sq  += __shfl_xor(sq , 16, 64); sq  += __shfl_xor(sq , 32, 64);
    if (lane < 16) { s_sum[wm*128 + cb] = sum; s_sq[wm*128 + cb] = sq; }
  }
  __syncthreads();
  if (tid < 128) {
    atomicAdd(&gsum[bn*128 + tid], s_sum[tid] + s_sum[128 + tid]);
    atomicAdd(&gsq [bn*128 + tid], s_sq [tid] + s_sq [128 + tid]);
  }
}

// ---------- 4. GEMM2: fused BN1+ReLU on A-load (scale/shift computed in preamble
// from raw sums), y2 bf16 out, + BN2 stats ----------
__global__ __launch_bounds__(256)
void gemm2_kernel(const unsigned short* __restrict__ A,     // y1 raw bf16
                  const unsigned short* __restrict__ Bw,    // W2 bf16
                  const float* __restrict__ bias,           // b2
                  unsigned short* __restrict__ Out,         // y2 bf16
                  float* __restrict__ gsum, float* __restrict__ gsq,     // BN2 accum
                  const float* __restrict__ gsum1, const float* __restrict__ gsq1,
                  const float* __restrict__ g1, const float* __restrict__ be1) {
  constexpr int K = HH;
  __shared__ unsigned short As[128][64];   // 16 KB
  __shared__ unsigned short Bs[128][64];   // 16 KB
  __shared__ float sc_l[HH], sh_l[HH];     // 2 KB
  const int tid  = threadIdx.x;
  const int lane = tid & 63;
  const int wave = tid >> 6;          // 0..3
  const int wid  = blockIdx.x;
  const int slot = wid & 15;
  const int bm = ((wid >> 4) << 3) | (slot & 7);
  const int bn = slot >> 3;
  const int wm = wave >> 1, wn = wave & 1;

  {  // BN1 finalize (redundant per block; replaces stats_fin dispatch)
    float mu  = gsum1[tid] * (1.f/65536.f);
    float var = gsq1[tid]  * (1.f/65536.f) - mu*mu;
    float sc  = g1[tid] * rsqrtf(var + 1e-5f);
    sc_l[tid] = sc;
    sh_l[tid] = be1[tid] - mu*sc;
  }
  __syncthreads();

  f32x4 acc[4][4];
  const f32x4 zero = {0.f, 0.f, 0.f, 0.f};
  #pragma unroll
  for (int m = 0; m < 4; ++m)
    #pragma unroll
    for (int n = 0; n < 4; ++n) acc[m][n] = zero;

  for (int k0 = 0; k0 < K; k0 += 64) {
    #pragma unroll
    for (int i = 0; i < 4; ++i) {
      const int cbase = wave*64 + i*256;          // wave-uniform chunk base
      const int c = cbase + lane;                 // per-lane chunk (16 B)
      const int row = c >> 3, col = (c & 7) * 8;
      gload16(Bw + ((size_t)(bn*128 + row))*K + k0 + col, (unsigned short*)Bs + cbase*8);
      us8 v = *(const us8*)(A + ((size_t)(bm*128 + row))*K + k0 + col);
      us8 o;
      #pragma unroll
      for (int j = 0; j < 8; ++j) {
        float y = fmaxf(fmaf(bf2f(v[j]), sc_l[k0+col+j], sh_l[k0+col+j]), 0.f);
        o[j] = f2bf(y);
      }
      *(us8*)((unsigned short*)As + cbase*8 + lane*8) = o;
    }
    __syncthreads();
    const int kq = (lane >> 4) * 8;
    #pragma unroll
    for (int kk = 0; kk < 64; kk += 32) {
      bf16x8 af[4], bfr[4];
      #pragma unroll
      for (int m = 0; m < 4; ++m)
        af[m] = *(const bf16x8*)&As[wm*64 + m*16 + (lane & 15)][kk + kq];
      #pragma unroll
      for (int n = 0; n < 4; ++n)
        bfr[n] = *(const bf16x8*)&Bs[wn*64 + n*16 + (lane & 15)][kk + kq];
      #pragma unroll
      for (int m = 0; m < 4; ++m)
        #pragma unroll
        for (int n = 0; n < 4; ++n)
          acc[m][n] = __builtin_amdgcn_mfma_f32_16x16x32_bf16(af[m], bfr[n], acc[m][n], 0, 0, 0);
    }
    __syncthreads();
  }

  // epilogue: bias, store bf16 y2, per-channel sum/sumsq
  float* s_sum = (float*)&As[0][0];   // [2][128]
  float* s_sq  = s_sum + 256;         // [2][128]
  #pragma unroll
  for (int n = 0; n < 4; ++n) {
    const int cb   = wn*64 + n*16 + (lane & 15);
    const int gcol = bn*128 + cb;
    const float bv = bias[gcol];
    float sum = 0.f, sq = 0.f;
    #pragma unroll
    for (int m = 0; m < 4; ++m) {
      const size_t grow = (size_t)bm*128 + wm*64 + m*16 + (lane >> 4)*4;
      #pragma unroll
      for (int qq = 0; qq < 4; ++qq) {
        float y = acc[m][n][qq] + bv;
        sum += y; sq += y*y;
        Out[(grow+qq)*256 + gcol] = f2bf(y);
      }
    }
    sum += __shfl_xor(sum, 16, 64); sum += __shfl_xor(sum, 32, 64);
    sq  += __shfl_xor(sq , 16, 64); sq  += __shfl_xor(sq , 32, 64);
    if (lane < 16) { s_sum[wm*128 + cb] = sum; s_sq[wm*128 + cb] = sq; }
  }
  __syncthreads();
  if (tid < 128) {
    atomicAdd(&gsum[bn*128 + tid], s_sum[tid] + s_sum[128 + tid]);
    atomicAdd(&gsq [bn*128 + tid], s_sq [tid] + s_sq [128 + tid]);
  }
}

// ---------- 5. final BN2+ReLU: bf16 y2 -> fp32 d_out (scale/shift in preamble) ----------
__global__ __launch_bounds__(256)
void final_kernel(const unsigned short* __restrict__ Y2, float* __restrict__ Out,
                  const float* __restrict__ gsum, const float* __restrict__ gsq,
                  const float* __restrict__ g2, const float* __restrict__ be2) {
  __shared__ float sc[256], sh[256];
  {  // BN2 finalize (redundant per block; replaces stats_fin dispatch)
    float mu  = gsum[threadIdx.x] * (1.f/65536.f);
    float var = gsq[threadIdx.x]  * (1.f/65536.f) - mu*mu;
    float scv = g2[threadIdx.x] * rsqrtf(var + 1e-5f);
    sc[threadIdx.x] = scv;
    sh[threadIdx.x] = be2[threadIdx.x] - mu*scv;
  }
  __syncthreads();
  size_t i = ((size_t)blockIdx.x * 256 + threadIdx.x) * 8;
  int c0 = (int)(i & 255);
  us8 v = *(const us8*)(Y2 + i);
  float4 o1, o2;
  o1.x = fmaxf(fmaf(bf2f(v[0]), sc[c0+0], sh[c0+0]), 0.f);
  o1.y = fmaxf(fmaf(bf2f(v[1]), sc[c0+1], sh[c0+1]), 0.f);
  o1.z = fmaxf(fmaf(bf2f(v[2]), sc[c0+2], sh[c0+2]), 0.f);
  o1.w = fmaxf(fmaf(bf2f(v[3]), sc[c0+3], sh[c0+3]), 0.f);
  o2.x = fmaxf(fmaf(bf2f(v[4]), sc[c0+4], sh[c0+4]), 0.f);
  o2.y = fmaxf(fmaf(bf2f(v[5]), sc[c0+5], sh[c0+5]), 0.f);
  o2.z = fmaxf(fmaf(bf2f(v[6]), sc[c0+6], sh[c0+6]), 0.f);
  o2.w = fmaxf(fmaf(bf2f(v[7]), sc[c0+7], sh[c0+7]), 0.f);
  *(float4*)(Out + i)     = o1;
  *(float4*)(Out + i + 4) = o2;
}

// ---------- launch ----------
extern "C" void kernel_launch(void* const* d_in, const int* in_sizes, int n_in,
                              void* d_out, int out_size, void* d_ws, size_t ws_size,
                              hipStream_t stream) {
  const float* unknown = (const float*)d_in[0];
  const float* known   = (const float*)d_in[1];
  const float* uf      = (const float*)d_in[2];
  const float* kf      = (const float*)d_in[3];
  const float* W1      = (const float*)d_in[4];
  const float* b1      = (const float*)d_in[5];
  const float* g1      = (const float*)d_in[6];
  const float* be1     = (const float*)d_in[7];
  const float* W2      = (const float*)d_in[8];
  const float* b2      = (const float*)d_in[9];
  const float* g2      = (const float*)d_in[10];
  const float* be2     = (const float*)d_in[11];

  char* ws = (char*)d_ws;
  unsigned short* X    = (unsigned short*)(ws);                 // 50,331,648 (y2 scratch)
  unsigned short* Y1   = (unsigned short*)(ws + 50331648);      // 33,554,432 (y1 raw)
  unsigned short* w1b  = (unsigned short*)(ws + 83886080);      // 196,608
  unsigned short* w2b  = (unsigned short*)(ws + 84082688);      // 131,072
  int*            widx = (int*)  (ws + 84213760);               // 786,432
  float*          wwgt = (float*)(ws + 85000192);               // 786,432
  float*          stats= (float*)(ws + 85786624);               // 8 KB
  float4*         kprep= (float4*)(ws + 85794816);              // 262,144
  float *sum1 = stats,        *sq1 = stats + 256;
  float *sum2 = stats + 512,  *sq2 = stats + 768;
  float* out = (float*)d_out;

  prep_kernel<<<708, 256, 0, stream>>>(W1, W2, known, w1b, w2b, stats, kprep);
  nn_kernel<<<dim3(128, 8), 512, 0, stream>>>(unknown, kprep, widx, wwgt);
  // gemm1 with fused interp+concat on the A-staging path (interp kernel deleted)
  gemm1_fused<<<1024, 256, 0, stream>>>(kf, uf, widx, wwgt, w1b, b1, Y1, sum1, sq1);
  // gemm2: BN1 finalized in-kernel from raw sums; fused BN1+ReLU on A; y2 -> X
  gemm2_kernel<<<1024, 256, 0, stream>>>(Y1, w2b, b2, X, sum2, sq2, sum1, sq1, g1, be1);
  // final: BN2 finalized in-kernel from raw sums; bf16 y2 -> fp32 d_out
  final_kernel<<<8192, 256, 0, stream>>>(X, out, sum2, sq2, g2, be2);
}

// Round 12
// 159.948 us; speedup vs baseline: 1.3948x; 1.0207x over previous
//
#include <hip/hip_runtime.h>

// ---------- problem constants ----------
#define BQ   8
#define NQ   8192      // unknown points per batch
#define MK   2048      // known points per batch
#define C1v  128
#define C2v  256
#define CIN  384
#define HH   256
#define MTOT (BQ*NQ)   // 65536

#define NCHUNK 8       // candidate chunks per nn block (= waves per block)
#define CHSZ   (MK/NCHUNK)   // 256 candidates per chunk

typedef __attribute__((ext_vector_type(8))) __bf16 bf16x8;
typedef __attribute__((ext_vector_type(4))) float f32x4;
typedef __attribute__((ext_vector_type(8))) unsigned short us8;
typedef __attribute__((ext_vector_type(4))) unsigned short us4;
typedef __attribute__((ext_vector_type(2))) unsigned short us2;

__device__ __forceinline__ unsigned short f2bf(float f) {
  unsigned int u = __builtin_bit_cast(unsigned int, f);
  u += 0x7fffu + ((u >> 16) & 1u);           // round-to-nearest-even
  return (unsigned short)(u >> 16);
}
__device__ __forceinline__ float bf2f(unsigned short h) {
  unsigned int u = ((unsigned int)h) << 16;
  return __builtin_bit_cast(float, u);
}

__device__ __forceinline__ void gload16(const void* g, void* l) {
  __builtin_amdgcn_global_load_lds((const __attribute__((address_space(1))) void*)g,
                                   (__attribute__((address_space(3))) void*)l, 16, 0, 0);
}

// packed f32->bf16 RNE convert (dst.lo = src0, dst.hi = src1)
__device__ __forceinline__ unsigned int cvtpk_bf16(float lo, float hi) {
  unsigned int r;
  asm("v_cvt_pk_bf16_f32 %0, %1, %2" : "=v"(r) : "v"(lo), "v"(hi));
  return r;
}

// score from a staged candidate: s = u.k - 0.5|k|^2  (kprep.w = -0.5|k|^2)
#define SCORE(k4) (fmaf((k4).x, ux, fmaf((k4).y, uy, (k4).z * uz)) + (k4).w)

// pack fp32 score + candidate index into one exactly-ordered f64 key:
// (double)s has 29 zero low mantissa bits; OR in (2047-j). Distinct fp32
// scores keep exact order; equal scores tie-break to smaller j (top_k rule).
__device__ __forceinline__ double packsd(float s, int negj) {
  unsigned long long u = __builtin_bit_cast(unsigned long long, (double)s)
                       | (unsigned long long)(unsigned int)negj;
  return __builtin_bit_cast(double, u);
}

// 5-op f64 top-3 insert (keys are all distinct): {s0,s1,s2} <- top3 of {s0,s1,s2,t}
#define INS3D(s0, s1, s2, t)                                  \
  do {                                                        \
    double _hi0 = fmax(s0, (t)), _lo0 = fmin(s0, (t));        \
    double _hi1 = fmax(s1, _lo0), _lo1 = fmin(s1, _lo0);      \
    s0 = _hi0; s1 = _hi1; s2 = fmax(s2, _lo1);                \
  } while (0)

// ---------- 1. prep: W->bf16, zero BN accumulators, stage kprep ----------
__global__ __launch_bounds__(256)
void prep_kernel(const float* __restrict__ W1, const float* __restrict__ W2,
                 const float* __restrict__ known,
                 unsigned short* __restrict__ w1b, unsigned short* __restrict__ w2b,
                 float* __restrict__ stats, float4* __restrict__ kprep) {
  int i = blockIdx.x * 256 + threadIdx.x;
  if (i < HH*CIN) w1b[i] = f2bf(W1[i]);
  else if (i < HH*CIN + HH*HH) w2b[i - HH*CIN] = f2bf(W2[i - HH*CIN]);
  int z = i - (HH*CIN + HH*HH);
  if (z >= 0 && z < 1024) stats[z] = 0.f;
  int z2 = i - (HH*CIN + HH*HH + 1024);
  if (z2 >= 0 && z2 < BQ*MK) {
    const float* kp = known + (size_t)z2 * 3;
    float x = kp[0], y = kp[1], zz = kp[2];
    kprep[z2] = make_float4(x, y, zz, -0.5f*(x*x + y*y + zz*zz));
  }
}

// ---------- 2. three_nn: single pass, index-packed f64 keys ----------
__global__ __launch_bounds__(512)
void nn_kernel(const float* __restrict__ unknown, const float4* __restrict__ kprep,
               int* __restrict__ widx, float* __restrict__ wwgt) {
  __shared__ double pd[NCHUNK][64][3];      // per-chunk packed triples (12 KB)
  const int b = blockIdx.y;
  const int tid = threadIdx.x;
  const int wave = tid >> 6, lane = tid & 63;

  const int q = blockIdx.x * 64 + lane;
  const float* up = unknown + ((size_t)b * NQ + q) * 3;
  const float ux = up[0], uy = up[1], uz = up[2];
  const float nu = ux*ux + uy*uy + uz*uz;
  const int jbase = wave * CHSZ;
  // wave-uniform chunk pointer -> scalar-path candidate fetch
  const float4* cp = kprep + (b << 11) + __builtin_amdgcn_readfirstlane(jbase);

  // dual accumulator sets for ILP; keys are distinct so merge order is free
  double A0=-1e300, A1=-1e300, A2=-1e300;
  double B0=-1e300, B1=-1e300, B2=-1e300;
  #pragma unroll 4
  for (int j = 0; j < CHSZ; j += 2) {
    float4 ka = cp[j];
    float4 kc = cp[j+1];
    float sA = SCORE(ka);
    float sB = SCORE(kc);
    double da = packsd(sA, 2047 - (jbase + j));
    double db = packsd(sB, 2047 - (jbase + j + 1));
    INS3D(A0, A1, A2, da);
    INS3D(B0, B1, B2, db);
  }
  INS3D(A0, A1, A2, B0);
  INS3D(A0, A1, A2, B1);
  INS3D(A0, A1, A2, B2);
  pd[wave][lane][0] = A0; pd[wave][lane][1] = A1; pd[wave][lane][2] = A2;
  __syncthreads();

  if (tid < 64) {   // wave 0: lane == query; merge the 8 chunk triples
    double f0=-1e300, f1=-1e300, f2=-1e300;
    #pragma unroll
    for (int c = 0; c < NCHUNK; ++c) {
      INS3D(f0, f1, f2, pd[c][tid][0]);
      INS3D(f0, f1, f2, pd[c][tid][1]);
      INS3D(f0, f1, f2, pd[c][tid][2]);
    }
    unsigned long long u0 = __builtin_bit_cast(unsigned long long, f0);
    unsigned long long u1 = __builtin_bit_cast(unsigned long long, f1);
    unsigned long long u2 = __builtin_bit_cast(unsigned long long, f2);
    int x0 = 2047 - (int)(u0 & 2047ULL);
    int x1 = 2047 - (int)(u1 & 2047ULL);
    int x2 = 2047 - (int)(u2 & 2047ULL);
    // masking restores the exact fp32 score bits
    float s0 = (float)__builtin_bit_cast(double, u0 & ~2047ULL);
    float s1 = (float)__builtin_bit_cast(double, u1 & ~2047ULL);
    float s2 = (float)__builtin_bit_cast(double, u2 & ~2047ULL);
    float d0 = sqrtf(fmaxf(nu - 2.f*s0, 0.f)) + 1e-10f;
    float d1 = sqrtf(fmaxf(nu - 2.f*s1, 0.f)) + 1e-10f;
    float d2 = sqrtf(fmaxf(nu - 2.f*s2, 0.f)) + 1e-10f;
    float r0 = 1.f/d0, r1 = 1.f/d1, r2 = 1.f/d2;
    float rs = 1.f/(r0 + r1 + r2);
    size_t p = (size_t)b * NQ + q;
    widx[p*3+0] = x0;    widx[p*3+1] = x1;    widx[p*3+2] = x2;
    wwgt[p*3+0] = r0*rs; wwgt[p*3+1] = r1*rs; wwgt[p*3+2] = r2*rs;
  }
}

// ---------- 3. GEMM1 (fused interp): A[p][k] built in-staging from
// gather+lerp (k<256) and uf concat (k>=256); Y1 bf16 out + BN1 stats.
// Block swizzle: batch = wid&7 -> all 128 blocks of a batch land on one XCD
// (wid%8 -> XCD round-robin), so the batch's 2 MB kf slab stays L2-resident.
__global__ __launch_bounds__(256)
void gemm1_fused(const float* __restrict__ kf, const float* __restrict__ uf,
                 const int* __restrict__ widx, const float* __restrict__ wwgt,
                 const unsigned short* __restrict__ Bw,
                 const float* __restrict__ bias,
                 unsigned short* __restrict__ Out,
                 float* __restrict__ gsum, float* __restrict__ gsq) {
  constexpr int K = CIN;
  __shared__ unsigned short As[128][64];   // 16 KB
  __shared__ unsigned short Bs[128][64];   // 16 KB
  const int tid  = threadIdx.x;
  const int lane = tid & 63;
  const int wave = tid >> 6;          // 0..3
  const int wid   = blockIdx.x;
  const int batch = wid & 7;          // -> XCD id
  const int inner = wid >> 3;         // 0..127 within batch
  const int bm = batch * 64 + (inner >> 1);
  const int bn = inner & 1;
  const int wm = wave >> 1, wn = wave & 1;

  // prologue: per-chunk gather byte-offsets + weights (chunk i -> fixed row/col)
  unsigned int vo0[4], vo1[4], vo2[4], voU[4];
  float w0r[4], w1r[4], w2r[4];
  #pragma unroll
  for (int i = 0; i < 4; ++i) {
    const int c = wave*64 + i*256 + lane;
    const int row = c >> 3, colB = (c & 7) * 32;   // byte offset of col8*8 floats
    const int p = bm*128 + row;
    const int b = p >> 13;
    w0r[i] = wwgt[p*3+0]; w1r[i] = wwgt[p*3+1]; w2r[i] = wwgt[p*3+2];
    vo0[i] = ((unsigned)((b << 11) + widx[p*3+0]) << 10) + colB;  // kf row = 1024 B
    vo1[i] = ((unsigned)((b << 11) + widx[p*3+1]) << 10) + colB;
    vo2[i] = ((unsigned)((b << 11) + widx[p*3+2]) << 10) + colB;
    voU[i] = (unsigned)p * 512u + colB;                            // uf row = 512 B
  }

  f32x4 acc[4][4];
  const f32x4 zero = {0.f, 0.f, 0.f, 0.f};
  #pragma unroll
  for (int m = 0; m < 4; ++m)
    #pragma unroll
    for (int n = 0; n < 4; ++n) acc[m][n] = zero;

  const char* kfb = (const char*)kf;
  const char* ufb = (const char*)uf;

  #pragma unroll
  for (int t = 0; t < 6; ++t) {
    const int k0 = t * 64;
    #pragma unroll
    for (int i = 0; i < 4; ++i) {
      const int cbase = wave*64 + i*256;
      const int c = cbase + lane;
      const int brow = c >> 3, bcol = (c & 7) * 8;
      gload16(Bw + ((size_t)(bn*128 + brow))*K + k0 + bcol, (unsigned short*)Bs + cbase*8);
      float4 r0, r1;
      if (t < 4) {           // interp region: 3-way lerp of gathered kf rows
        float4 a0 = *(const float4*)(kfb + vo0[i] + k0*4);
        float4 a1 = *(const float4*)(kfb + vo0[i] + k0*4 + 16);
        float4 e0 = *(const float4*)(kfb + vo1[i] + k0*4);
        float4 e1 = *(const float4*)(kfb + vo1[i] + k0*4 + 16);
        float4 g0 = *(const float4*)(kfb + vo2[i] + k0*4);
        float4 g1 = *(const float4*)(kfb + vo2[i] + k0*4 + 16);
        const float w0 = w0r[i], w1 = w1r[i], w2 = w2r[i];
        r0.x = w0*a0.x + w1*e0.x + w2*g0.x;
        r0.y = w0*a0.y + w1*e0.y + w2*g0.y;
        r0.z = w0*a0.z + w1*e0.z + w2*g0.z;
        r0.w = w0*a0.w + w1*e0.w + w2*g0.w;
        r1.x = w0*a1.x + w1*e1.x + w2*g1.x;
        r1.y = w0*a1.y + w1*e1.y + w2*g1.y;
        r1.z = w0*a1.z + w1*e1.z + w2*g1.z;
        r1.w = w0*a1.w + w1*e1.w + w2*g1.w;
      } else {               // concat region: uf passthrough
        r0 = *(const float4*)(ufb + voU[i] + (k0 - 256)*4);
        r1 = *(const float4*)(ufb + voU[i] + (k0 - 256)*4 + 16);
      }
      uint4 ov;
      ov.x = cvtpk_bf16(r0.x, r0.y);
      ov.y = cvtpk_bf16(r0.z, r0.w);
      ov.z = cvtpk_bf16(r1.x, r1.y);
      ov.w = cvtpk_bf16(r1.z, r1.w);
      *(uint4*)((unsigned short*)As + (size_t)c*8) = ov;
    }
    __syncthreads();
    const int kq = (lane >> 4) * 8;
    #pragma unroll
    for (int kk = 0; kk < 64; kk += 32) {
      bf16x8 af[4], bfr[4];
      #pragma unroll
      for (int m = 0; m < 4; ++m)
        af[m] = *(const bf16x8*)&As[wm*64 + m*16 + (lane & 15)][kk + kq];
      #pragma unroll
      for (int n = 0; n < 4; ++n)
        bfr[n] = *(const bf16x8*)&Bs[wn*64 + n*16 + (lane & 15)][kk + kq];
      #pragma unroll
      for (int m = 0; m < 4; ++m)
        #pragma unroll
        for (int n = 0; n < 4; ++n)
          acc[m][n] = __builtin_amdgcn_mfma_f32_16x16x32_bf16(af[m], bfr[n], acc[m][n], 0, 0, 0);
    }
    __syncthreads();
  }

  // epilogue: bias, store bf16, per-channel sum/sumsq
  float* s_sum = (float*)&As[0][0];   // [2][128]
  float* s_sq  = s_sum + 256;         // [2][128]
  #pragma unroll
  for (int n = 0; n < 4; ++n) {
    const int cb   = wn*64 + n*16 + (lane & 15);
    const int gcol = bn*128 + cb;
    const float bv = bias[gcol];
    float sum = 0.f, sq = 0.f;
    #pragma unroll
    for (int m = 0; m < 4; ++m) {
      const size_t grow = (size_t)bm*128 + wm*64 + m*16 + (lane >> 4)*4;
      #pragma unroll
      for (int qq = 0; qq < 4; ++qq) {
        float y = acc[m][n][qq] + bv;
        sum += y; sq += y*y;
        Out[(grow+qq)*256 + gcol] = f2bf(y);
      }
    }
    sum += __shfl_xor(sum, 16, 64); sum += __shfl_xor(sum, 32, 64);
    sq  += __shfl_xor(sq , 16, 64); sq  += __shfl_xor(sq , 32, 64);
    if (lane < 16) { s_sum[wm*128 + cb] = sum; s_sq[wm*128 + cb] = sq; }
  }
  __syncthreads();
  if (tid < 128) {
    atomicAdd(&gsum[bn*128 + tid], s_sum[tid] + s_sum[128 + tid]);
    atomicAdd(&gsq [bn*128 + tid], s_sq [tid] + s_sq [128 + tid]);
  }
}

// ---------- 4. GEMM2: fused BN1+ReLU on A-load (scale/shift computed in preamble
// from raw sums), y2 bf16 out, + BN2 stats ----------
__global__ __launch_bounds__(256)
void gemm2_kernel(const unsigned short* __restrict__ A,     // y1 raw bf16
                  const unsigned short* __restrict__ Bw,    // W2 bf16
                  const float* __restrict__ bias,           // b2
                  unsigned short* __restrict__ Out,         // y2 bf16
                  float* __restrict__ gsum, float* __restrict__ gsq,     // BN2 accum
                  const float* __restrict__ gsum1, const float* __restrict__ gsq1,
                  const float* __restrict__ g1, const float* __restrict__ be1) {
  constexpr int K = HH;
  __shared__ unsigned short As[128][64];   // 16 KB
  __shared__ unsigned short Bs[128][64];   // 16 KB
  __shared__ float sc_l[HH], sh_l[HH];     // 2 KB
  const int tid  = threadIdx.x;
  const int lane = tid & 63;
  const int wave = tid >> 6;          // 0..3
  const int wid  = blockIdx.x;
  const int slot = wid & 15;
  const int bm = ((wid >> 4) << 3) | (slot & 7);
  const int bn = slot >> 3;
  const int wm = wave >> 1, wn = wave & 1;

  {  // BN1 finalize (redundant per block; replaces stats_fin dispatch)
    float mu  = gsum1[tid] * (1.f/65536.f);
    float var = gsq1[tid]  * (1.f/65536.f) - mu*mu;
    float sc  = g1[tid] * rsqrtf(var + 1e-5f);
    sc_l[tid] = sc;
    sh_l[tid] = be1[tid] - mu*sc;
  }
  __syncthreads();

  f32x4 acc[4][4];
  const f32x4 zero = {0.f, 0.f, 0.f, 0.f};
  #pragma unroll
  for (int m = 0; m < 4; ++m)
    #pragma unroll
    for (int n = 0; n < 4; ++n) acc[m][n] = zero;

  for (int k0 = 0; k0 < K; k0 += 64) {
    #pragma unroll
    for (int i = 0; i < 4; ++i) {
      const int cbase = wave*64 + i*256;          // wave-uniform chunk base
      const int c = cbase + lane;                 // per-lane chunk (16 B)
      const int row = c >> 3, col = (c & 7) * 8;
      gload16(Bw + ((size_t)(bn*128 + row))*K + k0 + col, (unsigned short*)Bs + cbase*8);
      us8 v = *(const us8*)(A + ((size_t)(bm*128 + row))*K + k0 + col);
      us8 o;
      #pragma unroll
      for (int j = 0; j < 8; ++j) {
        float y = fmaxf(fmaf(bf2f(v[j]), sc_l[k0+col+j], sh_l[k0+col+j]), 0.f);
        o[j] = f2bf(y);
      }
      *(us8*)((unsigned short*)As + cbase*8 + lane*8) = o;
    }
    __syncthreads();
    const int kq = (lane >> 4) * 8;
    #pragma unroll
    for (int kk = 0; kk < 64; kk += 32) {
      bf16x8 af[4], bfr[4];
      #pragma unroll
      for (int m = 0; m < 4; ++m)
        af[m] = *(const bf16x8*)&As[wm*64 + m*16 + (lane & 15)][kk + kq];
      #pragma unroll
      for (int n = 0; n < 4; ++n)
        bfr[n] = *(const bf16x8*)&Bs[wn*64 + n*16 + (lane & 15)][kk + kq];
      #pragma unroll
      for (int m = 0; m < 4; ++m)
        #pragma unroll
        for (int n = 0; n < 4; ++n)
          acc[m][n] = __builtin_amdgcn_mfma_f32_16x16x32_bf16(af[m], bfr[n], acc[m][n], 0, 0, 0);
    }
    __syncthreads();
  }

  // epilogue: bias, store bf16 y2, per-channel sum/sumsq
  float* s_sum = (float*)&As[0][0];   // [2][128]
  float* s_sq  = s_sum + 256;         // [2][128]
  #pragma unroll
  for (int n = 0; n < 4; ++n) {
    const int cb   = wn*64 + n*16 + (lane & 15);
    const int gcol = bn*128 + cb;
    const float bv = bias[gcol];
    float sum = 0.f, sq = 0.f;
    #pragma unroll
    for (int m = 0; m < 4; ++m) {
      const size_t grow = (size_t)bm*128 + wm*64 + m*16 + (lane >> 4)*4;
      #pragma unroll
      for (int qq = 0; qq < 4; ++qq) {
        float y = acc[m][n][qq] + bv;
        sum += y; sq += y*y;
        Out[(grow+qq)*256 + gcol] = f2bf(y);
      }
    }
    sum += __shfl_xor(sum, 16, 64); sum += __shfl_xor(sum, 32, 64);
    sq  += __shfl_xor(sq , 16, 64); sq  += __shfl_xor(sq , 32, 64);
    if (lane < 16) { s_sum[wm*128 + cb] = sum; s_sq[wm*128 + cb] = sq; }
  }
  __syncthreads();
  if (tid < 128) {
    atomicAdd(&gsum[bn*128 + tid], s_sum[tid] + s_sum[128 + tid]);
    atomicAdd(&gsq [bn*128 + tid], s_sq [tid] + s_sq [128 + tid]);
  }
}

// ---------- 5. final BN2+ReLU: bf16 y2 -> fp32 d_out (scale/shift in preamble) ----------
__global__ __launch_bounds__(256)
void final_kernel(const unsigned short* __restrict__ Y2, float* __restrict__ Out,
                  const float* __restrict__ gsum, const float* __restrict__ gsq,
                  const float* __restrict__ g2, const float* __restrict__ be2) {
  __shared__ float sc[256], sh[256];
  {  // BN2 finalize (redundant per block; replaces stats_fin dispatch)
    float mu  = gsum[threadIdx.x] * (1.f/65536.f);
    float var = gsq[threadIdx.x]  * (1.f/65536.f) - mu*mu;
    float scv = g2[threadIdx.x] * rsqrtf(var + 1e-5f);
    sc[threadIdx.x] = scv;
    sh[threadIdx.x] = be2[threadIdx.x] - mu*scv;
  }
  __syncthreads();
  size_t i = ((size_t)blockIdx.x * 256 + threadIdx.x) * 8;
  int c0 = (int)(i & 255);
  us8 v = *(const us8*)(Y2 + i);
  float4 o1, o2;
  o1.x = fmaxf(fmaf(bf2f(v[0]), sc[c0+0], sh[c0+0]), 0.f);
  o1.y = fmaxf(fmaf(bf2f(v[1]), sc[c0+1], sh[c0+1]), 0.f);
  o1.z = fmaxf(fmaf(bf2f(v[2]), sc[c0+2], sh[c0+2]), 0.f);
  o1.w = fmaxf(fmaf(bf2f(v[3]), sc[c0+3], sh[c0+3]), 0.f);
  o2.x = fmaxf(fmaf(bf2f(v[4]), sc[c0+4], sh[c0+4]), 0.f);
  o2.y = fmaxf(fmaf(bf2f(v[5]), sc[c0+5], sh[c0+5]), 0.f);
  o2.z = fmaxf(fmaf(bf2f(v[6]), sc[c0+6], sh[c0+6]), 0.f);
  o2.w = fmaxf(fmaf(bf2f(v[7]), sc[c0+7], sh[c0+7]), 0.f);
  *(float4*)(Out + i)     = o1;
  *(float4*)(Out + i + 4) = o2;
}

// ---------- launch ----------
extern "C" void kernel_launch(void* const* d_in, const int* in_sizes, int n_in,
                              void* d_out, int out_size, void* d_ws, size_t ws_size,
                              hipStream_t stream) {
  const float* unknown = (const float*)d_in[0];
  const float* known   = (const float*)d_in[1];
  const float* uf      = (const float*)d_in[2];
  const float* kf      = (const float*)d_in[3];
  const float* W1      = (const float*)d_in[4];
  const float* b1      = (const float*)d_in[5];
  const float* g1      = (const float*)d_in[6];
  const float* be1     = (const float*)d_in[7];
  const float* W2      = (const float*)d_in[8];
  const float* b2      = (const float*)d_in[9];
  const float* g2      = (const float*)d_in[10];
  const float* be2     = (const float*)d_in[11];

  char* ws = (char*)d_ws;
  unsigned short* X    = (unsigned short*)(ws);                 // 50,331,648 (y2 scratch)
  unsigned short* Y1   = (unsigned short*)(ws + 50331648);      // 33,554,432 (y1 raw)
  unsigned short* w1b  = (unsigned short*)(ws + 83886080);      // 196,608
  unsigned short* w2b  = (unsigned short*)(ws + 84082688);      // 131,072
  int*            widx = (int*)  (ws + 84213760);               // 786,432
  float*          wwgt = (float*)(ws + 85000192);               // 786,432
  float*          stats= (float*)(ws + 85786624);               // 8 KB
  float4*         kprep= (float4*)(ws + 85794816);              // 262,144
  float *sum1 = stats,        *sq1 = stats + 256;
  float *sum2 = stats + 512,  *sq2 = stats + 768;
  float* out = (float*)d_out;

  prep_kernel<<<708, 256, 0, stream>>>(W1, W2, known, w1b, w2b, stats, kprep);
  nn_kernel<<<dim3(128, 8), 512, 0, stream>>>(unknown, kprep, widx, wwgt);
  // gemm1 with fused interp+concat on the A-staging path; batch->XCD swizzle
  gemm1_fused<<<1024, 256, 0, stream>>>(kf, uf, widx, wwgt, w1b, b1, Y1, sum1, sq1);
  // gemm2: BN1 finalized in-kernel from raw sums; fused BN1+ReLU on A; y2 -> X
  gemm2_kernel<<<1024, 256, 0, stream>>>(Y1, w2b, b2, X, sum2, sq2, sum1, sq1, g1, be1);
  // final: BN2 finalized in-kernel from raw sums; bf16 y2 -> fp32 d_out
  final_kernel<<<8192, 256, 0, stream>>>(X, out, sum2, sq2, g2, be2);
}

// Round 13
// 159.888 us; speedup vs baseline: 1.3953x; 1.0004x over previous
//
#include <hip/hip_runtime.h>

// ---------- problem constants ----------
#define BQ   8
#define NQ   8192      // unknown points per batch
#define MK   2048      // known points per batch
#define C1v  128
#define C2v  256
#define CIN  384
#define HH   256
#define MTOT (BQ*NQ)   // 65536

#define NCHUNK 8       // candidate chunks per nn block (= waves per block)
#define CHSZ   (MK/NCHUNK)   // 256 candidates per chunk

typedef __attribute__((ext_vector_type(8))) __bf16 bf16x8;
typedef __attribute__((ext_vector_type(4))) float f32x4;
typedef __attribute__((ext_vector_type(8))) unsigned short us8;
typedef __attribute__((ext_vector_type(4))) unsigned short us4;
typedef __attribute__((ext_vector_type(2))) unsigned short us2;

__device__ __forceinline__ unsigned short f2bf(float f) {
  unsigned int u = __builtin_bit_cast(unsigned int, f);
  u += 0x7fffu + ((u >> 16) & 1u);           // round-to-nearest-even
  return (unsigned short)(u >> 16);
}
__device__ __forceinline__ float bf2f(unsigned short h) {
  unsigned int u = ((unsigned int)h) << 16;
  return __builtin_bit_cast(float, u);
}

__device__ __forceinline__ void gload16(const void* g, void* l) {
  __builtin_amdgcn_global_load_lds((const __attribute__((address_space(1))) void*)g,
                                   (__attribute__((address_space(3))) void*)l, 16, 0, 0);
}

// packed f32->bf16 RNE convert (dst.lo = src0, dst.hi = src1)
__device__ __forceinline__ unsigned int cvtpk_bf16(float lo, float hi) {
  unsigned int r;
  asm("v_cvt_pk_bf16_f32 %0, %1, %2" : "=v"(r) : "v"(lo), "v"(hi));
  return r;
}

// score from a staged candidate: s = u.k - 0.5|k|^2  (kprep.w = -0.5|k|^2)
#define SCORE(k4) (fmaf((k4).x, ux, fmaf((k4).y, uy, (k4).z * uz)) + (k4).w)

// pack fp32 score + candidate index into one exactly-ordered f64 key:
// (double)s has 29 zero low mantissa bits; OR in (2047-j). Distinct fp32
// scores keep exact order; equal scores tie-break to smaller j (top_k rule).
__device__ __forceinline__ double packsd(float s, int negj) {
  unsigned long long u = __builtin_bit_cast(unsigned long long, (double)s)
                       | (unsigned long long)(unsigned int)negj;
  return __builtin_bit_cast(double, u);
}

// 5-op f64 top-3 insert (keys are all distinct): {s0,s1,s2} <- top3 of {s0,s1,s2,t}
#define INS3D(s0, s1, s2, t)                                  \
  do {                                                        \
    double _hi0 = fmax(s0, (t)), _lo0 = fmin(s0, (t));        \
    double _hi1 = fmax(s1, _lo0), _lo1 = fmin(s1, _lo0);      \
    s0 = _hi0; s1 = _hi1; s2 = fmax(s2, _lo1);                \
  } while (0)

// ---------- 1. prep: W->bf16, zero BN accumulators, stage kprep ----------
__global__ __launch_bounds__(256)
void prep_kernel(const float* __restrict__ W1, const float* __restrict__ W2,
                 const float* __restrict__ known,
                 unsigned short* __restrict__ w1b, unsigned short* __restrict__ w2b,
                 float* __restrict__ stats, float4* __restrict__ kprep) {
  int i = blockIdx.x * 256 + threadIdx.x;
  if (i < HH*CIN) w1b[i] = f2bf(W1[i]);
  else if (i < HH*CIN + HH*HH) w2b[i - HH*CIN] = f2bf(W2[i - HH*CIN]);
  int z = i - (HH*CIN + HH*HH);
  if (z >= 0 && z < 1024) stats[z] = 0.f;
  int z2 = i - (HH*CIN + HH*HH + 1024);
  if (z2 >= 0 && z2 < BQ*MK) {
    const float* kp = known + (size_t)z2 * 3;
    float x = kp[0], y = kp[1], zz = kp[2];
    kprep[z2] = make_float4(x, y, zz, -0.5f*(x*x + y*y + zz*zz));
  }
}

// ---------- 2. three_nn: single pass, index-packed f64 keys ----------
__global__ __launch_bounds__(512)
void nn_kernel(const float* __restrict__ unknown, const float4* __restrict__ kprep,
               int* __restrict__ widx, float* __restrict__ wwgt) {
  __shared__ double pd[NCHUNK][64][3];      // per-chunk packed triples (12 KB)
  const int b = blockIdx.y;
  const int tid = threadIdx.x;
  const int wave = tid >> 6, lane = tid & 63;

  const int q = blockIdx.x * 64 + lane;
  const float* up = unknown + ((size_t)b * NQ + q) * 3;
  const float ux = up[0], uy = up[1], uz = up[2];
  const float nu = ux*ux + uy*uy + uz*uz;
  const int jbase = wave * CHSZ;
  // wave-uniform chunk pointer -> scalar-path candidate fetch
  const float4* cp = kprep + (b << 11) + __builtin_amdgcn_readfirstlane(jbase);

  // dual accumulator sets for ILP; keys are distinct so merge order is free
  double A0=-1e300, A1=-1e300, A2=-1e300;
  double B0=-1e300, B1=-1e300, B2=-1e300;
  #pragma unroll 4
  for (int j = 0; j < CHSZ; j += 2) {
    float4 ka = cp[j];
    float4 kc = cp[j+1];
    float sA = SCORE(ka);
    float sB = SCORE(kc);
    double da = packsd(sA, 2047 - (jbase + j));
    double db = packsd(sB, 2047 - (jbase + j + 1));
    INS3D(A0, A1, A2, da);
    INS3D(B0, B1, B2, db);
  }
  INS3D(A0, A1, A2, B0);
  INS3D(A0, A1, A2, B1);
  INS3D(A0, A1, A2, B2);
  pd[wave][lane][0] = A0; pd[wave][lane][1] = A1; pd[wave][lane][2] = A2;
  __syncthreads();

  if (tid < 64) {   // wave 0: lane == query; merge the 8 chunk triples
    double f0=-1e300, f1=-1e300, f2=-1e300;
    #pragma unroll
    for (int c = 0; c < NCHUNK; ++c) {
      INS3D(f0, f1, f2, pd[c][tid][0]);
      INS3D(f0, f1, f2, pd[c][tid][1]);
      INS3D(f0, f1, f2, pd[c][tid][2]);
    }
    unsigned long long u0 = __builtin_bit_cast(unsigned long long, f0);
    unsigned long long u1 = __builtin_bit_cast(unsigned long long, f1);
    unsigned long long u2 = __builtin_bit_cast(unsigned long long, f2);
    int x0 = 2047 - (int)(u0 & 2047ULL);
    int x1 = 2047 - (int)(u1 & 2047ULL);
    int x2 = 2047 - (int)(u2 & 2047ULL);
    // masking restores the exact fp32 score bits
    float s0 = (float)__builtin_bit_cast(double, u0 & ~2047ULL);
    float s1 = (float)__builtin_bit_cast(double, u1 & ~2047ULL);
    float s2 = (float)__builtin_bit_cast(double, u2 & ~2047ULL);
    float d0 = sqrtf(fmaxf(nu - 2.f*s0, 0.f)) + 1e-10f;
    float d1 = sqrtf(fmaxf(nu - 2.f*s1, 0.f)) + 1e-10f;
    float d2 = sqrtf(fmaxf(nu - 2.f*s2, 0.f)) + 1e-10f;
    float r0 = 1.f/d0, r1 = 1.f/d1, r2 = 1.f/d2;
    float rs = 1.f/(r0 + r1 + r2);
    size_t p = (size_t)b * NQ + q;
    widx[p*3+0] = x0;    widx[p*3+1] = x1;    widx[p*3+2] = x2;
    wwgt[p*3+0] = r0*rs; wwgt[p*3+1] = r1*rs; wwgt[p*3+2] = r2*rs;
  }
}

// ---------- 3. GEMM1 (fused interp): A[p][k] built in-staging from
// gather+lerp (k<256) and uf concat (k>=256); Y1 bf16 out + BN1 stats.
// Block swizzle: batch = wid&7 -> all 128 blocks of a batch land on one XCD.
// Staging is pair-batched: 12 gathers issued into regs before any use, so the
// wave pays ~2 L2 latencies per K-step instead of ~24 serialized ones.
__global__ __launch_bounds__(256)
void gemm1_fused(const float* __restrict__ kf, const float* __restrict__ uf,
                 const int* __restrict__ widx, const float* __restrict__ wwgt,
                 const unsigned short* __restrict__ Bw,
                 const float* __restrict__ bias,
                 unsigned short* __restrict__ Out,
                 float* __restrict__ gsum, float* __restrict__ gsq) {
  constexpr int K = CIN;
  __shared__ unsigned short As[128][64];   // 16 KB
  __shared__ unsigned short Bs[128][64];   // 16 KB
  const int tid  = threadIdx.x;
  const int lane = tid & 63;
  const int wave = tid >> 6;          // 0..3
  const int wid   = blockIdx.x;
  const int batch = wid & 7;          // -> XCD id
  const int inner = wid >> 3;         // 0..127 within batch
  const int bm = batch * 64 + (inner >> 1);
  const int bn = inner & 1;
  const int wm = wave >> 1, wn = wave & 1;

  // prologue: per-chunk gather byte-offsets + weights (chunk i -> fixed row/col)
  unsigned int vo0[4], vo1[4], vo2[4], voU[4];
  float w0r[4], w1r[4], w2r[4];
  #pragma unroll
  for (int i = 0; i < 4; ++i) {
    const int c = wave*64 + i*256 + lane;
    const int row = c >> 3, colB = (c & 7) * 32;   // byte offset of col8*8 floats
    const int p = bm*128 + row;
    const int b = p >> 13;
    w0r[i] = wwgt[p*3+0]; w1r[i] = wwgt[p*3+1]; w2r[i] = wwgt[p*3+2];
    vo0[i] = ((unsigned)((b << 11) + widx[p*3+0]) << 10) + colB;  // kf row = 1024 B
    vo1[i] = ((unsigned)((b << 11) + widx[p*3+1]) << 10) + colB;
    vo2[i] = ((unsigned)((b << 11) + widx[p*3+2]) << 10) + colB;
    voU[i] = (unsigned)p * 512u + colB;                            // uf row = 512 B
  }

  f32x4 acc[4][4];
  const f32x4 zero = {0.f, 0.f, 0.f, 0.f};
  #pragma unroll
  for (int m = 0; m < 4; ++m)
    #pragma unroll
    for (int n = 0; n < 4; ++n) acc[m][n] = zero;

  const char* kfb = (const char*)kf;
  const char* ufb = (const char*)uf;

  #pragma unroll
  for (int t = 0; t < 6; ++t) {
    const int k0 = t * 64;
    // B-tile: async LDS-direct (no VGPR cost)
    #pragma unroll
    for (int i = 0; i < 4; ++i) {
      const int cbase = wave*64 + i*256;
      const int c = cbase + lane;
      const int brow = c >> 3, bcol = (c & 7) * 8;
      gload16(Bw + ((size_t)(bn*128 + brow))*K + k0 + bcol, (unsigned short*)Bs + cbase*8);
    }
    // A-tile: pair-batched reg staging (12 loads in flight)
    #pragma unroll
    for (int ip = 0; ip < 2; ++ip) {
      float4 La0[2], La1[2], Le0[2], Le1[2], Lg0[2], Lg1[2];
      if (t < 4) {
        #pragma unroll
        for (int u = 0; u < 2; ++u) {
          const int i = ip*2 + u;
          La0[u] = *(const float4*)(kfb + vo0[i] + k0*4);
          La1[u] = *(const float4*)(kfb + vo0[i] + k0*4 + 16);
          Le0[u] = *(const float4*)(kfb + vo1[i] + k0*4);
          Le1[u] = *(const float4*)(kfb + vo1[i] + k0*4 + 16);
          Lg0[u] = *(const float4*)(kfb + vo2[i] + k0*4);
          Lg1[u] = *(const float4*)(kfb + vo2[i] + k0*4 + 16);
        }
      } else {
        #pragma unroll
        for (int u = 0; u < 2; ++u) {
          const int i = ip*2 + u;
          La0[u] = *(const float4*)(ufb + voU[i] + (k0 - 256)*4);
          La1[u] = *(const float4*)(ufb + voU[i] + (k0 - 256)*4 + 16);
        }
      }
      #pragma unroll
      for (int u = 0; u < 2; ++u) {
        const int i = ip*2 + u;
        const int c = wave*64 + i*256 + lane;
        float4 r0, r1;
        if (t < 4) {
          const float w0 = w0r[i], w1 = w1r[i], w2 = w2r[i];
          r0.x = w0*La0[u].x + w1*Le0[u].x + w2*Lg0[u].x;
          r0.y = w0*La0[u].y + w1*Le0[u].y + w2*Lg0[u].y;
          r0.z = w0*La0[u].z + w1*Le0[u].z + w2*Lg0[u].z;
          r0.w = w0*La0[u].w + w1*Le0[u].w + w2*Lg0[u].w;
          r1.x = w0*La1[u].x + w1*Le1[u].x + w2*Lg1[u].x;
          r1.y = w0*La1[u].y + w1*Le1[u].y + w2*Lg1[u].y;
          r1.z = w0*La1[u].z + w1*Le1[u].z + w2*Lg1[u].z;
          r1.w = w0*La1[u].w + w1*Le1[u].w + w2*Lg1[u].w;
        } else {
          r0 = La0[u]; r1 = La1[u];
        }
        uint4 ov;
        ov.x = cvtpk_bf16(r0.x, r0.y);
        ov.y = cvtpk_bf16(r0.z, r0.w);
        ov.z = cvtpk_bf16(r1.x, r1.y);
        ov.w = cvtpk_bf16(r1.z, r1.w);
        *(uint4*)((unsigned short*)As + (size_t)c*8) = ov;
      }
    }
    __syncthreads();
    const int kq = (lane >> 4) * 8;
    #pragma unroll
    for (int kk = 0; kk < 64; kk += 32) {
      bf16x8 af[4], bfr[4];
      #pragma unroll
      for (int m = 0; m < 4; ++m)
        af[m] = *(const bf16x8*)&As[wm*64 + m*16 + (lane & 15)][kk + kq];
      #pragma unroll
      for (int n = 0; n < 4; ++n)
        bfr[n] = *(const bf16x8*)&Bs[wn*64 + n*16 + (lane & 15)][kk + kq];
      #pragma unroll
      for (int m = 0; m < 4; ++m)
        #pragma unroll
        for (int n = 0; n < 4; ++n)
          acc[m][n] = __builtin_amdgcn_mfma_f32_16x16x32_bf16(af[m], bfr[n], acc[m][n], 0, 0, 0);
    }
    __syncthreads();
  }

  // epilogue: bias, store bf16, per-channel sum/sumsq
  float* s_sum = (float*)&As[0][0];   // [2][128]
  float* s_sq  = s_sum + 256;         // [2][128]
  #pragma unroll
  for (int n = 0; n < 4; ++n) {
    const int cb   = wn*64 + n*16 + (lane & 15);
    const int gcol = bn*128 + cb;
    const float bv = bias[gcol];
    float sum = 0.f, sq = 0.f;
    #pragma unroll
    for (int m = 0; m < 4; ++m) {
      const size_t grow = (size_t)bm*128 + wm*64 + m*16 + (lane >> 4)*4;
      #pragma unroll
      for (int qq = 0; qq < 4; ++qq) {
        float y = acc[m][n][qq] + bv;
        sum += y; sq += y*y;
        Out[(grow+qq)*256 + gcol] = f2bf(y);
      }
    }
    sum += __shfl_xor(sum, 16, 64); sum += __shfl_xor(sum, 32, 64);
    sq  += __shfl_xor(sq , 16, 64); sq  += __shfl_xor(sq , 32, 64);
    if (lane < 16) { s_sum[wm*128 + cb] = sum; s_sq[wm*128 + cb] = sq; }
  }
  __syncthreads();
  if (tid < 128) {
    atomicAdd(&gsum[bn*128 + tid], s_sum[tid] + s_sum[128 + tid]);
    atomicAdd(&gsq [bn*128 + tid], s_sq [tid] + s_sq [128 + tid]);
  }
}

// ---------- 4. GEMM2: fused BN1+ReLU on A-load (scale/shift computed in preamble
// from raw sums), y2 bf16 out, + BN2 stats ----------
__global__ __launch_bounds__(256)
void gemm2_kernel(const unsigned short* __restrict__ A,     // y1 raw bf16
                  const unsigned short* __restrict__ Bw,    // W2 bf16
                  const float* __restrict__ bias,           // b2
                  unsigned short* __restrict__ Out,         // y2 bf16
                  float* __restrict__ gsum, float* __restrict__ gsq,     // BN2 accum
                  const float* __restrict__ gsum1, const float* __restrict__ gsq1,
                  const float* __restrict__ g1, const float* __restrict__ be1) {
  constexpr int K = HH;
  __shared__ unsigned short As[128][64];   // 16 KB
  __shared__ unsigned short Bs[128][64];   // 16 KB
  __shared__ float sc_l[HH], sh_l[HH];     // 2 KB
  const int tid  = threadIdx.x;
  const int lane = tid & 63;
  const int wave = tid >> 6;          // 0..3
  const int wid  = blockIdx.x;
  const int slot = wid & 15;
  const int bm = ((wid >> 4) << 3) | (slot & 7);
  const int bn = slot >> 3;
  const int wm = wave >> 1, wn = wave & 1;

  {  // BN1 finalize (redundant per block; replaces stats_fin dispatch)
    float mu  = gsum1[tid] * (1.f/65536.f);
    float var = gsq1[tid]  * (1.f/65536.f) - mu*mu;
    float sc  = g1[tid] * rsqrtf(var + 1e-5f);
    sc_l[tid] = sc;
    sh_l[tid] = be1[tid] - mu*sc;
  }
  __syncthreads();

  f32x4 acc[4][4];
  const f32x4 zero = {0.f, 0.f, 0.f, 0.f};
  #pragma unroll
  for (int m = 0; m < 4; ++m)
    #pragma unroll
    for (int n = 0; n < 4; ++n) acc[m][n] = zero;

  for (int k0 = 0; k0 < K; k0 += 64) {
    #pragma unroll
    for (int i = 0; i < 4; ++i) {
      const int cbase = wave*64 + i*256;          // wave-uniform chunk base
      const int c = cbase + lane;                 // per-lane chunk (16 B)
      const int row = c >> 3, col = (c & 7) * 8;
      gload16(Bw + ((size_t)(bn*128 + row))*K + k0 + col, (unsigned short*)Bs + cbase*8);
      us8 v = *(const us8*)(A + ((size_t)(bm*128 + row))*K + k0 + col);
      us8 o;
      #pragma unroll
      for (int j = 0; j < 8; ++j) {
        float y = fmaxf(fmaf(bf2f(v[j]), sc_l[k0+col+j], sh_l[k0+col+j]), 0.f);
        o[j] = f2bf(y);
      }
      *(us8*)((unsigned short*)As + cbase*8 + lane*8) = o;
    }
    __syncthreads();
    const int kq = (lane >> 4) * 8;
    #pragma unroll
    for (int kk = 0; kk < 64; kk += 32) {
      bf16x8 af[4], bfr[4];
      #pragma unroll
      for (int m = 0; m < 4; ++m)
        af[m] = *(const bf16x8*)&As[wm*64 + m*16 + (lane & 15)][kk + kq];
      #pragma unroll
      for (int n = 0; n < 4; ++n)
        bfr[n] = *(const bf16x8*)&Bs[wn*64 + n*16 + (lane & 15)][kk + kq];
      #pragma unroll
      for (int m = 0; m < 4; ++m)
        #pragma unroll
        for (int n = 0; n < 4; ++n)
          acc[m][n] = __builtin_amdgcn_mfma_f32_16x16x32_bf16(af[m], bfr[n], acc[m][n], 0, 0, 0);
    }
    __syncthreads();
  }

  // epilogue: bias, store bf16 y2, per-channel sum/sumsq
  float* s_sum = (float*)&As[0][0];   // [2][128]
  float* s_sq  = s_sum + 256;         // [2][128]
  #pragma unroll
  for (int n = 0; n < 4; ++n) {
    const int cb   = wn*64 + n*16 + (lane & 15);
    const int gcol = bn*128 + cb;
    const float bv = bias[gcol];
    float sum = 0.f, sq = 0.f;
    #pragma unroll
    for (int m = 0; m < 4; ++m) {
      const size_t grow = (size_t)bm*128 + wm*64 + m*16 + (lane >> 4)*4;
      #pragma unroll
      for (int qq = 0; qq < 4; ++qq) {
        float y = acc[m][n][qq] + bv;
        sum += y; sq += y*y;
        Out[(grow+qq)*256 + gcol] = f2bf(y);
      }
    }
    sum += __shfl_xor(sum, 16, 64); sum += __shfl_xor(sum, 32, 64);
    sq  += __shfl_xor(sq , 16, 64); sq  += __shfl_xor(sq , 32, 64);
    if (lane < 16) { s_sum[wm*128 + cb] = sum; s_sq[wm*128 + cb] = sq; }
  }
  __syncthreads();
  if (tid < 128) {
    atomicAdd(&gsum[bn*128 + tid], s_sum[tid] + s_sum[128 + tid]);
    atomicAdd(&gsq [bn*128 + tid], s_sq [tid] + s_sq [128 + tid]);
  }
}

// ---------- 5. final BN2+ReLU: bf16 y2 -> fp32 d_out (scale/shift in preamble) ----------
__global__ __launch_bounds__(256)
void final_kernel(const unsigned short* __restrict__ Y2, float* __restrict__ Out,
                  const float* __restrict__ gsum, const float* __restrict__ gsq,
                  const float* __restrict__ g2, const float* __restrict__ be2) {
  __shared__ float sc[256], sh[256];
  {  // BN2 finalize (redundant per block; replaces stats_fin dispatch)
    float mu  = gsum[threadIdx.x] * (1.f/65536.f);
    float var = gsq[threadIdx.x]  * (1.f/65536.f) - mu*mu;
    float scv = g2[threadIdx.x] * rsqrtf(var + 1e-5f);
    sc[threadIdx.x] = scv;
    sh[threadIdx.x] = be2[threadIdx.x] - mu*scv;
  }
  __syncthreads();
  size_t i = ((size_t)blockIdx.x * 256 + threadIdx.x) * 8;
  int c0 = (int)(i & 255);
  us8 v = *(const us8*)(Y2 + i);
  float4 o1, o2;
  o1.x = fmaxf(fmaf(bf2f(v[0]), sc[c0+0], sh[c0+0]), 0.f);
  o1.y = fmaxf(fmaf(bf2f(v[1]), sc[c0+1], sh[c0+1]), 0.f);
  o1.z = fmaxf(fmaf(bf2f(v[2]), sc[c0+2], sh[c0+2]), 0.f);
  o1.w = fmaxf(fmaf(bf2f(v[3]), sc[c0+3], sh[c0+3]), 0.f);
  o2.x = fmaxf(fmaf(bf2f(v[4]), sc[c0+4], sh[c0+4]), 0.f);
  o2.y = fmaxf(fmaf(bf2f(v[5]), sc[c0+5], sh[c0+5]), 0.f);
  o2.z = fmaxf(fmaf(bf2f(v[6]), sc[c0+6], sh[c0+6]), 0.f);
  o2.w = fmaxf(fmaf(bf2f(v[7]), sc[c0+7], sh[c0+7]), 0.f);
  *(float4*)(Out + i)     = o1;
  *(float4*)(Out + i + 4) = o2;
}

// ---------- launch ----------
extern "C" void kernel_launch(void* const* d_in, const int* in_sizes, int n_in,
                              void* d_out, int out_size, void* d_ws, size_t ws_size,
                              hipStream_t stream) {
  const float* unknown = (const float*)d_in[0];
  const float* known   = (const float*)d_in[1];
  const float* uf      = (const float*)d_in[2];
  const float* kf      = (const float*)d_in[3];
  const float* W1      = (const float*)d_in[4];
  const float* b1      = (const float*)d_in[5];
  const float* g1      = (const float*)d_in[6];
  const float* be1     = (const float*)d_in[7];
  const float* W2      = (const float*)d_in[8];
  const float* b2      = (const float*)d_in[9];
  const float* g2      = (const float*)d_in[10];
  const float* be2     = (const float*)d_in[11];

  char* ws = (char*)d_ws;
  unsigned short* X    = (unsigned short*)(ws);                 // 50,331,648 (y2 scratch)
  unsigned short* Y1   = (unsigned short*)(ws + 50331648);      // 33,554,432 (y1 raw)
  unsigned short* w1b  = (unsigned short*)(ws + 83886080);      // 196,608
  unsigned short* w2b  = (unsigned short*)(ws + 84082688);      // 131,072
  int*            widx = (int*)  (ws + 84213760);               // 786,432
  float*          wwgt = (float*)(ws + 85000192);               // 786,432
  float*          stats= (float*)(ws + 85786624);               // 8 KB
  float4*         kprep= (float4*)(ws + 85794816);              // 262,144
  float *sum1 = stats,        *sq1 = stats + 256;
  float *sum2 = stats + 512,  *sq2 = stats + 768;
  float* out = (float*)d_out;

  prep_kernel<<<708, 256, 0, stream>>>(W1, W2, known, w1b, w2b, stats, kprep);
  nn_kernel<<<dim3(128, 8), 512, 0, stream>>>(unknown, kprep, widx, wwgt);
  // gemm1 with fused interp+concat on the A-staging path; batch->XCD swizzle
  gemm1_fused<<<1024, 256, 0, stream>>>(kf, uf, widx, wwgt, w1b, b1, Y1, sum1, sq1);
  // gemm2: BN1 finalized in-kernel from raw sums; fused BN1+ReLU on A; y2 -> X
  gemm2_kernel<<<1024, 256, 0, stream>>>(Y1, w2b, b2, X, sum2, sq2, sum1, sq1, g1, be1);
  // final: BN2 finalized in-kernel from raw sums; bf16 y2 -> fp32 d_out
  final_kernel<<<8192, 256, 0, stream>>>(X, out, sum2, sq2, g2, be2);
}

// Round 14
// 146.752 us; speedup vs baseline: 1.5202x; 1.0895x over previous
//
#include <hip/hip_runtime.h>

// ---------- problem constants ----------
#define BQ   8
#define NQ   8192      // unknown points per batch
#define MK   2048      // known points per batch
#define C1v  128
#define C2v  256
#define CIN  384
#define HH   256
#define MTOT (BQ*NQ)   // 65536

#define NCHUNK 8       // candidate chunks per nn block (= waves per block)
#define CHSZ   (MK/NCHUNK)   // 256 candidates per chunk

typedef __attribute__((ext_vector_type(8))) __bf16 bf16x8;
typedef __attribute__((ext_vector_type(4))) float f32x4;
typedef __attribute__((ext_vector_type(8))) unsigned short us8;
typedef __attribute__((ext_vector_type(4))) unsigned short us4;
typedef __attribute__((ext_vector_type(2))) unsigned short us2;

__device__ __forceinline__ unsigned short f2bf(float f) {
  unsigned int u = __builtin_bit_cast(unsigned int, f);
  u += 0x7fffu + ((u >> 16) & 1u);           // round-to-nearest-even
  return (unsigned short)(u >> 16);
}
__device__ __forceinline__ float bf2f(unsigned short h) {
  unsigned int u = ((unsigned int)h) << 16;
  return __builtin_bit_cast(float, u);
}

__device__ __forceinline__ void gload16(const void* g, void* l) {
  __builtin_amdgcn_global_load_lds((const __attribute__((address_space(1))) void*)g,
                                   (__attribute__((address_space(3))) void*)l, 16, 0, 0);
}

// packed f32->bf16 RNE convert (dst.lo = src0, dst.hi = src1)
__device__ __forceinline__ unsigned int cvtpk_bf16(float lo, float hi) {
  unsigned int r;
  asm("v_cvt_pk_bf16_f32 %0, %1, %2" : "=v"(r) : "v"(lo), "v"(hi));
  return r;
}

// score from a staged candidate: s = u.k - 0.5|k|^2  (kprep.w = -0.5|k|^2)
#define SCORE(k4) (fmaf((k4).x, ux, fmaf((k4).y, uy, (k4).z * uz)) + (k4).w)

// pack fp32 score + candidate index into one exactly-ordered f64 key:
// (double)s has 29 zero low mantissa bits; OR in (2047-j). Distinct fp32
// scores keep exact order; equal scores tie-break to smaller j (top_k rule).
__device__ __forceinline__ double packsd(float s, int negj) {
  unsigned long long u = __builtin_bit_cast(unsigned long long, (double)s)
                       | (unsigned long long)(unsigned int)negj;
  return __builtin_bit_cast(double, u);
}

// 5-op f64 top-3 insert (keys are all distinct): {s0,s1,s2} <- top3 of {s0,s1,s2,t}
#define INS3D(s0, s1, s2, t)                                  \
  do {                                                        \
    double _hi0 = fmax(s0, (t)), _lo0 = fmin(s0, (t));        \
    double _hi1 = fmax(s1, _lo0), _lo1 = fmin(s1, _lo0);      \
    s0 = _hi0; s1 = _hi1; s2 = fmax(s2, _lo1);                \
  } while (0)

// ---------- 1. prep: W->bf16, BN accum zero, kprep, kf->bf16 (kfb) ----------
__global__ __launch_bounds__(256)
void prep_kernel(const float* __restrict__ W1, const float* __restrict__ W2,
                 const float* __restrict__ known, const float* __restrict__ kf,
                 unsigned short* __restrict__ w1b, unsigned short* __restrict__ w2b,
                 float* __restrict__ stats, float4* __restrict__ kprep,
                 unsigned short* __restrict__ kfb) {
  int i = blockIdx.x * 256 + threadIdx.x;
  if (i < HH*CIN) w1b[i] = f2bf(W1[i]);
  else if (i < HH*CIN + HH*HH) w2b[i - HH*CIN] = f2bf(W2[i - HH*CIN]);
  int z = i - (HH*CIN + HH*HH);
  if (z >= 0 && z < 1024) stats[z] = 0.f;
  int z2 = i - (HH*CIN + HH*HH + 1024);
  if (z2 >= 0 && z2 < BQ*MK) {
    const float* kp = known + (size_t)z2 * 3;
    float x = kp[0], y = kp[1], zz = kp[2];
    kprep[z2] = make_float4(x, y, zz, -0.5f*(x*x + y*y + zz*zz));
  }
  int z3 = i - (HH*CIN + HH*HH + 1024 + BQ*MK);
  if (z3 >= 0 && z3 < (BQ*MK*C2v)/8) {
    const float4* src = (const float4*)(kf + (size_t)z3 * 8);
    float4 v0 = src[0], v1 = src[1];
    us8 o;
    o[0]=f2bf(v0.x); o[1]=f2bf(v0.y); o[2]=f2bf(v0.z); o[3]=f2bf(v0.w);
    o[4]=f2bf(v1.x); o[5]=f2bf(v1.y); o[6]=f2bf(v1.z); o[7]=f2bf(v1.w);
    *(us8*)(kfb + (size_t)z3 * 8) = o;
  }
}

// ---------- 2. three_nn: single pass, index-packed f64 keys ----------
__global__ __launch_bounds__(512)
void nn_kernel(const float* __restrict__ unknown, const float4* __restrict__ kprep,
               int* __restrict__ widx, float* __restrict__ wwgt) {
  __shared__ double pd[NCHUNK][64][3];      // per-chunk packed triples (12 KB)
  const int b = blockIdx.y;
  const int tid = threadIdx.x;
  const int wave = tid >> 6, lane = tid & 63;

  const int q = blockIdx.x * 64 + lane;
  const float* up = unknown + ((size_t)b * NQ + q) * 3;
  const float ux = up[0], uy = up[1], uz = up[2];
  const float nu = ux*ux + uy*uy + uz*uz;
  const int jbase = wave * CHSZ;
  // wave-uniform chunk pointer -> scalar-path candidate fetch
  const float4* cp = kprep + (b << 11) + __builtin_amdgcn_readfirstlane(jbase);

  // dual accumulator sets for ILP; keys are distinct so merge order is free
  double A0=-1e300, A1=-1e300, A2=-1e300;
  double B0=-1e300, B1=-1e300, B2=-1e300;
  #pragma unroll 4
  for (int j = 0; j < CHSZ; j += 2) {
    float4 ka = cp[j];
    float4 kc = cp[j+1];
    float sA = SCORE(ka);
    float sB = SCORE(kc);
    double da = packsd(sA, 2047 - (jbase + j));
    double db = packsd(sB, 2047 - (jbase + j + 1));
    INS3D(A0, A1, A2, da);
    INS3D(B0, B1, B2, db);
  }
  INS3D(A0, A1, A2, B0);
  INS3D(A0, A1, A2, B1);
  INS3D(A0, A1, A2, B2);
  pd[wave][lane][0] = A0; pd[wave][lane][1] = A1; pd[wave][lane][2] = A2;
  __syncthreads();

  if (tid < 64) {   // wave 0: lane == query; merge the 8 chunk triples
    double f0=-1e300, f1=-1e300, f2=-1e300;
    #pragma unroll
    for (int c = 0; c < NCHUNK; ++c) {
      INS3D(f0, f1, f2, pd[c][tid][0]);
      INS3D(f0, f1, f2, pd[c][tid][1]);
      INS3D(f0, f1, f2, pd[c][tid][2]);
    }
    unsigned long long u0 = __builtin_bit_cast(unsigned long long, f0);
    unsigned long long u1 = __builtin_bit_cast(unsigned long long, f1);
    unsigned long long u2 = __builtin_bit_cast(unsigned long long, f2);
    int x0 = 2047 - (int)(u0 & 2047ULL);
    int x1 = 2047 - (int)(u1 & 2047ULL);
    int x2 = 2047 - (int)(u2 & 2047ULL);
    // masking restores the exact fp32 score bits
    float s0 = (float)__builtin_bit_cast(double, u0 & ~2047ULL);
    float s1 = (float)__builtin_bit_cast(double, u1 & ~2047ULL);
    float s2 = (float)__builtin_bit_cast(double, u2 & ~2047ULL);
    float d0 = sqrtf(fmaxf(nu - 2.f*s0, 0.f)) + 1e-10f;
    float d1 = sqrtf(fmaxf(nu - 2.f*s1, 0.f)) + 1e-10f;
    float d2 = sqrtf(fmaxf(nu - 2.f*s2, 0.f)) + 1e-10f;
    float r0 = 1.f/d0, r1 = 1.f/d1, r2 = 1.f/d2;
    float rs = 1.f/(r0 + r1 + r2);
    size_t p = (size_t)b * NQ + q;
    widx[p*3+0] = x0;    widx[p*3+1] = x1;    widx[p*3+2] = x2;
    wwgt[p*3+0] = r0*rs; wwgt[p*3+1] = r1*rs; wwgt[p*3+2] = r2*rs;
  }
}

// ---------- 3. GEMM1 (fused interp): A built in-staging from bf16-kf gathers
// (3x16B per chunk) + uf concat; cross-phase prefetch pinned by sched_barrier.
// Block swizzle: batch = wid&7 -> all 128 blocks of a batch land on one XCD.
__global__ __launch_bounds__(256)
void gemm1_fused(const unsigned short* __restrict__ kfb, const float* __restrict__ uf,
                 const int* __restrict__ widx, const float* __restrict__ wwgt,
                 const unsigned short* __restrict__ Bw,
                 const float* __restrict__ bias,
                 unsigned short* __restrict__ Out,
                 float* __restrict__ gsum, float* __restrict__ gsq) {
  constexpr int K = CIN;
  __shared__ unsigned short As[128][64];   // 16 KB
  __shared__ unsigned short Bs[128][64];   // 16 KB
  const int tid  = threadIdx.x;
  const int lane = tid & 63;
  const int wave = tid >> 6;          // 0..3
  const int wid   = blockIdx.x;
  const int batch = wid & 7;          // -> XCD id
  const int inner = wid >> 3;         // 0..127 within batch
  const int bm = batch * 64 + (inner >> 1);
  const int bn = inner & 1;
  const int wm = wave >> 1, wn = wave & 1;

  // prologue: per-chunk gather byte-offsets + weights (chunk i -> fixed row/col)
  unsigned int voK0[4], voK1[4], voK2[4], voU[4];
  float w0r[4], w1r[4], w2r[4];
  #pragma unroll
  for (int i = 0; i < 4; ++i) {
    const int c = wave*64 + i*256 + lane;
    const int row = c >> 3;
    const int colK = (c & 7) * 16;     // byte offset within 512 B bf16 row
    const int colU = (c & 7) * 32;     // byte offset within 512 B fp32 row
    const int p = bm*128 + row;
    const int b = p >> 13;
    w0r[i] = wwgt[p*3+0]; w1r[i] = wwgt[p*3+1]; w2r[i] = wwgt[p*3+2];
    voK0[i] = ((unsigned)((b << 11) + widx[p*3+0]) << 9) + colK;
    voK1[i] = ((unsigned)((b << 11) + widx[p*3+1]) << 9) + colK;
    voK2[i] = ((unsigned)((b << 11) + widx[p*3+2]) << 9) + colK;
    voU[i]  = (unsigned)p * 512u + colU;
  }

  f32x4 acc[4][4];
  const f32x4 zero = {0.f, 0.f, 0.f, 0.f};
  #pragma unroll
  for (int m = 0; m < 4; ++m)
    #pragma unroll
    for (int n = 0; n < 4; ++n) acc[m][n] = zero;

  const char* kfbb = (const char*)kfb;
  const char* ufb  = (const char*)uf;

  // ping-pong prefetch registers (indices constant after full unroll)
  us8    PK0[2][4], PK1[2][4], PK2[2][4];
  float4 PU0[2][4], PU1[2][4];

  #pragma unroll
  for (int i = 0; i < 4; ++i) {        // prologue: gathers for t = 0
    PK0[0][i] = *(const us8*)(kfbb + voK0[i]);
    PK1[0][i] = *(const us8*)(kfbb + voK1[i]);
    PK2[0][i] = *(const us8*)(kfbb + voK2[i]);
  }

  #pragma unroll
  for (int t = 0; t < 6; ++t) {
    const int cur = t & 1, nxt = cur ^ 1;
    const int k0 = t * 64;
    // B-tile: async LDS-direct
    #pragma unroll
    for (int i = 0; i < 4; ++i) {
      const int cbase = wave*64 + i*256;
      const int c = cbase + lane;
      const int brow = c >> 3, bcol = (c & 7) * 8;
      gload16(Bw + ((size_t)(bn*128 + brow))*K + k0 + bcol, (unsigned short*)Bs + cbase*8);
    }
    // prefetch A-tile for t+1 into regs; pin issue before the MFMA phase
    if (t < 3) {
      #pragma unroll
      for (int i = 0; i < 4; ++i) {
        PK0[nxt][i] = *(const us8*)(kfbb + voK0[i] + (t+1)*128);
        PK1[nxt][i] = *(const us8*)(kfbb + voK1[i] + (t+1)*128);
        PK2[nxt][i] = *(const us8*)(kfbb + voK2[i] + (t+1)*128);
      }
    } else if (t < 5) {
      #pragma unroll
      for (int i = 0; i < 4; ++i) {
        PU0[nxt][i] = *(const float4*)(ufb + voU[i] + (t-3)*256);
        PU1[nxt][i] = *(const float4*)(ufb + voU[i] + (t-3)*256 + 16);
      }
    }
    __builtin_amdgcn_sched_barrier(0);
    // convert current tile from regs -> LDS
    #pragma unroll
    for (int i = 0; i < 4; ++i) {
      const int c = wave*64 + i*256 + lane;
      uint4 ov;
      if (t < 4) {
        const float w0 = w0r[i], w1 = w1r[i], w2 = w2r[i];
        float r[8];
        #pragma unroll
        for (int j = 0; j < 8; ++j) {
          float fa = bf2f((unsigned short)PK0[cur][i][j]);
          float fe = bf2f((unsigned short)PK1[cur][i][j]);
          float fg = bf2f((unsigned short)PK2[cur][i][j]);
          r[j] = w0*fa + w1*fe + w2*fg;
        }
        ov.x = cvtpk_bf16(r[0], r[1]);
        ov.y = cvtpk_bf16(r[2], r[3]);
        ov.z = cvtpk_bf16(r[4], r[5]);
        ov.w = cvtpk_bf16(r[6], r[7]);
      } else {
        float4 r0 = PU0[cur][i], r1 = PU1[cur][i];
        ov.x = cvtpk_bf16(r0.x, r0.y);
        ov.y = cvtpk_bf16(r0.z, r0.w);
        ov.z = cvtpk_bf16(r1.x, r1.y);
        ov.w = cvtpk_bf16(r1.z, r1.w);
      }
      *(uint4*)((unsigned short*)As + (size_t)c*8) = ov;
    }
    __syncthreads();
    const int kq = (lane >> 4) * 8;
    #pragma unroll
    for (int kk = 0; kk < 64; kk += 32) {
      bf16x8 af[4], bfr[4];
      #pragma unroll
      for (int m = 0; m < 4; ++m)
        af[m] = *(const bf16x8*)&As[wm*64 + m*16 + (lane & 15)][kk + kq];
      #pragma unroll
      for (int n = 0; n < 4; ++n)
        bfr[n] = *(const bf16x8*)&Bs[wn*64 + n*16 + (lane & 15)][kk + kq];
      #pragma unroll
      for (int m = 0; m < 4; ++m)
        #pragma unroll
        for (int n = 0; n < 4; ++n)
          acc[m][n] = __builtin_amdgcn_mfma_f32_16x16x32_bf16(af[m], bfr[n], acc[m][n], 0, 0, 0);
    }
    __syncthreads();
  }

  // epilogue: bias, store bf16, per-channel sum/sumsq
  float* s_sum = (float*)&As[0][0];   // [2][128]
  float* s_sq  = s_sum + 256;         // [2][128]
  #pragma unroll
  for (int n = 0; n < 4; ++n) {
    const int cb   = wn*64 + n*16 + (lane & 15);
    const int gcol = bn*128 + cb;
    const float bv = bias[gcol];
    float sum = 0.f, sq = 0.f;
    #pragma unroll
    for (int m = 0; m < 4; ++m) {
      const size_t grow = (size_t)bm*128 + wm*64 + m*16 + (lane >> 4)*4;
      #pragma unroll
      for (int qq = 0; qq < 4; ++qq) {
        float y = acc[m][n][qq] + bv;
        sum += y; sq += y*y;
        Out[(grow+qq)*256 + gcol] = f2bf(y);
      }
    }
    sum += __shfl_xor(sum, 16, 64); sum += __shfl_xor(sum, 32, 64);
    sq  += __shfl_xor(sq , 16, 64); sq  += __shfl_xor(sq , 32, 64);
    if (lane < 16) { s_sum[wm*128 + cb] = sum; s_sq[wm*128 + cb] = sq; }
  }
  __syncthreads();
  if (tid < 128) {
    atomicAdd(&gsum[bn*128 + tid], s_sum[tid] + s_sum[128 + tid]);
    atomicAdd(&gsq [bn*128 + tid], s_sq [tid] + s_sq [128 + tid]);
  }
}

// ---------- 4. GEMM2: fused BN1+ReLU on A-load (scale/shift computed in preamble
// from raw sums), y2 bf16 out, + BN2 stats ----------
__global__ __launch_bounds__(256)
void gemm2_kernel(const unsigned short* __restrict__ A,     // y1 raw bf16
                  const unsigned short* __restrict__ Bw,    // W2 bf16
                  const float* __restrict__ bias,           // b2
                  unsigned short* __restrict__ Out,         // y2 bf16
                  float* __restrict__ gsum, float* __restrict__ gsq,     // BN2 accum
                  const float* __restrict__ gsum1, const float* __restrict__ gsq1,
                  const float* __restrict__ g1, const float* __restrict__ be1) {
  constexpr int K = HH;
  __shared__ unsigned short As[128][64];   // 16 KB
  __shared__ unsigned short Bs[128][64];   // 16 KB
  __shared__ float sc_l[HH], sh_l[HH];     // 2 KB
  const int tid  = threadIdx.x;
  const int lane = tid & 63;
  const int wave = tid >> 6;          // 0..3
  const int wid  = blockIdx.x;
  const int slot = wid & 15;
  const int bm = ((wid >> 4) << 3) | (slot & 7);
  const int bn = slot >> 3;
  const int wm = wave >> 1, wn = wave & 1;

  {  // BN1 finalize (redundant per block; replaces stats_fin dispatch)
    float mu  = gsum1[tid] * (1.f/65536.f);
    float var = gsq1[tid]  * (1.f/65536.f) - mu*mu;
    float sc  = g1[tid] * rsqrtf(var + 1e-5f);
    sc_l[tid] = sc;
    sh_l[tid] = be1[tid] - mu*sc;
  }
  __syncthreads();

  f32x4 acc[4][4];
  const f32x4 zero = {0.f, 0.f, 0.f, 0.f};
  #pragma unroll
  for (int m = 0; m < 4; ++m)
    #pragma unroll
    for (int n = 0; n < 4; ++n) acc[m][n] = zero;

  for (int k0 = 0; k0 < K; k0 += 64) {
    #pragma unroll
    for (int i = 0; i < 4; ++i) {
      const int cbase = wave*64 + i*256;          // wave-uniform chunk base
      const int c = cbase + lane;                 // per-lane chunk (16 B)
      const int row = c >> 3, col = (c & 7) * 8;
      gload16(Bw + ((size_t)(bn*128 + row))*K + k0 + col, (unsigned short*)Bs + cbase*8);
      us8 v = *(const us8*)(A + ((size_t)(bm*128 + row))*K + k0 + col);
      us8 o;
      #pragma unroll
      for (int j = 0; j < 8; ++j) {
        float y = fmaxf(fmaf(bf2f(v[j]), sc_l[k0+col+j], sh_l[k0+col+j]), 0.f);
        o[j] = f2bf(y);
      }
      *(us8*)((unsigned short*)As + cbase*8 + lane*8) = o;
    }
    __syncthreads();
    const int kq = (lane >> 4) * 8;
    #pragma unroll
    for (int kk = 0; kk < 64; kk += 32) {
      bf16x8 af[4], bfr[4];
      #pragma unroll
      for (int m = 0; m < 4; ++m)
        af[m] = *(const bf16x8*)&As[wm*64 + m*16 + (lane & 15)][kk + kq];
      #pragma unroll
      for (int n = 0; n < 4; ++n)
        bfr[n] = *(const bf16x8*)&Bs[wn*64 + n*16 + (lane & 15)][kk + kq];
      #pragma unroll
      for (int m = 0; m < 4; ++m)
        #pragma unroll
        for (int n = 0; n < 4; ++n)
          acc[m][n] = __builtin_amdgcn_mfma_f32_16x16x32_bf16(af[m], bfr[n], acc[m][n], 0, 0, 0);
    }
    __syncthreads();
  }

  // epilogue: bias, store bf16 y2, per-channel sum/sumsq
  float* s_sum = (float*)&As[0][0];   // [2][128]
  float* s_sq  = s_sum + 256;         // [2][128]
  #pragma unroll
  for (int n = 0; n < 4; ++n) {
    const int cb   = wn*64 + n*16 + (lane & 15);
    const int gcol = bn*128 + cb;
    const float bv = bias[gcol];
    float sum = 0.f, sq = 0.f;
    #pragma unroll
    for (int m = 0; m < 4; ++m) {
      const size_t grow = (size_t)bm*128 + wm*64 + m*16 + (lane >> 4)*4;
      #pragma unroll
      for (int qq = 0; qq < 4; ++qq) {
        float y = acc[m][n][qq] + bv;
        sum += y; sq += y*y;
        Out[(grow+qq)*256 + gcol] = f2bf(y);
      }
    }
    sum += __shfl_xor(sum, 16, 64); sum += __shfl_xor(sum, 32, 64);
    sq  += __shfl_xor(sq , 16, 64); sq  += __shfl_xor(sq , 32, 64);
    if (lane < 16) { s_sum[wm*128 + cb] = sum; s_sq[wm*128 + cb] = sq; }
  }
  __syncthreads();
  if (tid < 128) {
    atomicAdd(&gsum[bn*128 + tid], s_sum[tid] + s_sum[128 + tid]);
    atomicAdd(&gsq [bn*128 + tid], s_sq [tid] + s_sq [128 + tid]);
  }
}

// ---------- 5. final BN2+ReLU: bf16 y2 -> fp32 d_out (scale/shift in preamble) ----------
__global__ __launch_bounds__(256)
void final_kernel(const unsigned short* __restrict__ Y2, float* __restrict__ Out,
                  const float* __restrict__ gsum, const float* __restrict__ gsq,
                  const float* __restrict__ g2, const float* __restrict__ be2) {
  __shared__ float sc[256], sh[256];
  {  // BN2 finalize (redundant per block; replaces stats_fin dispatch)
    float mu  = gsum[threadIdx.x] * (1.f/65536.f);
    float var = gsq[threadIdx.x]  * (1.f/65536.f) - mu*mu;
    float scv = g2[threadIdx.x] * rsqrtf(var + 1e-5f);
    sc[threadIdx.x] = scv;
    sh[threadIdx.x] = be2[threadIdx.x] - mu*scv;
  }
  __syncthreads();
  size_t i = ((size_t)blockIdx.x * 256 + threadIdx.x) * 8;
  int c0 = (int)(i & 255);
  us8 v = *(const us8*)(Y2 + i);
  float4 o1, o2;
  o1.x = fmaxf(fmaf(bf2f(v[0]), sc[c0+0], sh[c0+0]), 0.f);
  o1.y = fmaxf(fmaf(bf2f(v[1]), sc[c0+1], sh[c0+1]), 0.f);
  o1.z = fmaxf(fmaf(bf2f(v[2]), sc[c0+2], sh[c0+2]), 0.f);
  o1.w = fmaxf(fmaf(bf2f(v[3]), sc[c0+3], sh[c0+3]), 0.f);
  o2.x = fmaxf(fmaf(bf2f(v[4]), sc[c0+4], sh[c0+4]), 0.f);
  o2.y = fmaxf(fmaf(bf2f(v[5]), sc[c0+5], sh[c0+5]), 0.f);
  o2.z = fmaxf(fmaf(bf2f(v[6]), sc[c0+6], sh[c0+6]), 0.f);
  o2.w = fmaxf(fmaf(bf2f(v[7]), sc[c0+7], sh[c0+7]), 0.f);
  *(float4*)(Out + i)     = o1;
  *(float4*)(Out + i + 4) = o2;
}

// ---------- launch ----------
extern "C" void kernel_launch(void* const* d_in, const int* in_sizes, int n_in,
                              void* d_out, int out_size, void* d_ws, size_t ws_size,
                              hipStream_t stream) {
  const float* unknown = (const float*)d_in[0];
  const float* known   = (const float*)d_in[1];
  const float* uf      = (const float*)d_in[2];
  const float* kf      = (const float*)d_in[3];
  const float* W1      = (const float*)d_in[4];
  const float* b1      = (const float*)d_in[5];
  const float* g1      = (const float*)d_in[6];
  const float* be1     = (const float*)d_in[7];
  const float* W2      = (const float*)d_in[8];
  const float* b2      = (const float*)d_in[9];
  const float* g2      = (const float*)d_in[10];
  const float* be2     = (const float*)d_in[11];

  char* ws = (char*)d_ws;
  unsigned short* X    = (unsigned short*)(ws);                 // kfb (8.4 MB) during gemm1, then y2 (33.5 MB)
  unsigned short* Y1   = (unsigned short*)(ws + 50331648);      // 33,554,432 (y1 raw)
  unsigned short* w1b  = (unsigned short*)(ws + 83886080);      // 196,608
  unsigned short* w2b  = (unsigned short*)(ws + 84082688);      // 131,072
  int*            widx = (int*)  (ws + 84213760);               // 786,432
  float*          wwgt = (float*)(ws + 85000192);               // 786,432
  float*          stats= (float*)(ws + 85786624);               // 8 KB
  float4*         kprep= (float4*)(ws + 85794816);              // 262,144
  float *sum1 = stats,        *sq1 = stats + 256;
  float *sum2 = stats + 512,  *sq2 = stats + 768;
  float* out = (float*)d_out;

  // prep: 181248 small items + 524288 kf->bf16 conversions = 705536 threads
  prep_kernel<<<2757, 256, 0, stream>>>(W1, W2, known, kf, w1b, w2b, stats, kprep, X);
  nn_kernel<<<dim3(128, 8), 512, 0, stream>>>(unknown, kprep, widx, wwgt);
  // gemm1: fused interp from bf16 kf (X region); batch->XCD swizzle
  gemm1_fused<<<1024, 256, 0, stream>>>(X, uf, widx, wwgt, w1b, b1, Y1, sum1, sq1);
  // gemm2: BN1 finalized in-kernel; fused BN1+ReLU on A; y2 -> X (overwrites kfb)
  gemm2_kernel<<<1024, 256, 0, stream>>>(Y1, w2b, b2, X, sum2, sq2, sum1, sq1, g1, be1);
  // final: BN2 finalized in-kernel; bf16 y2 -> fp32 d_out
  final_kernel<<<8192, 256, 0, stream>>>(X, out, sum2, sq2, g2, be2);
}